// Round 12
// baseline (929.151 us; speedup 1.0000x reference)
//
#include <hip/hip_runtime.h>
#include <stdint.h>

#define B64   64
#define T52   52
#define TD    51
#define V10K  10000
#define MP    3328   // padded M = 26*128
#define MR    3264   // real M = 64*51
#define NPFC  10112  // padded V = 79*128

typedef float  f32x4  __attribute__((ext_vector_type(4)));
typedef __bf16 bf16x8 __attribute__((ext_vector_type(8)));
typedef unsigned int u32x4 __attribute__((ext_vector_type(4)));
typedef unsigned short ushort_t;

__device__ inline unsigned short f2bf(float f) {
  unsigned u = __builtin_bit_cast(unsigned, f);
  u += 0x7fffu + ((u >> 16) & 1u);
  return (unsigned short)(u >> 16);
}
__device__ inline unsigned pack2(float a, float b) {
  return (unsigned)f2bf(a) | ((unsigned)f2bf(b) << 16);
}
__device__ inline float sigm(float x) { return 1.f / (1.f + expf(-x)); }

// MALL write-through 2B store (agent scope)
__device__ inline void store2_sc(ushort_t* p, unsigned v) {
  asm volatile("global_store_short %0, %1, off sc1" :: "v"(p), "v"(v) : "memory");
}
// 16 x 16B sc1 loads + single wait
__device__ inline void loadA16(const ushort_t* a, u32x4 (&h)[16]) {
  asm volatile(
    "global_load_dwordx4 %0,  %16, off sc1\n\t"
    "global_load_dwordx4 %1,  %16, off offset:64 sc1\n\t"
    "global_load_dwordx4 %2,  %16, off offset:128 sc1\n\t"
    "global_load_dwordx4 %3,  %16, off offset:192 sc1\n\t"
    "global_load_dwordx4 %4,  %16, off offset:256 sc1\n\t"
    "global_load_dwordx4 %5,  %16, off offset:320 sc1\n\t"
    "global_load_dwordx4 %6,  %16, off offset:384 sc1\n\t"
    "global_load_dwordx4 %7,  %16, off offset:448 sc1\n\t"
    "global_load_dwordx4 %8,  %16, off offset:512 sc1\n\t"
    "global_load_dwordx4 %9,  %16, off offset:576 sc1\n\t"
    "global_load_dwordx4 %10, %16, off offset:640 sc1\n\t"
    "global_load_dwordx4 %11, %16, off offset:704 sc1\n\t"
    "global_load_dwordx4 %12, %16, off offset:768 sc1\n\t"
    "global_load_dwordx4 %13, %16, off offset:832 sc1\n\t"
    "global_load_dwordx4 %14, %16, off offset:896 sc1\n\t"
    "global_load_dwordx4 %15, %16, off offset:960 sc1\n\t"
    "s_waitcnt vmcnt(0)"
    : "=&v"(h[0]),"=&v"(h[1]),"=&v"(h[2]),"=&v"(h[3]),
      "=&v"(h[4]),"=&v"(h[5]),"=&v"(h[6]),"=&v"(h[7]),
      "=&v"(h[8]),"=&v"(h[9]),"=&v"(h[10]),"=&v"(h[11]),
      "=&v"(h[12]),"=&v"(h[13]),"=&v"(h[14]),"=&v"(h[15])
    : "v"(a) : "memory");
}
// 32 x 16B sc1 loads from two bases + single wait
__device__ inline void loadA32(const ushort_t* a, const ushort_t* b,
                               u32x4 (&ha)[16], u32x4 (&hb)[16]) {
  asm volatile(
    "global_load_dwordx4 %0,  %32, off sc1\n\t"
    "global_load_dwordx4 %1,  %32, off offset:64 sc1\n\t"
    "global_load_dwordx4 %2,  %32, off offset:128 sc1\n\t"
    "global_load_dwordx4 %3,  %32, off offset:192 sc1\n\t"
    "global_load_dwordx4 %4,  %32, off offset:256 sc1\n\t"
    "global_load_dwordx4 %5,  %32, off offset:320 sc1\n\t"
    "global_load_dwordx4 %6,  %32, off offset:384 sc1\n\t"
    "global_load_dwordx4 %7,  %32, off offset:448 sc1\n\t"
    "global_load_dwordx4 %8,  %32, off offset:512 sc1\n\t"
    "global_load_dwordx4 %9,  %32, off offset:576 sc1\n\t"
    "global_load_dwordx4 %10, %32, off offset:640 sc1\n\t"
    "global_load_dwordx4 %11, %32, off offset:704 sc1\n\t"
    "global_load_dwordx4 %12, %32, off offset:768 sc1\n\t"
    "global_load_dwordx4 %13, %32, off offset:832 sc1\n\t"
    "global_load_dwordx4 %14, %32, off offset:896 sc1\n\t"
    "global_load_dwordx4 %15, %32, off offset:960 sc1\n\t"
    "global_load_dwordx4 %16, %33, off sc1\n\t"
    "global_load_dwordx4 %17, %33, off offset:64 sc1\n\t"
    "global_load_dwordx4 %18, %33, off offset:128 sc1\n\t"
    "global_load_dwordx4 %19, %33, off offset:192 sc1\n\t"
    "global_load_dwordx4 %20, %33, off offset:256 sc1\n\t"
    "global_load_dwordx4 %21, %33, off offset:320 sc1\n\t"
    "global_load_dwordx4 %22, %33, off offset:384 sc1\n\t"
    "global_load_dwordx4 %23, %33, off offset:448 sc1\n\t"
    "global_load_dwordx4 %24, %33, off offset:512 sc1\n\t"
    "global_load_dwordx4 %25, %33, off offset:576 sc1\n\t"
    "global_load_dwordx4 %26, %33, off offset:640 sc1\n\t"
    "global_load_dwordx4 %27, %33, off offset:704 sc1\n\t"
    "global_load_dwordx4 %28, %33, off offset:768 sc1\n\t"
    "global_load_dwordx4 %29, %33, off offset:832 sc1\n\t"
    "global_load_dwordx4 %30, %33, off offset:896 sc1\n\t"
    "global_load_dwordx4 %31, %33, off offset:960 sc1\n\t"
    "s_waitcnt vmcnt(0)"
    : "=&v"(ha[0]),"=&v"(ha[1]),"=&v"(ha[2]),"=&v"(ha[3]),
      "=&v"(ha[4]),"=&v"(ha[5]),"=&v"(ha[6]),"=&v"(ha[7]),
      "=&v"(ha[8]),"=&v"(ha[9]),"=&v"(ha[10]),"=&v"(ha[11]),
      "=&v"(ha[12]),"=&v"(ha[13]),"=&v"(ha[14]),"=&v"(ha[15]),
      "=&v"(hb[0]),"=&v"(hb[1]),"=&v"(hb[2]),"=&v"(hb[3]),
      "=&v"(hb[4]),"=&v"(hb[5]),"=&v"(hb[6]),"=&v"(hb[7]),
      "=&v"(hb[8]),"=&v"(hb[9]),"=&v"(hb[10]),"=&v"(hb[11]),
      "=&v"(hb[12]),"=&v"(hb[13]),"=&v"(hb[14]),"=&v"(hb[15])
    : "v"(a), "v"(b) : "memory");
}

// ---------------- prep ------------------------------------------------------
__global__ void k_prep(const int* __restrict__ cl, const int* __restrict__ caps,
                       float* __restrict__ out_caps, float* __restrict__ out_capr,
                       float* __restrict__ out_lm1, float* __restrict__ out_ord,
                       int* __restrict__ order_i, int* __restrict__ lensm1_i,
                       int* __restrict__ nvtab, int* __restrict__ capsS,
                       int* __restrict__ capsRev, int* __restrict__ cumtab,
                       int* __restrict__ rowmap)
{
  __shared__ int L[64], O[64], Ls_s[64], Cum[65];
  __shared__ int C_s[64][T52];
  int i = threadIdx.x;
  L[i] = cl[i];
  __syncthreads();
  if (i == 0) {
    for (int a = 0; a < 64; ++a) O[a] = a;
    for (int a = 1; a < 64; ++a) {
      int key = O[a], kl = L[key], b = a - 1;
      while (b >= 0 && L[O[b]] < kl) { O[b + 1] = O[b]; --b; }
      O[b + 1] = key;
    }
  }
  __syncthreads();
  int src = O[i];
  int Ls  = L[src];
  Ls_s[i] = Ls;
  order_i[i]  = src;
  lensm1_i[i] = Ls - 1;
  out_lm1[i]  = (float)(Ls - 1);
  out_ord[i]  = (float)src;
  for (int t = 0; t < T52; ++t) {
    int c = caps[src * T52 + t];
    C_s[i][t] = c;
    capsS[i * T52 + t]    = c;
    out_caps[i * T52 + t] = (float)c;
  }
  __syncthreads();
  for (int j = 0; j < T52; ++j) {
    int rv = (j < Ls) ? C_s[i][Ls - 1 - j] : 0;
    capsRev[i * T52 + j]  = rv;
    out_capr[i * T52 + j] = (float)rv;
  }
  if (i == 0) {
    int s = 0;
    for (int b = 0; b < 64; ++b) { Cum[b] = s; s += Ls_s[b] - 1; }
    Cum[64] = s;
  }
  __syncthreads();
  cumtab[i] = Cum[i];
  if (i == 0) cumtab[64] = Cum[64];
  for (int t = 0; t < Ls - 1; ++t) rowmap[Cum[i] + t] = i * TD + t;
  if (i < TD) {
    int nv = 0;
    for (int r = 0; r < 64; ++r) nv += (Ls_s[r] - 1 > i) ? 1 : 0;
    nvtab[i] = nv;
  }
}

// ------- convert weights to bf16 + bias sums + img operands + emb gather ----
__global__ void k_convert(const float* __restrict__ w_ih1, const float* __restrict__ w_ihr1,
                          const float* __restrict__ fc_w, const float* __restrict__ fcr_w,
                          const float* __restrict__ b_ih1, const float* __restrict__ b_hh1,
                          const float* __restrict__ b_ihr1, const float* __restrict__ b_hhr1,
                          const float* __restrict__ w_hh1, const float* __restrict__ w_hhr1,
                          const float* __restrict__ w_ih2, const float* __restrict__ w_ihr2,
                          const float* __restrict__ w_hh2, const float* __restrict__ w_hhr2,
                          const float* __restrict__ img_f_w, const float* __restrict__ img_b_w,
                          const float* __restrict__ b_ih2, const float* __restrict__ b_hh2,
                          const float* __restrict__ b_ihr2, const float* __restrict__ b_hhr2,
                          const float* __restrict__ enc, const int* __restrict__ order_i,
                          const float* __restrict__ emb_w, const float* __restrict__ emb_r_w,
                          const int* __restrict__ capsS, const int* __restrict__ capsRev,
                          const int* __restrict__ rowmap, const int* __restrict__ cumtab,
                          ushort_t* __restrict__ wih1bf, ushort_t* __restrict__ fcwbf,
                          ushort_t* __restrict__ whh1bf, ushort_t* __restrict__ wih2Lbf,
                          ushort_t* __restrict__ whh2bf, ushort_t* __restrict__ wih2Ibf,
                          ushort_t* __restrict__ imgwbf, ushort_t* __restrict__ encbf,
                          ushort_t* __restrict__ embA,
                          float* __restrict__ biasg1, float* __restrict__ biasg2)
{
  long long gid = (long long)blockIdx.x * blockDim.x + threadIdx.x;
  const long long C1 = 2048LL * 512 / 8;          // 131072
  const long long CF = (long long)NPFC * 512 / 8; // 647168
  const long long CPD = (long long)MP * 512 / 8;  // 212992
  const long long bs  = 2 * C1 + 2 * CF;
  const long long bs2 = bs + 6 * C1;
  const long long bs3 = bs2 + 2 * C1;   // wih2Ibf
  const long long bs4 = bs3 + 2 * C1;   // imgwbf
  const long long bs5 = bs4 + 32768;    // encbf
  const long long bs6 = bs5 + 2 * CPD;  // embA
  if (gid < 2 * C1) {
    int dir = gid >= C1; long long cid = gid - (long long)dir * C1;
    const float* s = (dir ? w_ihr1 : w_ih1) + cid * 8;
    ushort_t* d = wih1bf + (long long)dir * 2048 * 512 + cid * 8;
    uint4 v;
    v.x = pack2(s[0], s[1]); v.y = pack2(s[2], s[3]);
    v.z = pack2(s[4], s[5]); v.w = pack2(s[6], s[7]);
    *(uint4*)d = v;
  } else if (gid < bs) {
    long long g2 = gid - 2 * C1; int dir = g2 >= CF;
    long long cid = g2 - (long long)dir * CF;
    long long row = cid >> 6; int k8 = (int)(cid & 63) * 8;
    ushort_t* d = fcwbf + (long long)dir * NPFC * 512 + row * 512 + k8;
    uint4 v;
    if (row < V10K) {
      const float* s = (dir ? fcr_w : fc_w) + row * 512 + k8;
      v.x = pack2(s[0], s[1]); v.y = pack2(s[2], s[3]);
      v.z = pack2(s[4], s[5]); v.w = pack2(s[6], s[7]);
    } else { v.x = v.y = v.z = v.w = 0u; }
    *(uint4*)d = v;
  } else if (gid < bs2) {
    long long e = gid - bs;
    int arr = (int)(e / (2 * C1));
    long long d2 = e - (long long)arr * 2 * C1;
    int dir = d2 >= C1;
    long long cid = d2 - (long long)dir * C1;
    long long row = cid >> 6; int k8 = (int)(cid & 63) * 8;
    const float* s;
    ushort_t* d;
    if (arr == 0)      { s = (dir ? w_hhr1 : w_hh1) + row * 512  + k8; d = whh1bf; }
    else if (arr == 1) { s = (dir ? w_ihr2 : w_ih2) + row * 1024 + k8; d = wih2Lbf; }
    else               { s = (dir ? w_hhr2 : w_hh2) + row * 512  + k8; d = whh2bf; }
    d += (long long)dir * 2048 * 512 + cid * 8;
    uint4 v;
    v.x = pack2(s[0], s[1]); v.y = pack2(s[2], s[3]);
    v.z = pack2(s[4], s[5]); v.w = pack2(s[6], s[7]);
    *(uint4*)d = v;
  } else if (gid < bs3) {
    long long e = gid - bs2; int dir = e >= C1;
    long long cid = e - (long long)dir * C1;
    long long row = cid >> 6; int k8 = (int)(cid & 63) * 8;
    const float* s = (dir ? w_ihr2 : w_ih2) + row * 1024 + 512 + k8;
    ushort_t* d = wih2Ibf + (long long)dir * 2048 * 512 + cid * 8;
    uint4 v;
    v.x = pack2(s[0], s[1]); v.y = pack2(s[2], s[3]);
    v.z = pack2(s[4], s[5]); v.w = pack2(s[6], s[7]);
    *(uint4*)d = v;
  } else if (gid < bs4) {
    long long e = gid - bs3; int dir = e >= C1;
    long long cid = e - (long long)dir * C1;
    long long row = cid >> 8; int c8 = (int)(cid & 255) * 8;
    const float* s = (dir ? img_b_w : img_f_w) + row * 2048 + c8;
    ushort_t* d = imgwbf + (long long)dir * 512 * 2048 + cid * 8;
    uint4 v;
    v.x = pack2(s[0], s[1]); v.y = pack2(s[2], s[3]);
    v.z = pack2(s[4], s[5]); v.w = pack2(s[6], s[7]);
    *(uint4*)d = v;
  } else if (gid < bs5) {
    long long cid = gid - bs4;
    int m = (int)(cid >> 8); int c8 = (int)(cid & 255) * 8;
    const float* s = enc + (long long)order_i[m & 63] * 2048 + c8;
    ushort_t* d = encbf + cid * 8;
    uint4 v;
    v.x = pack2(s[0], s[1]); v.y = pack2(s[2], s[3]);
    v.z = pack2(s[4], s[5]); v.w = pack2(s[6], s[7]);
    *(uint4*)d = v;
  } else if (gid < bs6) {
    long long e = gid - bs5;
    int dir = e >= CPD; long long cid = e - (long long)dir * CPD;
    int c = (int)(cid >> 6); int k8 = (int)(cid & 63) * 8;
    ushort_t* d = embA + (long long)dir * MP * 512 + (long long)c * 512 + k8;
    uint4 v;
    if (c < cumtab[64]) {
      int m = rowmap[c];
      int b = m / TD, t = m - b * TD;
      int row = dir ? capsRev[b * T52 + t] : capsS[b * T52 + t];
      const float* s = (dir ? emb_r_w : emb_w) + (long long)row * 512 + k8;
      v.x = pack2(s[0], s[1]); v.y = pack2(s[2], s[3]);
      v.z = pack2(s[4], s[5]); v.w = pack2(s[6], s[7]);
    } else { v.x = v.y = v.z = v.w = 0u; }
    *(uint4*)d = v;
  } else {
    long long g3 = gid - bs6;
    if (g3 < 4096) {
      int dir = g3 >= 2048; int j = (int)(g3 & 2047);
      biasg1[dir * 2048 + j] = dir ? (b_ihr1[j] + b_hhr1[j]) : (b_ih1[j] + b_hh1[j]);
    } else if (g3 < 8192) {
      long long g4 = g3 - 4096;
      int dir = g4 >= 2048; int j = (int)(g4 & 2047);
      biasg2[dir * 2048 + j] = dir ? (b_ihr2[j] + b_hhr2[j]) : (b_ih2[j] + b_hh2[j]);
    }
  }
}

// ------- bf16 MFMA GEMM, BK=64 XOR-swizzled staging -------------------------
// MODE 0: fp32 out, no guards, +bias[n]  (mlim: early-exit on tm >= mlim[64])
// MODE 2: fp32 out, n<Nreal guard, +bias[m]
// MODE 3: bf16 out, no guards, +bias[n]
template<int MODE>
__global__ __launch_bounds__(256)
void k_gemm(const ushort_t* __restrict__ A0, long long As,
            const ushort_t* __restrict__ B0, long long Bs,
            const float* __restrict__ bias0, const float* __restrict__ bias1,
            void* __restrict__ out0, long long Os,
            int Nreal, int K, const int* __restrict__ mlim)
{
  long long tm = (long long)blockIdx.x * 128;
  if (mlim && tm >= mlim[64]) return;
  __shared__ ushort_t Ab[128 * 64];
  __shared__ ushort_t Bb[128 * 64];
  int dirz = blockIdx.z;
  const ushort_t* A = A0 + dirz * As;
  const ushort_t* Bm = B0 + dirz * Bs;
  const float* bias = dirz ? bias1 : bias0;
  int tid = threadIdx.x;
  int lane = tid & 63, wid = tid >> 6;
  int wr = wid >> 1, wc = wid & 1;
  long long tn = (long long)blockIdx.y * 128;
  f32x4 acc[4][4] = {};
  int KK = K >> 6;
  for (int kk = 0; kk < KK; ++kk) {
    uint4 va[4], vb[4];
    #pragma unroll
    for (int p = 0; p < 4; ++p) {
      int g = tid + p * 256;
      int row = g >> 3, gc = g & 7;
      va[p] = *(const uint4*)(A + (tm + row) * K + kk * 64 + gc * 8);
      vb[p] = *(const uint4*)(Bm + (tn + row) * K + kk * 64 + gc * 8);
    }
    __syncthreads();
    #pragma unroll
    for (int p = 0; p < 4; ++p) {
      int g = tid + p * 256;
      int row = g >> 3, gc = g & 7;
      int slot = gc ^ (row & 7);
      *(uint4*)&Ab[row * 64 + slot * 8] = va[p];
      *(uint4*)&Bb[row * 64 + slot * 8] = vb[p];
    }
    __syncthreads();
    #pragma unroll
    for (int sub = 0; sub < 2; ++sub) {
      bf16x8 av[4], bv[4];
      #pragma unroll
      for (int mi = 0; mi < 4; ++mi) {
        int row = wr * 64 + mi * 16 + (lane & 15);
        int gcol = sub * 4 + (lane >> 4);
        av[mi] = *(const bf16x8*)&Ab[row * 64 + (gcol ^ (row & 7)) * 8];
      }
      #pragma unroll
      for (int ni = 0; ni < 4; ++ni) {
        int row = wc * 64 + ni * 16 + (lane & 15);
        int gcol = sub * 4 + (lane >> 4);
        bv[ni] = *(const bf16x8*)&Bb[row * 64 + (gcol ^ (row & 7)) * 8];
      }
      #pragma unroll
      for (int mi = 0; mi < 4; ++mi)
        #pragma unroll
        for (int ni = 0; ni < 4; ++ni)
          acc[mi][ni] = __builtin_amdgcn_mfma_f32_16x16x32_bf16(av[mi], bv[ni], acc[mi][ni], 0, 0, 0);
    }
  }
  #pragma unroll
  for (int mi = 0; mi < 4; ++mi) {
    #pragma unroll
    for (int rr = 0; rr < 4; ++rr) {
      long long m = tm + wr * 64 + mi * 16 + ((lane >> 4) * 4) + rr;
      if (MODE == 0) {
        float* orow = (float*)out0 + dirz * Os + m * (long long)Nreal;
        #pragma unroll
        for (int ni = 0; ni < 4; ++ni) {
          int n = (int)tn + wc * 64 + ni * 16 + (lane & 15);
          orow[n] = acc[mi][ni][rr] + bias[n];
        }
      } else if (MODE == 2) {
        float bm = bias[m];
        float* orow = (float*)out0 + dirz * Os + m * (long long)Nreal;
        #pragma unroll
        for (int ni = 0; ni < 4; ++ni) {
          int n = (int)tn + wc * 64 + ni * 16 + (lane & 15);
          if (n < Nreal) orow[n] = acc[mi][ni][rr] + bm;
        }
      } else {
        ushort_t* orow = (ushort_t*)out0 + dirz * Os + m * (long long)Nreal;
        #pragma unroll
        for (int ni = 0; ni < 4; ++ni) {
          int n = (int)tn + wc * 64 + ni * 16 + (lane & 15);
          orow[n] = f2bf(acc[mi][ni][rr] + bias[n]);
        }
      }
    }
  }
}

// ------- FC on compacted rows (BK=64): preds[rowmap[c]] = A[c].fcw^T --------
__global__ __launch_bounds__(256)
void k_fc(const ushort_t* __restrict__ A0, const ushort_t* __restrict__ B0,
          const float* __restrict__ bias0, const float* __restrict__ bias1,
          float* __restrict__ out0, const int* __restrict__ rowmap,
          const int* __restrict__ cumtab)
{
  const long long PRED = (long long)MR * V10K;
  int Mc = cumtab[64];
  long long tm = (long long)blockIdx.x * 128;
  if (tm >= Mc) return;
  __shared__ ushort_t Ab[128 * 64];
  __shared__ ushort_t Bb[128 * 64];
  int dirz = blockIdx.z;
  const ushort_t* A = A0 + (long long)dirz * MP * 512;
  const ushort_t* Bm = B0 + (long long)dirz * NPFC * 512;
  const float* bias = dirz ? bias1 : bias0;
  float* out = out0 + (long long)dirz * PRED;
  int tid = threadIdx.x;
  int lane = tid & 63, wid = tid >> 6;
  int wr = wid >> 1, wc = wid & 1;
  long long tn = (long long)blockIdx.y * 128;
  f32x4 acc[4][4] = {};
  for (int kk = 0; kk < 8; ++kk) {
    uint4 va[4], vb[4];
    #pragma unroll
    for (int p = 0; p < 4; ++p) {
      int g = tid + p * 256;
      int row = g >> 3, gc = g & 7;
      va[p] = *(const uint4*)(A + (tm + row) * 512 + kk * 64 + gc * 8);
      vb[p] = *(const uint4*)(Bm + (tn + row) * 512 + kk * 64 + gc * 8);
    }
    __syncthreads();
    #pragma unroll
    for (int p = 0; p < 4; ++p) {
      int g = tid + p * 256;
      int row = g >> 3, gc = g & 7;
      int slot = gc ^ (row & 7);
      *(uint4*)&Ab[row * 64 + slot * 8] = va[p];
      *(uint4*)&Bb[row * 64 + slot * 8] = vb[p];
    }
    __syncthreads();
    #pragma unroll
    for (int sub = 0; sub < 2; ++sub) {
      bf16x8 av[4], bv[4];
      #pragma unroll
      for (int mi = 0; mi < 4; ++mi) {
        int row = wr * 64 + mi * 16 + (lane & 15);
        int gcol = sub * 4 + (lane >> 4);
        av[mi] = *(const bf16x8*)&Ab[row * 64 + (gcol ^ (row & 7)) * 8];
      }
      #pragma unroll
      for (int ni = 0; ni < 4; ++ni) {
        int row = wc * 64 + ni * 16 + (lane & 15);
        int gcol = sub * 4 + (lane >> 4);
        bv[ni] = *(const bf16x8*)&Bb[row * 64 + (gcol ^ (row & 7)) * 8];
      }
      #pragma unroll
      for (int mi = 0; mi < 4; ++mi)
        #pragma unroll
        for (int ni = 0; ni < 4; ++ni)
          acc[mi][ni] = __builtin_amdgcn_mfma_f32_16x16x32_bf16(av[mi], bv[ni], acc[mi][ni], 0, 0, 0);
    }
  }
  #pragma unroll
  for (int mi = 0; mi < 4; ++mi) {
    #pragma unroll
    for (int rr = 0; rr < 4; ++rr) {
      long long c = tm + wr * 64 + mi * 16 + ((lane >> 4) * 4) + rr;
      if (c < Mc) {
        int m = rowmap[c];
        float* orow = out + (long long)m * V10K;
        #pragma unroll
        for (int ni = 0; ni < 4; ++ni) {
          int n = (int)tn + wc * 64 + ni * 16 + (lane & 15);
          if (n < V10K) orow[n] = acc[mi][ni][rr] + bias[n];
        }
      }
    }
  }
}

// ---------------- zero-fill invalid preds rows ------------------------------
__global__ __launch_bounds__(256)
void k_zero(float* __restrict__ outF, const int* __restrict__ lensm1_i)
{
  const long long PRED = (long long)MR * V10K;
  int m = blockIdx.x;            // 0..MR-1
  int b = m / TD, t = m - b * TD;
  if (t < lensm1_i[b]) return;
  float4 z = {0.f, 0.f, 0.f, 0.f};
  float* r0 = outF + (long long)m * V10K;
  float* r1 = outF + PRED + (long long)m * V10K;
  for (int i = threadIdx.x; i < 2500; i += 256) {
    ((float4*)r0)[i] = z;
    ((float4*)r1)[i] = z;
  }
}

// ---------------- persistent recurrent kernel (r10 structure, verbatim) -----
// bid 0..127:   L1 (idx=bid:     dir=idx>>6, half=(idx&63)>>5, ht=idx&31)
// bid 128..255: L2 (idx=bid-128: same decomposition)
// 128 threads (2 waves), both waves compute 16 rows each.
// Single combined poll per step (proven in r10; split polls regress).
__global__ __launch_bounds__(128, 1)
void k_rec(const ushort_t* __restrict__ whh1bf, const ushort_t* __restrict__ wih2Lbf,
           const ushort_t* __restrict__ whh2bf, const float* __restrict__ xg1,
           const float* __restrict__ xg2imgT,
           ushort_t* __restrict__ h1hist,   // [52][2][64][512] bf16; slot0 = zeros
           ushort_t* __restrict__ h2buf,    // [2][2][64][512]  (ping-pong, zeroed)
           ushort_t* __restrict__ h2allbf,  // [dir][compact c][512]
           const int* __restrict__ nvtab, const int* __restrict__ cumtab,
           int* __restrict__ slots)         // [0..127]=aS (4 grp x32), [128..255]=bS
{
  const int bid = blockIdx.x;
  const bool isL2 = bid >= 128;
  const int idx = isL2 ? bid - 128 : bid;
  const int dir = idx >> 6, sub = idx & 63, half = sub >> 5, ht = sub & 31;
  const int tid = threadIdx.x;          // 0..127
  const int lane = tid & 63, mt = tid >> 6;
  const int l15 = lane & 15, l4 = lane >> 4;
  const int jl = ht * 16 + l15;
  const int rbase = half * 32 + mt * 16;
  const int r0 = rbase + l4 * 4;

  __shared__ ushort_t Wl[32768];  // 64KB [4 gates][16 cols][512 k] XOR-swizzled
  __shared__ ushort_t Wi[32768];  // 64KB wih2 h1-part (L2 only)
  __shared__ int nv_s[64];
  __shared__ int cum_s[64];

  {
    const ushort_t* src = (isL2 ? whh2bf : whh1bf) + (long long)dir * 2048 * 512;
    #pragma unroll
    for (int i = 0; i < 32; ++i) {
      int c = tid + i * 128;
      int nl = c >> 6;
      int kb = (c & 63) * 16;
      int row = (nl >> 4) * 512 + ht * 16 + (nl & 15);
      u32x4 v = *(const u32x4*)(src + (long long)row * 512 + (long long)(c & 63) * 8);
      *(u32x4*)((char*)Wl + nl * 1024 + (kb ^ ((nl & 7) << 4))) = v;
    }
    if (isL2) {
      const ushort_t* src2 = wih2Lbf + (long long)dir * 2048 * 512;
      #pragma unroll
      for (int i = 0; i < 32; ++i) {
        int c = tid + i * 128;
        int nl = c >> 6;
        int kb = (c & 63) * 16;
        int row = (nl >> 4) * 512 + ht * 16 + (nl & 15);
        u32x4 v = *(const u32x4*)(src2 + (long long)row * 512 + (long long)(c & 63) * 8);
        *(u32x4*)((char*)Wi + nl * 1024 + (kb ^ ((nl & 7) << 4))) = v;
      }
    }
    if (tid < TD) nv_s[tid] = nvtab[tid];
    if (tid < 64) cum_s[tid] = cumtab[tid];
  }
  __syncthreads();

  int* aS = slots + (dir * 2 + half) * 32;
  int* bS = slots + 128 + (dir * 2 + half) * 32;

  if (!isL2) {
    // ---------------- L1 pipeline (2 waves x 16 rows) ----------------
    f32x4 creg = {0.f, 0.f, 0.f, 0.f};
    for (int t = 0; t < TD; ++t) {
      bool act = (rbase < nv_s[t]);
      // x-gate loads (h-independent, compacted xg1): issue before the poll
      float xs[4][4];
      if (act) {
        const float* xb = xg1 + (long long)dir * MP * 2048;
        #pragma unroll
        for (int rr = 0; rr < 4; ++rr) {
          const float* xr = xb + (long long)(cum_s[r0 + rr] + t) * 2048;
          #pragma unroll
          for (int g = 0; g < 4; ++g)
            xs[g][rr] = xr[g * 512 + jl];
        }
      }
      if (t > 0) {
        if (mt == 0) {
          for (;;) {
            int v = __hip_atomic_load(&aS[lane & 31], __ATOMIC_RELAXED, __HIP_MEMORY_SCOPE_AGENT);
            if (__all(v >= t)) break;
          }
        }
        __syncthreads();
      }
      if (act) {
        const ushort_t* hsrc = h1hist + ((long long)t * 2 + dir) * (64 * 512);
        u32x4 hv[16];
        loadA16(hsrc + (long long)(rbase + l15) * 512 + l4 * 8, hv);
        f32x4 acc[4] = {};
        #pragma unroll
        for (int kk = 0; kk < 16; ++kk) {
          bf16x8 av = __builtin_bit_cast(bf16x8, hv[kk]);
          int kb = kk * 64 + l4 * 16;
          #pragma unroll
          for (int g = 0; g < 4; ++g) {
            bf16x8 bv = *(const bf16x8*)((const char*)Wl + (g * 16 + l15) * 1024 + (kb ^ ((l15 & 7) << 4)));
            acc[g] = __builtin_amdgcn_mfma_f32_16x16x32_bf16(av, bv, acc[g], 0, 0, 0);
          }
        }
        ushort_t* hdst = h1hist + ((long long)(t + 1) * 2 + dir) * (64 * 512);
        f32x4 cn;
        #pragma unroll
        for (int rr = 0; rr < 4; ++rr) {
          float gi = acc[0][rr] + xs[0][rr];
          float gf = acc[1][rr] + xs[1][rr];
          float gg = acc[2][rr] + xs[2][rr];
          float go = acc[3][rr] + xs[3][rr];
          float c = sigm(gf) * creg[rr] + sigm(gi) * tanhf(gg);
          float h = sigm(go) * tanhf(c);
          cn[rr] = c;
          store2_sc(hdst + (long long)(r0 + rr) * 512 + jl, (unsigned)f2bf(h));
        }
        creg = cn;
      }
      __syncthreads();   // drains each wave's vmcnt before the slot store
      if (tid == 0)
        __hip_atomic_store(&aS[ht], t + 1, __ATOMIC_RELAXED, __HIP_MEMORY_SCOPE_AGENT);
    }
  } else {
    // ---------------- L2 pipeline (2 waves x 16 rows) ----------------
    f32x4 xv2[4];
    {
      const float* xg = xg2imgT + (long long)dir * (2048 * 64);
      #pragma unroll
      for (int g = 0; g < 4; ++g)
        xv2[g] = *(const f32x4*)(xg + (long long)(g * 512 + jl) * 64 + r0);
    }
    f32x4 creg = {0.f, 0.f, 0.f, 0.f};
    for (int t = 0; t < TD; ++t) {
      // single combined poll: h1(t) ready (aS >= t+1) AND h2(t-1) ready (bS >= t)
      if (mt == 0) {
        for (;;) {
          int va = __hip_atomic_load(&aS[lane & 31], __ATOMIC_RELAXED, __HIP_MEMORY_SCOPE_AGENT);
          int vb = __hip_atomic_load(&bS[lane & 31], __ATOMIC_RELAXED, __HIP_MEMORY_SCOPE_AGENT);
          if (__all((va >= t + 1) & (vb >= t))) break;
        }
      }
      __syncthreads();
      int nv = nv_s[t];
      if (rbase < nv) {
        const ushort_t* h1s = h1hist + ((long long)(t + 1) * 2 + dir) * (64 * 512);
        const ushort_t* h2s = h2buf + ((long long)((t + 1) & 1) * 2 + dir) * (64 * 512);
        u32x4 ha[16], hb[16];
        loadA32(h1s + (long long)(rbase + l15) * 512 + l4 * 8,
                h2s + (long long)(rbase + l15) * 512 + l4 * 8, ha, hb);
        f32x4 acc[4] = {};
        #pragma unroll
        for (int kk = 0; kk < 16; ++kk) {
          bf16x8 av = __builtin_bit_cast(bf16x8, ha[kk]);
          int kb = kk * 64 + l4 * 16;
          #pragma unroll
          for (int g = 0; g < 4; ++g) {
            bf16x8 bv = *(const bf16x8*)((const char*)Wi + (g * 16 + l15) * 1024 + (kb ^ ((l15 & 7) << 4)));
            acc[g] = __builtin_amdgcn_mfma_f32_16x16x32_bf16(av, bv, acc[g], 0, 0, 0);
          }
        }
        #pragma unroll
        for (int kk = 0; kk < 16; ++kk) {
          bf16x8 av = __builtin_bit_cast(bf16x8, hb[kk]);
          int kb = kk * 64 + l4 * 16;
          #pragma unroll
          for (int g = 0; g < 4; ++g) {
            bf16x8 bv = *(const bf16x8*)((const char*)Wl + (g * 16 + l15) * 1024 + (kb ^ ((l15 & 7) << 4)));
            acc[g] = __builtin_amdgcn_mfma_f32_16x16x32_bf16(av, bv, acc[g], 0, 0, 0);
          }
        }
        ushort_t* h2n = h2buf + ((long long)(t & 1) * 2 + dir) * (64 * 512);
        ushort_t* h2a = h2allbf + (long long)dir * MP * 512;
        f32x4 cn;
        #pragma unroll
        for (int rr = 0; rr < 4; ++rr) {
          float gi = acc[0][rr] + xv2[0][rr];
          float gf = acc[1][rr] + xv2[1][rr];
          float gg = acc[2][rr] + xv2[2][rr];
          float go = acc[3][rr] + xv2[3][rr];
          float c = sigm(gf) * creg[rr] + sigm(gi) * tanhf(gg);
          float h = sigm(go) * tanhf(c);
          cn[rr] = c;
          ushort_t hbb = f2bf(h);
          store2_sc(h2n + (long long)(r0 + rr) * 512 + jl, (unsigned)hbb);
          if (r0 + rr < nv)
            h2a[((long long)(cum_s[r0 + rr] + t)) * 512 + jl] = hbb;
        }
        creg = cn;
      }
      __syncthreads();   // drains each wave's vmcnt before the slot store
      if (tid == 0)
        __hip_atomic_store(&bS[ht], t + 1, __ATOMIC_RELAXED, __HIP_MEMORY_SCOPE_AGENT);
    }
  }
}

// ---------------------------------------------------------------------------
extern "C" void kernel_launch(void* const* d_in, const int* in_sizes, int n_in,
                              void* d_out, int out_size, void* d_ws, size_t ws_size,
                              hipStream_t stream)
{
  const float* enc     = (const float*)d_in[0];
  const int*   caps    = (const int*)d_in[1];
  const int*   cl      = (const int*)d_in[2];
  const float* emb_w   = (const float*)d_in[3];
  const float* emb_r_w = (const float*)d_in[4];
  const float* w_ih1   = (const float*)d_in[5];
  const float* w_hh1   = (const float*)d_in[6];
  const float* b_ih1   = (const float*)d_in[7];
  const float* b_hh1   = (const float*)d_in[8];
  const float* w_ih2   = (const float*)d_in[9];
  const float* w_hh2   = (const float*)d_in[10];
  const float* b_ih2   = (const float*)d_in[11];
  const float* b_hh2   = (const float*)d_in[12];
  const float* w_ihr1  = (const float*)d_in[13];
  const float* w_hhr1  = (const float*)d_in[14];
  const float* b_ihr1  = (const float*)d_in[15];
  const float* b_hhr1  = (const float*)d_in[16];
  const float* w_ihr2  = (const float*)d_in[17];
  const float* w_hhr2  = (const float*)d_in[18];
  const float* b_ihr2  = (const float*)d_in[19];
  const float* b_hhr2  = (const float*)d_in[20];
  const float* img_f_w = (const float*)d_in[21];
  const float* img_f_b = (const float*)d_in[22];
  const float* img_b_w = (const float*)d_in[23];
  const float* img_b_b = (const float*)d_in[24];
  const float* fc_w    = (const float*)d_in[25];
  const float* fc_b    = (const float*)d_in[26];
  const float* fcr_w   = (const float*)d_in[27];
  const float* fcr_b   = (const float*)d_in[28];

  float* outF = (float*)d_out;
  const long long PRED = (long long)MR * V10K;          // 32,640,000
  float* o_caps = outF + 2 * PRED;
  float* o_capr = o_caps + B64 * T52;
  float* o_lm1  = o_capr + B64 * T52;
  float* o_ord  = o_lm1 + B64;
  // big scratch parked inside the preds region of d_out (dead before FC/zero):
  float*    xg1       = outF;                           // [2][MP][2048] compact
  ushort_t* whh1bf    = (ushort_t*)(outF + 27500000);   // 2,097,152 us each
  ushort_t* wih2Lbf   = (ushort_t*)(outF + 28600000);
  ushort_t* whh2bf    = (ushort_t*)(outF + 29700000);
  ushort_t* h1hist    = (ushort_t*)(outF + 31000000);   // [52][2][64][512] = 6.8MB
  ushort_t* wih2Ibf   = (ushort_t*)(outF + 34600000);
  ushort_t* imgwbf    = (ushort_t*)(outF + 35700000);   // [2][512][2048] bf16
  ushort_t* encbf     = (ushort_t*)(outF + 36800000);   // [128][2048] bf16
  ushort_t* imgbf     = (ushort_t*)(outF + 37000000);   // [2][128][512] bf16

  char* w = (char*)d_ws;
  auto alloc = [&](size_t bytes) -> char* {
    char* p = w; w += (bytes + 255) & ~(size_t)255; return p;
  };
  int*      order_i  = (int*)alloc(64 * 4);
  int*      lensm1_i = (int*)alloc(64 * 4);
  int*      nvtab    = (int*)alloc(64 * 4);
  int*      cumtab   = (int*)alloc(65 * 4);
  int*      rowmap   = (int*)alloc(MR * 4);
  int*      capsS    = (int*)alloc(B64 * T52 * 4);
  int*      capsRev  = (int*)alloc(B64 * T52 * 4);
  float*    biasg1   = (float*)alloc(2 * 2048 * 4);
  float*    biasg2   = (float*)alloc(2 * 2048 * 4);
  float*    xg2imgT  = (float*)alloc((size_t)2 * 2048 * 64 * 4);
  char*     stateBase = alloc(262144 + 1024);
  ushort_t* h2buf = (ushort_t*)stateBase;               // [2 pp][2 dir][64][512] bf16
  int*      slotp = (int*)(stateBase + 262144);         // 256 flags
  ushort_t* embA    = (ushort_t*)alloc((size_t)2 * MP * 512 * 2);
  ushort_t* wih1bf  = (ushort_t*)alloc((size_t)2 * 2048 * 512 * 2);
  ushort_t* fcwbf   = (ushort_t*)alloc((size_t)2 * NPFC * 512 * 2);
  ushort_t* h2allbf = (ushort_t*)alloc((size_t)2 * MP * 512 * 2);

  hipMemsetAsync(stateBase, 0, 262144 + 1024, stream);
  hipMemsetAsync(h1hist, 0, 131072, stream);   // slot 0 = h1(-1) = zeros

  k_prep<<<1, 64, 0, stream>>>(cl, caps, o_caps, o_capr, o_lm1, o_ord,
                               order_i, lensm1_i, nvtab, capsS, capsRev,
                               cumtab, rowmap);
  k_convert<<<13024, 256, 0, stream>>>(w_ih1, w_ihr1, fc_w, fcr_w,
                                       b_ih1, b_hh1, b_ihr1, b_hhr1,
                                       w_hh1, w_hhr1, w_ih2, w_ihr2, w_hh2, w_hhr2,
                                       img_f_w, img_b_w, b_ih2, b_hh2, b_ihr2, b_hhr2,
                                       enc, order_i, emb_w, emb_r_w,
                                       capsS, capsRev, rowmap, cumtab,
                                       wih1bf, fcwbf, whh1bf, wih2Lbf, whh2bf,
                                       wih2Ibf, imgwbf, encbf, embA, biasg1, biasg2);
  // img = enc @ imgw^T + b  (bf16 out, [2][128][512])
  k_gemm<3><<<dim3(1, 4, 2), 256, 0, stream>>>(encbf, 0LL,
                                               imgwbf, 512LL * 2048,
                                               img_f_b, img_b_b,
                                               imgbf, 128LL * 512,
                                               512, 2048, nullptr);
  // xg2imgT[j][b] = wih2I[j] . img[b] + biasg2[j]   ([2][2048][64] fp32)
  k_gemm<2><<<dim3(16, 1, 2), 256, 0, stream>>>(wih2Ibf, 2048LL * 512,
                                                imgbf, 128LL * 512,
                                                biasg2, biasg2 + 2048,
                                                xg2imgT, 2048LL * 64,
                                                64, 512, nullptr);
  // xg1 [dir][compact c][2048] fp32 (early-exit on tm >= Mc)
  k_gemm<0><<<dim3(26, 16, 2), 256, 0, stream>>>(embA, (long long)MP * 512,
                                                 wih1bf, 2048LL * 512,
                                                 biasg1, biasg1 + 2048,
                                                 xg1, (long long)MP * 2048,
                                                 2048, 512, cumtab);
  k_rec<<<256, 128, 0, stream>>>(whh1bf, wih2Lbf, whh2bf, xg1, xg2imgT,
                                 h1hist, h2buf, h2allbf, nvtab, cumtab, slotp);
  k_zero<<<MR, 256, 0, stream>>>(outF, lensm1_i);
  k_fc<<<dim3(26, 79, 2), 256, 0, stream>>>(h2allbf, fcwbf, fc_b, fcr_b,
                                            outF, rowmap, cumtab);
}

// Round 13
// 697.366 us; speedup vs baseline: 1.3324x; 1.3324x over previous
//
#include <hip/hip_runtime.h>
#include <stdint.h>

#define B64   64
#define T52   52
#define TD    51
#define V10K  10000
#define MP    3328   // padded M = 26*128
#define MR    3264   // real M = 64*51
#define NPFC  10112  // padded V = 79*128

typedef float  f32x4  __attribute__((ext_vector_type(4)));
typedef __bf16 bf16x8 __attribute__((ext_vector_type(8)));
typedef unsigned int u32x4 __attribute__((ext_vector_type(4)));
typedef unsigned short ushort_t;

__device__ inline unsigned short f2bf(float f) {
  unsigned u = __builtin_bit_cast(unsigned, f);
  u += 0x7fffu + ((u >> 16) & 1u);
  return (unsigned short)(u >> 16);
}
__device__ inline unsigned pack2(float a, float b) {
  return (unsigned)f2bf(a) | ((unsigned)f2bf(b) << 16);
}
__device__ inline float sigm(float x) { return 1.f / (1.f + expf(-x)); }

// MALL write-through 2B store (agent scope)
__device__ inline void store2_sc(ushort_t* p, unsigned v) {
  asm volatile("global_store_short %0, %1, off sc1" :: "v"(p), "v"(v) : "memory");
}
// 16 x 16B sc1 loads + single wait
__device__ inline void loadA16(const ushort_t* a, u32x4 (&h)[16]) {
  asm volatile(
    "global_load_dwordx4 %0,  %16, off sc1\n\t"
    "global_load_dwordx4 %1,  %16, off offset:64 sc1\n\t"
    "global_load_dwordx4 %2,  %16, off offset:128 sc1\n\t"
    "global_load_dwordx4 %3,  %16, off offset:192 sc1\n\t"
    "global_load_dwordx4 %4,  %16, off offset:256 sc1\n\t"
    "global_load_dwordx4 %5,  %16, off offset:320 sc1\n\t"
    "global_load_dwordx4 %6,  %16, off offset:384 sc1\n\t"
    "global_load_dwordx4 %7,  %16, off offset:448 sc1\n\t"
    "global_load_dwordx4 %8,  %16, off offset:512 sc1\n\t"
    "global_load_dwordx4 %9,  %16, off offset:576 sc1\n\t"
    "global_load_dwordx4 %10, %16, off offset:640 sc1\n\t"
    "global_load_dwordx4 %11, %16, off offset:704 sc1\n\t"
    "global_load_dwordx4 %12, %16, off offset:768 sc1\n\t"
    "global_load_dwordx4 %13, %16, off offset:832 sc1\n\t"
    "global_load_dwordx4 %14, %16, off offset:896 sc1\n\t"
    "global_load_dwordx4 %15, %16, off offset:960 sc1\n\t"
    "s_waitcnt vmcnt(0)"
    : "=&v"(h[0]),"=&v"(h[1]),"=&v"(h[2]),"=&v"(h[3]),
      "=&v"(h[4]),"=&v"(h[5]),"=&v"(h[6]),"=&v"(h[7]),
      "=&v"(h[8]),"=&v"(h[9]),"=&v"(h[10]),"=&v"(h[11]),
      "=&v"(h[12]),"=&v"(h[13]),"=&v"(h[14]),"=&v"(h[15])
    : "v"(a) : "memory");
}
// 32 x 16B sc1 loads from two bases + single wait
__device__ inline void loadA32(const ushort_t* a, const ushort_t* b,
                               u32x4 (&ha)[16], u32x4 (&hb)[16]) {
  asm volatile(
    "global_load_dwordx4 %0,  %32, off sc1\n\t"
    "global_load_dwordx4 %1,  %32, off offset:64 sc1\n\t"
    "global_load_dwordx4 %2,  %32, off offset:128 sc1\n\t"
    "global_load_dwordx4 %3,  %32, off offset:192 sc1\n\t"
    "global_load_dwordx4 %4,  %32, off offset:256 sc1\n\t"
    "global_load_dwordx4 %5,  %32, off offset:320 sc1\n\t"
    "global_load_dwordx4 %6,  %32, off offset:384 sc1\n\t"
    "global_load_dwordx4 %7,  %32, off offset:448 sc1\n\t"
    "global_load_dwordx4 %8,  %32, off offset:512 sc1\n\t"
    "global_load_dwordx4 %9,  %32, off offset:576 sc1\n\t"
    "global_load_dwordx4 %10, %32, off offset:640 sc1\n\t"
    "global_load_dwordx4 %11, %32, off offset:704 sc1\n\t"
    "global_load_dwordx4 %12, %32, off offset:768 sc1\n\t"
    "global_load_dwordx4 %13, %32, off offset:832 sc1\n\t"
    "global_load_dwordx4 %14, %32, off offset:896 sc1\n\t"
    "global_load_dwordx4 %15, %32, off offset:960 sc1\n\t"
    "global_load_dwordx4 %16, %33, off sc1\n\t"
    "global_load_dwordx4 %17, %33, off offset:64 sc1\n\t"
    "global_load_dwordx4 %18, %33, off offset:128 sc1\n\t"
    "global_load_dwordx4 %19, %33, off offset:192 sc1\n\t"
    "global_load_dwordx4 %20, %33, off offset:256 sc1\n\t"
    "global_load_dwordx4 %21, %33, off offset:320 sc1\n\t"
    "global_load_dwordx4 %22, %33, off offset:384 sc1\n\t"
    "global_load_dwordx4 %23, %33, off offset:448 sc1\n\t"
    "global_load_dwordx4 %24, %33, off offset:512 sc1\n\t"
    "global_load_dwordx4 %25, %33, off offset:576 sc1\n\t"
    "global_load_dwordx4 %26, %33, off offset:640 sc1\n\t"
    "global_load_dwordx4 %27, %33, off offset:704 sc1\n\t"
    "global_load_dwordx4 %28, %33, off offset:768 sc1\n\t"
    "global_load_dwordx4 %29, %33, off offset:832 sc1\n\t"
    "global_load_dwordx4 %30, %33, off offset:896 sc1\n\t"
    "global_load_dwordx4 %31, %33, off offset:960 sc1\n\t"
    "s_waitcnt vmcnt(0)"
    : "=&v"(ha[0]),"=&v"(ha[1]),"=&v"(ha[2]),"=&v"(ha[3]),
      "=&v"(ha[4]),"=&v"(ha[5]),"=&v"(ha[6]),"=&v"(ha[7]),
      "=&v"(ha[8]),"=&v"(ha[9]),"=&v"(ha[10]),"=&v"(ha[11]),
      "=&v"(ha[12]),"=&v"(ha[13]),"=&v"(ha[14]),"=&v"(ha[15]),
      "=&v"(hb[0]),"=&v"(hb[1]),"=&v"(hb[2]),"=&v"(hb[3]),
      "=&v"(hb[4]),"=&v"(hb[5]),"=&v"(hb[6]),"=&v"(hb[7]),
      "=&v"(hb[8]),"=&v"(hb[9]),"=&v"(hb[10]),"=&v"(hb[11]),
      "=&v"(hb[12]),"=&v"(hb[13]),"=&v"(hb[14]),"=&v"(hb[15])
    : "v"(a), "v"(b) : "memory");
}

// ---------------- prep ------------------------------------------------------
__global__ void k_prep(const int* __restrict__ cl, const int* __restrict__ caps,
                       float* __restrict__ out_caps, float* __restrict__ out_capr,
                       float* __restrict__ out_lm1, float* __restrict__ out_ord,
                       int* __restrict__ order_i, int* __restrict__ lensm1_i,
                       int* __restrict__ nvtab, int* __restrict__ capsS,
                       int* __restrict__ capsRev, int* __restrict__ cumtab,
                       int* __restrict__ rowmap)
{
  __shared__ int L[64], O[64], Ls_s[64], Cum[65];
  __shared__ int C_s[64][T52];
  int i = threadIdx.x;
  L[i] = cl[i];
  __syncthreads();
  if (i == 0) {
    for (int a = 0; a < 64; ++a) O[a] = a;
    for (int a = 1; a < 64; ++a) {
      int key = O[a], kl = L[key], b = a - 1;
      while (b >= 0 && L[O[b]] < kl) { O[b + 1] = O[b]; --b; }
      O[b + 1] = key;
    }
  }
  __syncthreads();
  int src = O[i];
  int Ls  = L[src];
  Ls_s[i] = Ls;
  order_i[i]  = src;
  lensm1_i[i] = Ls - 1;
  out_lm1[i]  = (float)(Ls - 1);
  out_ord[i]  = (float)src;
  for (int t = 0; t < T52; ++t) {
    int c = caps[src * T52 + t];
    C_s[i][t] = c;
    capsS[i * T52 + t]    = c;
    out_caps[i * T52 + t] = (float)c;
  }
  __syncthreads();
  for (int j = 0; j < T52; ++j) {
    int rv = (j < Ls) ? C_s[i][Ls - 1 - j] : 0;
    capsRev[i * T52 + j]  = rv;
    out_capr[i * T52 + j] = (float)rv;
  }
  if (i == 0) {
    int s = 0;
    for (int b = 0; b < 64; ++b) { Cum[b] = s; s += Ls_s[b] - 1; }
    Cum[64] = s;
  }
  __syncthreads();
  cumtab[i] = Cum[i];
  if (i == 0) cumtab[64] = Cum[64];
  // full permutation rowmap: [0,Mc) = valid rows, [Mc,MR) = invalid rows
  for (int t = 0; t < Ls - 1; ++t) rowmap[Cum[i] + t] = i * TD + t;
  {
    int Mc = Cum[64];
    int invBase = Mc + i * TD - Cum[i];
    for (int t = Ls - 1; t < TD; ++t)
      rowmap[invBase + (t - (Ls - 1))] = i * TD + t;
  }
  if (i < TD) {
    int nv = 0;
    for (int r = 0; r < 64; ++r) nv += (Ls_s[r] - 1 > i) ? 1 : 0;
    nvtab[i] = nv;
  }
}

// ------- convert weights to bf16 + bias sums + img operands + emb gather ----
__global__ void k_convert(const float* __restrict__ w_ih1, const float* __restrict__ w_ihr1,
                          const float* __restrict__ fc_w, const float* __restrict__ fcr_w,
                          const float* __restrict__ b_ih1, const float* __restrict__ b_hh1,
                          const float* __restrict__ b_ihr1, const float* __restrict__ b_hhr1,
                          const float* __restrict__ w_hh1, const float* __restrict__ w_hhr1,
                          const float* __restrict__ w_ih2, const float* __restrict__ w_ihr2,
                          const float* __restrict__ w_hh2, const float* __restrict__ w_hhr2,
                          const float* __restrict__ img_f_w, const float* __restrict__ img_b_w,
                          const float* __restrict__ b_ih2, const float* __restrict__ b_hh2,
                          const float* __restrict__ b_ihr2, const float* __restrict__ b_hhr2,
                          const float* __restrict__ enc, const int* __restrict__ order_i,
                          const float* __restrict__ emb_w, const float* __restrict__ emb_r_w,
                          const int* __restrict__ capsS, const int* __restrict__ capsRev,
                          const int* __restrict__ rowmap, const int* __restrict__ cumtab,
                          ushort_t* __restrict__ wih1bf, ushort_t* __restrict__ fcwbf,
                          ushort_t* __restrict__ whh1bf, ushort_t* __restrict__ wih2Lbf,
                          ushort_t* __restrict__ whh2bf, ushort_t* __restrict__ wih2Ibf,
                          ushort_t* __restrict__ imgwbf, ushort_t* __restrict__ encbf,
                          ushort_t* __restrict__ embA,
                          float* __restrict__ biasg1, float* __restrict__ biasg2)
{
  long long gid = (long long)blockIdx.x * blockDim.x + threadIdx.x;
  const long long C1 = 2048LL * 512 / 8;          // 131072
  const long long CF = (long long)NPFC * 512 / 8; // 647168
  const long long CPD = (long long)MP * 512 / 8;  // 212992
  const long long bs  = 2 * C1 + 2 * CF;
  const long long bs2 = bs + 6 * C1;
  const long long bs3 = bs2 + 2 * C1;   // wih2Ibf
  const long long bs4 = bs3 + 2 * C1;   // imgwbf
  const long long bs5 = bs4 + 32768;    // encbf
  const long long bs6 = bs5 + 2 * CPD;  // embA
  if (gid < 2 * C1) {
    int dir = gid >= C1; long long cid = gid - (long long)dir * C1;
    const float* s = (dir ? w_ihr1 : w_ih1) + cid * 8;
    ushort_t* d = wih1bf + (long long)dir * 2048 * 512 + cid * 8;
    uint4 v;
    v.x = pack2(s[0], s[1]); v.y = pack2(s[2], s[3]);
    v.z = pack2(s[4], s[5]); v.w = pack2(s[6], s[7]);
    *(uint4*)d = v;
  } else if (gid < bs) {
    long long g2 = gid - 2 * C1; int dir = g2 >= CF;
    long long cid = g2 - (long long)dir * CF;
    long long row = cid >> 6; int k8 = (int)(cid & 63) * 8;
    ushort_t* d = fcwbf + (long long)dir * NPFC * 512 + row * 512 + k8;
    uint4 v;
    if (row < V10K) {
      const float* s = (dir ? fcr_w : fc_w) + row * 512 + k8;
      v.x = pack2(s[0], s[1]); v.y = pack2(s[2], s[3]);
      v.z = pack2(s[4], s[5]); v.w = pack2(s[6], s[7]);
    } else { v.x = v.y = v.z = v.w = 0u; }
    *(uint4*)d = v;
  } else if (gid < bs2) {
    long long e = gid - bs;
    int arr = (int)(e / (2 * C1));
    long long d2 = e - (long long)arr * 2 * C1;
    int dir = d2 >= C1;
    long long cid = d2 - (long long)dir * C1;
    long long row = cid >> 6; int k8 = (int)(cid & 63) * 8;
    const float* s;
    ushort_t* d;
    if (arr == 0)      { s = (dir ? w_hhr1 : w_hh1) + row * 512  + k8; d = whh1bf; }
    else if (arr == 1) { s = (dir ? w_ihr2 : w_ih2) + row * 1024 + k8; d = wih2Lbf; }
    else               { s = (dir ? w_hhr2 : w_hh2) + row * 512  + k8; d = whh2bf; }
    d += (long long)dir * 2048 * 512 + cid * 8;
    uint4 v;
    v.x = pack2(s[0], s[1]); v.y = pack2(s[2], s[3]);
    v.z = pack2(s[4], s[5]); v.w = pack2(s[6], s[7]);
    *(uint4*)d = v;
  } else if (gid < bs3) {
    long long e = gid - bs2; int dir = e >= C1;
    long long cid = e - (long long)dir * C1;
    long long row = cid >> 6; int k8 = (int)(cid & 63) * 8;
    const float* s = (dir ? w_ihr2 : w_ih2) + row * 1024 + 512 + k8;
    ushort_t* d = wih2Ibf + (long long)dir * 2048 * 512 + cid * 8;
    uint4 v;
    v.x = pack2(s[0], s[1]); v.y = pack2(s[2], s[3]);
    v.z = pack2(s[4], s[5]); v.w = pack2(s[6], s[7]);
    *(uint4*)d = v;
  } else if (gid < bs4) {
    long long e = gid - bs3; int dir = e >= C1;
    long long cid = e - (long long)dir * C1;
    long long row = cid >> 8; int c8 = (int)(cid & 255) * 8;
    const float* s = (dir ? img_b_w : img_f_w) + row * 2048 + c8;
    ushort_t* d = imgwbf + (long long)dir * 512 * 2048 + cid * 8;
    uint4 v;
    v.x = pack2(s[0], s[1]); v.y = pack2(s[2], s[3]);
    v.z = pack2(s[4], s[5]); v.w = pack2(s[6], s[7]);
    *(uint4*)d = v;
  } else if (gid < bs5) {
    long long cid = gid - bs4;
    int m = (int)(cid >> 8); int c8 = (int)(cid & 255) * 8;
    const float* s = enc + (long long)order_i[m & 63] * 2048 + c8;
    ushort_t* d = encbf + cid * 8;
    uint4 v;
    v.x = pack2(s[0], s[1]); v.y = pack2(s[2], s[3]);
    v.z = pack2(s[4], s[5]); v.w = pack2(s[6], s[7]);
    *(uint4*)d = v;
  } else if (gid < bs6) {
    long long e = gid - bs5;
    int dir = e >= CPD; long long cid = e - (long long)dir * CPD;
    int c = (int)(cid >> 6); int k8 = (int)(cid & 63) * 8;
    ushort_t* d = embA + (long long)dir * MP * 512 + (long long)c * 512 + k8;
    uint4 v;
    if (c < cumtab[64]) {
      int m = rowmap[c];
      int b = m / TD, t = m - b * TD;
      int row = dir ? capsRev[b * T52 + t] : capsS[b * T52 + t];
      const float* s = (dir ? emb_r_w : emb_w) + (long long)row * 512 + k8;
      v.x = pack2(s[0], s[1]); v.y = pack2(s[2], s[3]);
      v.z = pack2(s[4], s[5]); v.w = pack2(s[6], s[7]);
    } else { v.x = v.y = v.z = v.w = 0u; }
    *(uint4*)d = v;
  } else {
    long long g3 = gid - bs6;
    if (g3 < 4096) {
      int dir = g3 >= 2048; int j = (int)(g3 & 2047);
      biasg1[dir * 2048 + j] = dir ? (b_ihr1[j] + b_hhr1[j]) : (b_ih1[j] + b_hh1[j]);
    } else if (g3 < 8192) {
      long long g4 = g3 - 4096;
      int dir = g4 >= 2048; int j = (int)(g4 & 2047);
      biasg2[dir * 2048 + j] = dir ? (b_ihr2[j] + b_hhr2[j]) : (b_ih2[j] + b_hh2[j]);
    }
  }
}

// ---------------- bf16 MFMA GEMM (r10 BK=32): C[m][n] = sum_k A[m][k]*B[n][k]
// MODE 0: fp32 out, no guards, +bias[n]  (mlim: early-exit on tm >= mlim[64])
// MODE 2: fp32 out, n<Nreal guard, +bias[m]
// MODE 3: bf16 out, no guards, +bias[n]
template<int MODE>
__global__ __launch_bounds__(256)
void k_gemm(const ushort_t* __restrict__ A0, long long As,
            const ushort_t* __restrict__ B0, long long Bs,
            const float* __restrict__ bias0, const float* __restrict__ bias1,
            void* __restrict__ out0, long long Os,
            int Nreal, int K, const int* __restrict__ mlim)
{
  long long tm = (long long)blockIdx.x * 128;
  if (mlim && tm >= mlim[64]) return;
  __shared__ ushort_t Ab[128 * 32];
  __shared__ ushort_t Bb[128 * 32];
  int dirz = blockIdx.z;
  const ushort_t* A = A0 + dirz * As;
  const ushort_t* Bm = B0 + dirz * Bs;
  const float* bias = dirz ? bias1 : bias0;
  int tid = threadIdx.x;
  int lane = tid & 63, wid = tid >> 6;
  int wr = wid >> 1, wc = wid & 1;
  long long tn = (long long)blockIdx.y * 128;
  f32x4 acc[4][4] = {};
  int c0 = tid, c1 = tid + 256;
  const ushort_t* Ag0 = A + (tm + (c0 >> 2)) * K + (c0 & 3) * 8;
  const ushort_t* Ag1 = A + (tm + (c1 >> 2)) * K + (c1 & 3) * 8;
  const ushort_t* Bg0 = Bm + (tn + (c0 >> 2)) * K + (c0 & 3) * 8;
  const ushort_t* Bg1 = Bm + (tn + (c1 >> 2)) * K + (c1 & 3) * 8;
  int KK = K >> 5;
  for (int kk = 0; kk < KK; ++kk) {
    uint4 va0 = *(const uint4*)(Ag0 + kk * 32);
    uint4 va1 = *(const uint4*)(Ag1 + kk * 32);
    uint4 vb0 = *(const uint4*)(Bg0 + kk * 32);
    uint4 vb1 = *(const uint4*)(Bg1 + kk * 32);
    __syncthreads();
    *(uint4*)&Ab[c0 * 8] = va0;
    *(uint4*)&Ab[c1 * 8] = va1;
    *(uint4*)&Bb[c0 * 8] = vb0;
    *(uint4*)&Bb[c1 * 8] = vb1;
    __syncthreads();
    int koff = (lane >> 4) * 8;
    bf16x8 av[4], bv[4];
    #pragma unroll
    for (int mi = 0; mi < 4; ++mi)
      av[mi] = *(const bf16x8*)&Ab[(wr * 64 + mi * 16 + (lane & 15)) * 32 + koff];
    #pragma unroll
    for (int ni = 0; ni < 4; ++ni)
      bv[ni] = *(const bf16x8*)&Bb[(wc * 64 + ni * 16 + (lane & 15)) * 32 + koff];
    #pragma unroll
    for (int mi = 0; mi < 4; ++mi)
      #pragma unroll
      for (int ni = 0; ni < 4; ++ni)
        acc[mi][ni] = __builtin_amdgcn_mfma_f32_16x16x32_bf16(av[mi], bv[ni], acc[mi][ni], 0, 0, 0);
  }
  #pragma unroll
  for (int mi = 0; mi < 4; ++mi) {
    #pragma unroll
    for (int rr = 0; rr < 4; ++rr) {
      long long m = tm + wr * 64 + mi * 16 + ((lane >> 4) * 4) + rr;
      if (MODE == 0) {
        float* orow = (float*)out0 + dirz * Os + m * (long long)Nreal;
        #pragma unroll
        for (int ni = 0; ni < 4; ++ni) {
          int n = (int)tn + wc * 64 + ni * 16 + (lane & 15);
          orow[n] = acc[mi][ni][rr] + bias[n];
        }
      } else if (MODE == 2) {
        float bm = bias[m];
        float* orow = (float*)out0 + dirz * Os + m * (long long)Nreal;
        #pragma unroll
        for (int ni = 0; ni < 4; ++ni) {
          int n = (int)tn + wc * 64 + ni * 16 + (lane & 15);
          if (n < Nreal) orow[n] = acc[mi][ni][rr] + bm;
        }
      } else {
        ushort_t* orow = (ushort_t*)out0 + dirz * Os + m * (long long)Nreal;
        #pragma unroll
        for (int ni = 0; ni < 4; ++ni) {
          int n = (int)tn + wc * 64 + ni * 16 + (lane & 15);
          orow[n] = f2bf(acc[mi][ni][rr] + bias[n]);
        }
      }
    }
  }
}

// ------- FC on compacted rows (r10 BK=32) + fused zero-fill of invalid rows -
// rowmap is a FULL permutation: [0,Mc) valid rows, [Mc,MR) invalid rows.
__global__ __launch_bounds__(256)
void k_fc(const ushort_t* __restrict__ A0, const ushort_t* __restrict__ B0,
          const float* __restrict__ bias0, const float* __restrict__ bias1,
          float* __restrict__ out0, const int* __restrict__ rowmap,
          const int* __restrict__ cumtab)
{
  const long long PRED = (long long)MR * V10K;
  int Mc = cumtab[64];
  long long tm = (long long)blockIdx.x * 128;
  int dirz = blockIdx.z;
  long long tn = (long long)blockIdx.y * 128;
  float* out = out0 + (long long)dirz * PRED;
  int tid = threadIdx.x;
  if (tm >= Mc) {
    // pure zero tile: 2 threads/row, float4 stores (V10K % 4 == 0)
    int row = tid >> 1, hf = tid & 1;
    long long c = tm + row;
    if (c < MR) {
      int m = rowmap[c];
      float* orow = out + (long long)m * V10K;
      float4 z = {0.f, 0.f, 0.f, 0.f};
      int col0 = (int)tn + hf * 64;
      #pragma unroll
      for (int q = 0; q < 16; ++q) {
        int col = col0 + q * 4;
        if (col < V10K) *(float4*)(orow + col) = z;
      }
    }
    return;
  }
  __shared__ ushort_t Ab[128 * 32];
  __shared__ ushort_t Bb[128 * 32];
  const ushort_t* A = A0 + (long long)dirz * MP * 512;
  const ushort_t* Bm = B0 + (long long)dirz * NPFC * 512;
  const float* bias = dirz ? bias1 : bias0;
  int lane = tid & 63, wid = tid >> 6;
  int wr = wid >> 1, wc = wid & 1;
  f32x4 acc[4][4] = {};
  int c0 = tid, c1 = tid + 256;
  const ushort_t* Ag0 = A + (tm + (c0 >> 2)) * 512 + (c0 & 3) * 8;
  const ushort_t* Ag1 = A + (tm + (c1 >> 2)) * 512 + (c1 & 3) * 8;
  const ushort_t* Bg0 = Bm + (tn + (c0 >> 2)) * 512 + (c0 & 3) * 8;
  const ushort_t* Bg1 = Bm + (tn + (c1 >> 2)) * 512 + (c1 & 3) * 8;
  for (int kk = 0; kk < 16; ++kk) {
    uint4 va0 = *(const uint4*)(Ag0 + kk * 32);
    uint4 va1 = *(const uint4*)(Ag1 + kk * 32);
    uint4 vb0 = *(const uint4*)(Bg0 + kk * 32);
    uint4 vb1 = *(const uint4*)(Bg1 + kk * 32);
    __syncthreads();
    *(uint4*)&Ab[c0 * 8] = va0;
    *(uint4*)&Ab[c1 * 8] = va1;
    *(uint4*)&Bb[c0 * 8] = vb0;
    *(uint4*)&Bb[c1 * 8] = vb1;
    __syncthreads();
    int koff = (lane >> 4) * 8;
    bf16x8 av[4], bv[4];
    #pragma unroll
    for (int mi = 0; mi < 4; ++mi)
      av[mi] = *(const bf16x8*)&Ab[(wr * 64 + mi * 16 + (lane & 15)) * 32 + koff];
    #pragma unroll
    for (int ni = 0; ni < 4; ++ni)
      bv[ni] = *(const bf16x8*)&Bb[(wc * 64 + ni * 16 + (lane & 15)) * 32 + koff];
    #pragma unroll
    for (int mi = 0; mi < 4; ++mi)
      #pragma unroll
      for (int ni = 0; ni < 4; ++ni)
        acc[mi][ni] = __builtin_amdgcn_mfma_f32_16x16x32_bf16(av[mi], bv[ni], acc[mi][ni], 0, 0, 0);
  }
  #pragma unroll
  for (int mi = 0; mi < 4; ++mi) {
    #pragma unroll
    for (int rr = 0; rr < 4; ++rr) {
      long long c = tm + wr * 64 + mi * 16 + ((lane >> 4) * 4) + rr;
      if (c < MR) {
        int m = rowmap[c];
        bool val = (c < Mc);
        float* orow = out + (long long)m * V10K;
        #pragma unroll
        for (int ni = 0; ni < 4; ++ni) {
          int n = (int)tn + wc * 64 + ni * 16 + (lane & 15);
          if (n < V10K) orow[n] = val ? (acc[mi][ni][rr] + bias[n]) : 0.f;
        }
      }
    }
  }
}

// ---------------- persistent recurrent kernel (r10 structure, verbatim) -----
// bid 0..127:   L1 (idx=bid:     dir=idx>>6, half=(idx&63)>>5, ht=idx&31)
// bid 128..255: L2 (idx=bid-128: same decomposition)
// 128 threads (2 waves), both waves compute 16 rows each.
// Single combined poll per step (proven in r10; split polls regress).
__global__ __launch_bounds__(128, 1)
void k_rec(const ushort_t* __restrict__ whh1bf, const ushort_t* __restrict__ wih2Lbf,
           const ushort_t* __restrict__ whh2bf, const float* __restrict__ xg1,
           const float* __restrict__ xg2imgT,
           ushort_t* __restrict__ h1hist,   // [52][2][64][512] bf16; slot0 = zeros
           ushort_t* __restrict__ h2buf,    // [2][2][64][512]  (ping-pong, zeroed)
           ushort_t* __restrict__ h2allbf,  // [dir][compact c][512]
           const int* __restrict__ nvtab, const int* __restrict__ cumtab,
           int* __restrict__ slots)         // [0..127]=aS (4 grp x32), [128..255]=bS
{
  const int bid = blockIdx.x;
  const bool isL2 = bid >= 128;
  const int idx = isL2 ? bid - 128 : bid;
  const int dir = idx >> 6, sub = idx & 63, half = sub >> 5, ht = sub & 31;
  const int tid = threadIdx.x;          // 0..127
  const int lane = tid & 63, mt = tid >> 6;
  const int l15 = lane & 15, l4 = lane >> 4;
  const int jl = ht * 16 + l15;
  const int rbase = half * 32 + mt * 16;
  const int r0 = rbase + l4 * 4;

  __shared__ ushort_t Wl[32768];  // 64KB [4 gates][16 cols][512 k] XOR-swizzled
  __shared__ ushort_t Wi[32768];  // 64KB wih2 h1-part (L2 only)
  __shared__ int nv_s[64];
  __shared__ int cum_s[64];

  {
    const ushort_t* src = (isL2 ? whh2bf : whh1bf) + (long long)dir * 2048 * 512;
    #pragma unroll
    for (int i = 0; i < 32; ++i) {
      int c = tid + i * 128;
      int nl = c >> 6;
      int kb = (c & 63) * 16;
      int row = (nl >> 4) * 512 + ht * 16 + (nl & 15);
      u32x4 v = *(const u32x4*)(src + (long long)row * 512 + (long long)(c & 63) * 8);
      *(u32x4*)((char*)Wl + nl * 1024 + (kb ^ ((nl & 7) << 4))) = v;
    }
    if (isL2) {
      const ushort_t* src2 = wih2Lbf + (long long)dir * 2048 * 512;
      #pragma unroll
      for (int i = 0; i < 32; ++i) {
        int c = tid + i * 128;
        int nl = c >> 6;
        int kb = (c & 63) * 16;
        int row = (nl >> 4) * 512 + ht * 16 + (nl & 15);
        u32x4 v = *(const u32x4*)(src2 + (long long)row * 512 + (long long)(c & 63) * 8);
        *(u32x4*)((char*)Wi + nl * 1024 + (kb ^ ((nl & 7) << 4))) = v;
      }
    }
    if (tid < TD) nv_s[tid] = nvtab[tid];
    if (tid < 64) cum_s[tid] = cumtab[tid];
  }
  __syncthreads();

  int* aS = slots + (dir * 2 + half) * 32;
  int* bS = slots + 128 + (dir * 2 + half) * 32;

  if (!isL2) {
    // ---------------- L1 pipeline (2 waves x 16 rows) ----------------
    f32x4 creg = {0.f, 0.f, 0.f, 0.f};
    for (int t = 0; t < TD; ++t) {
      bool act = (rbase < nv_s[t]);
      // x-gate loads (h-independent, compacted xg1): issue before the poll
      float xs[4][4];
      if (act) {
        const float* xb = xg1 + (long long)dir * MP * 2048;
        #pragma unroll
        for (int rr = 0; rr < 4; ++rr) {
          const float* xr = xb + (long long)(cum_s[r0 + rr] + t) * 2048;
          #pragma unroll
          for (int g = 0; g < 4; ++g)
            xs[g][rr] = xr[g * 512 + jl];
        }
      }
      if (t > 0) {
        if (mt == 0) {
          for (;;) {
            int v = __hip_atomic_load(&aS[lane & 31], __ATOMIC_RELAXED, __HIP_MEMORY_SCOPE_AGENT);
            if (__all(v >= t)) break;
          }
        }
        __syncthreads();
      }
      if (act) {
        const ushort_t* hsrc = h1hist + ((long long)t * 2 + dir) * (64 * 512);
        u32x4 hv[16];
        loadA16(hsrc + (long long)(rbase + l15) * 512 + l4 * 8, hv);
        f32x4 acc[4] = {};
        #pragma unroll
        for (int kk = 0; kk < 16; ++kk) {
          bf16x8 av = __builtin_bit_cast(bf16x8, hv[kk]);
          int kb = kk * 64 + l4 * 16;
          #pragma unroll
          for (int g = 0; g < 4; ++g) {
            bf16x8 bv = *(const bf16x8*)((const char*)Wl + (g * 16 + l15) * 1024 + (kb ^ ((l15 & 7) << 4)));
            acc[g] = __builtin_amdgcn_mfma_f32_16x16x32_bf16(av, bv, acc[g], 0, 0, 0);
          }
        }
        ushort_t* hdst = h1hist + ((long long)(t + 1) * 2 + dir) * (64 * 512);
        f32x4 cn;
        #pragma unroll
        for (int rr = 0; rr < 4; ++rr) {
          float gi = acc[0][rr] + xs[0][rr];
          float gf = acc[1][rr] + xs[1][rr];
          float gg = acc[2][rr] + xs[2][rr];
          float go = acc[3][rr] + xs[3][rr];
          float c = sigm(gf) * creg[rr] + sigm(gi) * tanhf(gg);
          float h = sigm(go) * tanhf(c);
          cn[rr] = c;
          store2_sc(hdst + (long long)(r0 + rr) * 512 + jl, (unsigned)f2bf(h));
        }
        creg = cn;
      }
      __syncthreads();   // drains each wave's vmcnt before the slot store
      if (tid == 0)
        __hip_atomic_store(&aS[ht], t + 1, __ATOMIC_RELAXED, __HIP_MEMORY_SCOPE_AGENT);
    }
  } else {
    // ---------------- L2 pipeline (2 waves x 16 rows) ----------------
    f32x4 xv2[4];
    {
      const float* xg = xg2imgT + (long long)dir * (2048 * 64);
      #pragma unroll
      for (int g = 0; g < 4; ++g)
        xv2[g] = *(const f32x4*)(xg + (long long)(g * 512 + jl) * 64 + r0);
    }
    f32x4 creg = {0.f, 0.f, 0.f, 0.f};
    for (int t = 0; t < TD; ++t) {
      // single combined poll: h1(t) ready (aS >= t+1) AND h2(t-1) ready (bS >= t)
      if (mt == 0) {
        for (;;) {
          int va = __hip_atomic_load(&aS[lane & 31], __ATOMIC_RELAXED, __HIP_MEMORY_SCOPE_AGENT);
          int vb = __hip_atomic_load(&bS[lane & 31], __ATOMIC_RELAXED, __HIP_MEMORY_SCOPE_AGENT);
          if (__all((va >= t + 1) & (vb >= t))) break;
        }
      }
      __syncthreads();
      int nv = nv_s[t];
      if (rbase < nv) {
        const ushort_t* h1s = h1hist + ((long long)(t + 1) * 2 + dir) * (64 * 512);
        const ushort_t* h2s = h2buf + ((long long)((t + 1) & 1) * 2 + dir) * (64 * 512);
        u32x4 ha[16], hb[16];
        loadA32(h1s + (long long)(rbase + l15) * 512 + l4 * 8,
                h2s + (long long)(rbase + l15) * 512 + l4 * 8, ha, hb);
        f32x4 acc[4] = {};
        #pragma unroll
        for (int kk = 0; kk < 16; ++kk) {
          bf16x8 av = __builtin_bit_cast(bf16x8, ha[kk]);
          int kb = kk * 64 + l4 * 16;
          #pragma unroll
          for (int g = 0; g < 4; ++g) {
            bf16x8 bv = *(const bf16x8*)((const char*)Wi + (g * 16 + l15) * 1024 + (kb ^ ((l15 & 7) << 4)));
            acc[g] = __builtin_amdgcn_mfma_f32_16x16x32_bf16(av, bv, acc[g], 0, 0, 0);
          }
        }
        #pragma unroll
        for (int kk = 0; kk < 16; ++kk) {
          bf16x8 av = __builtin_bit_cast(bf16x8, hb[kk]);
          int kb = kk * 64 + l4 * 16;
          #pragma unroll
          for (int g = 0; g < 4; ++g) {
            bf16x8 bv = *(const bf16x8*)((const char*)Wl + (g * 16 + l15) * 1024 + (kb ^ ((l15 & 7) << 4)));
            acc[g] = __builtin_amdgcn_mfma_f32_16x16x32_bf16(av, bv, acc[g], 0, 0, 0);
          }
        }
        ushort_t* h2n = h2buf + ((long long)(t & 1) * 2 + dir) * (64 * 512);
        ushort_t* h2a = h2allbf + (long long)dir * MP * 512;
        f32x4 cn;
        #pragma unroll
        for (int rr = 0; rr < 4; ++rr) {
          float gi = acc[0][rr] + xv2[0][rr];
          float gf = acc[1][rr] + xv2[1][rr];
          float gg = acc[2][rr] + xv2[2][rr];
          float go = acc[3][rr] + xv2[3][rr];
          float c = sigm(gf) * creg[rr] + sigm(gi) * tanhf(gg);
          float h = sigm(go) * tanhf(c);
          cn[rr] = c;
          ushort_t hbb = f2bf(h);
          store2_sc(h2n + (long long)(r0 + rr) * 512 + jl, (unsigned)hbb);
          if (r0 + rr < nv)
            h2a[((long long)(cum_s[r0 + rr] + t)) * 512 + jl] = hbb;
        }
        creg = cn;
      }
      __syncthreads();   // drains each wave's vmcnt before the slot store
      if (tid == 0)
        __hip_atomic_store(&bS[ht], t + 1, __ATOMIC_RELAXED, __HIP_MEMORY_SCOPE_AGENT);
    }
  }
}

// ---------------------------------------------------------------------------
extern "C" void kernel_launch(void* const* d_in, const int* in_sizes, int n_in,
                              void* d_out, int out_size, void* d_ws, size_t ws_size,
                              hipStream_t stream)
{
  const float* enc     = (const float*)d_in[0];
  const int*   caps    = (const int*)d_in[1];
  const int*   cl      = (const int*)d_in[2];
  const float* emb_w   = (const float*)d_in[3];
  const float* emb_r_w = (const float*)d_in[4];
  const float* w_ih1   = (const float*)d_in[5];
  const float* w_hh1   = (const float*)d_in[6];
  const float* b_ih1   = (const float*)d_in[7];
  const float* b_hh1   = (const float*)d_in[8];
  const float* w_ih2   = (const float*)d_in[9];
  const float* w_hh2   = (const float*)d_in[10];
  const float* b_ih2   = (const float*)d_in[11];
  const float* b_hh2   = (const float*)d_in[12];
  const float* w_ihr1  = (const float*)d_in[13];
  const float* w_hhr1  = (const float*)d_in[14];
  const float* b_ihr1  = (const float*)d_in[15];
  const float* b_hhr1  = (const float*)d_in[16];
  const float* w_ihr2  = (const float*)d_in[17];
  const float* w_hhr2  = (const float*)d_in[18];
  const float* b_ihr2  = (const float*)d_in[19];
  const float* b_hhr2  = (const float*)d_in[20];
  const float* img_f_w = (const float*)d_in[21];
  const float* img_f_b = (const float*)d_in[22];
  const float* img_b_w = (const float*)d_in[23];
  const float* img_b_b = (const float*)d_in[24];
  const float* fc_w    = (const float*)d_in[25];
  const float* fc_b    = (const float*)d_in[26];
  const float* fcr_w   = (const float*)d_in[27];
  const float* fcr_b   = (const float*)d_in[28];

  float* outF = (float*)d_out;
  const long long PRED = (long long)MR * V10K;          // 32,640,000
  float* o_caps = outF + 2 * PRED;
  float* o_capr = o_caps + B64 * T52;
  float* o_lm1  = o_capr + B64 * T52;
  float* o_ord  = o_lm1 + B64;
  // big scratch parked inside the preds region of d_out (dead before FC):
  float*    xg1       = outF;                           // [2][MP][2048] compact
  ushort_t* whh1bf    = (ushort_t*)(outF + 27500000);   // 2,097,152 us each
  ushort_t* wih2Lbf   = (ushort_t*)(outF + 28600000);
  ushort_t* whh2bf    = (ushort_t*)(outF + 29700000);
  ushort_t* h1hist    = (ushort_t*)(outF + 31000000);   // [52][2][64][512] = 6.8MB
  ushort_t* wih2Ibf   = (ushort_t*)(outF + 34600000);
  ushort_t* imgwbf    = (ushort_t*)(outF + 35700000);   // [2][512][2048] bf16
  ushort_t* encbf     = (ushort_t*)(outF + 36800000);   // [128][2048] bf16
  ushort_t* imgbf     = (ushort_t*)(outF + 37000000);   // [2][128][512] bf16

  char* w = (char*)d_ws;
  auto alloc = [&](size_t bytes) -> char* {
    char* p = w; w += (bytes + 255) & ~(size_t)255; return p;
  };
  int*      order_i  = (int*)alloc(64 * 4);
  int*      lensm1_i = (int*)alloc(64 * 4);
  int*      nvtab    = (int*)alloc(64 * 4);
  int*      cumtab   = (int*)alloc(65 * 4);
  int*      rowmap   = (int*)alloc(MR * 4);
  int*      capsS    = (int*)alloc(B64 * T52 * 4);
  int*      capsRev  = (int*)alloc(B64 * T52 * 4);
  float*    biasg1   = (float*)alloc(2 * 2048 * 4);
  float*    biasg2   = (float*)alloc(2 * 2048 * 4);
  float*    xg2imgT  = (float*)alloc((size_t)2 * 2048 * 64 * 4);
  char*     stateBase = alloc(262144 + 1024);
  ushort_t* h2buf = (ushort_t*)stateBase;               // [2 pp][2 dir][64][512] bf16
  int*      slotp = (int*)(stateBase + 262144);         // 256 flags
  ushort_t* embA    = (ushort_t*)alloc((size_t)2 * MP * 512 * 2);
  ushort_t* wih1bf  = (ushort_t*)alloc((size_t)2 * 2048 * 512 * 2);
  ushort_t* fcwbf   = (ushort_t*)alloc((size_t)2 * NPFC * 512 * 2);
  ushort_t* h2allbf = (ushort_t*)alloc((size_t)2 * MP * 512 * 2);

  hipMemsetAsync(stateBase, 0, 262144 + 1024, stream);
  hipMemsetAsync(h1hist, 0, 131072, stream);   // slot 0 = h1(-1) = zeros

  k_prep<<<1, 64, 0, stream>>>(cl, caps, o_caps, o_capr, o_lm1, o_ord,
                               order_i, lensm1_i, nvtab, capsS, capsRev,
                               cumtab, rowmap);
  k_convert<<<13024, 256, 0, stream>>>(w_ih1, w_ihr1, fc_w, fcr_w,
                                       b_ih1, b_hh1, b_ihr1, b_hhr1,
                                       w_hh1, w_hhr1, w_ih2, w_ihr2, w_hh2, w_hhr2,
                                       img_f_w, img_b_w, b_ih2, b_hh2, b_ihr2, b_hhr2,
                                       enc, order_i, emb_w, emb_r_w,
                                       capsS, capsRev, rowmap, cumtab,
                                       wih1bf, fcwbf, whh1bf, wih2Lbf, whh2bf,
                                       wih2Ibf, imgwbf, encbf, embA, biasg1, biasg2);
  // img = enc @ imgw^T + b  (bf16 out, [2][128][512])
  k_gemm<3><<<dim3(1, 4, 2), 256, 0, stream>>>(encbf, 0LL,
                                               imgwbf, 512LL * 2048,
                                               img_f_b, img_b_b,
                                               imgbf, 128LL * 512,
                                               512, 2048, nullptr);
  // xg2imgT[j][b] = wih2I[j] . img[b] + biasg2[j]   ([2][2048][64] fp32)
  k_gemm<2><<<dim3(16, 1, 2), 256, 0, stream>>>(wih2Ibf, 2048LL * 512,
                                                imgbf, 128LL * 512,
                                                biasg2, biasg2 + 2048,
                                                xg2imgT, 2048LL * 64,
                                                64, 512, nullptr);
  // xg1 [dir][compact c][2048] fp32 (early-exit on tm >= Mc)
  k_gemm<0><<<dim3(26, 16, 2), 256, 0, stream>>>(embA, (long long)MP * 512,
                                                 wih1bf, 2048LL * 512,
                                                 biasg1, biasg1 + 2048,
                                                 xg1, (long long)MP * 2048,
                                                 2048, 512, cumtab);
  k_rec<<<256, 128, 0, stream>>>(whh1bf, wih2Lbf, whh2bf, xg1, xg2imgT,
                                 h1hist, h2buf, h2allbf, nvtab, cumtab, slotp);
  k_fc<<<dim3(26, 79, 2), 256, 0, stream>>>(h2allbf, fcwbf, fc_b, fcr_b,
                                            outF, rowmap, cumtab);
}

// Round 14
// 693.941 us; speedup vs baseline: 1.3389x; 1.0049x over previous
//
#include <hip/hip_runtime.h>
#include <stdint.h>

#define B64   64
#define T52   52
#define TD    51
#define V10K  10000
#define MP    3328   // padded M = 26*128
#define MR    3264   // real M = 64*51
#define NPFC  10112  // padded V = 79*128

typedef float  f32x4  __attribute__((ext_vector_type(4)));
typedef __bf16 bf16x8 __attribute__((ext_vector_type(8)));
typedef unsigned int u32x4 __attribute__((ext_vector_type(4)));
typedef unsigned short ushort_t;

__device__ inline unsigned short f2bf(float f) {
  unsigned u = __builtin_bit_cast(unsigned, f);
  u += 0x7fffu + ((u >> 16) & 1u);
  return (unsigned short)(u >> 16);
}
__device__ inline unsigned pack2(float a, float b) {
  return (unsigned)f2bf(a) | ((unsigned)f2bf(b) << 16);
}
__device__ inline float sigm(float x) { return 1.f / (1.f + expf(-x)); }

// MALL write-through 2B store (agent scope)
__device__ inline void store2_sc(ushort_t* p, unsigned v) {
  asm volatile("global_store_short %0, %1, off sc1" :: "v"(p), "v"(v) : "memory");
}
// 16 x 16B sc1 loads + single wait
__device__ inline void loadA16(const ushort_t* a, u32x4 (&h)[16]) {
  asm volatile(
    "global_load_dwordx4 %0,  %16, off sc1\n\t"
    "global_load_dwordx4 %1,  %16, off offset:64 sc1\n\t"
    "global_load_dwordx4 %2,  %16, off offset:128 sc1\n\t"
    "global_load_dwordx4 %3,  %16, off offset:192 sc1\n\t"
    "global_load_dwordx4 %4,  %16, off offset:256 sc1\n\t"
    "global_load_dwordx4 %5,  %16, off offset:320 sc1\n\t"
    "global_load_dwordx4 %6,  %16, off offset:384 sc1\n\t"
    "global_load_dwordx4 %7,  %16, off offset:448 sc1\n\t"
    "global_load_dwordx4 %8,  %16, off offset:512 sc1\n\t"
    "global_load_dwordx4 %9,  %16, off offset:576 sc1\n\t"
    "global_load_dwordx4 %10, %16, off offset:640 sc1\n\t"
    "global_load_dwordx4 %11, %16, off offset:704 sc1\n\t"
    "global_load_dwordx4 %12, %16, off offset:768 sc1\n\t"
    "global_load_dwordx4 %13, %16, off offset:832 sc1\n\t"
    "global_load_dwordx4 %14, %16, off offset:896 sc1\n\t"
    "global_load_dwordx4 %15, %16, off offset:960 sc1\n\t"
    "s_waitcnt vmcnt(0)"
    : "=&v"(h[0]),"=&v"(h[1]),"=&v"(h[2]),"=&v"(h[3]),
      "=&v"(h[4]),"=&v"(h[5]),"=&v"(h[6]),"=&v"(h[7]),
      "=&v"(h[8]),"=&v"(h[9]),"=&v"(h[10]),"=&v"(h[11]),
      "=&v"(h[12]),"=&v"(h[13]),"=&v"(h[14]),"=&v"(h[15])
    : "v"(a) : "memory");
}
// 32 x 16B sc1 loads from two bases + single wait
__device__ inline void loadA32(const ushort_t* a, const ushort_t* b,
                               u32x4 (&ha)[16], u32x4 (&hb)[16]) {
  asm volatile(
    "global_load_dwordx4 %0,  %32, off sc1\n\t"
    "global_load_dwordx4 %1,  %32, off offset:64 sc1\n\t"
    "global_load_dwordx4 %2,  %32, off offset:128 sc1\n\t"
    "global_load_dwordx4 %3,  %32, off offset:192 sc1\n\t"
    "global_load_dwordx4 %4,  %32, off offset:256 sc1\n\t"
    "global_load_dwordx4 %5,  %32, off offset:320 sc1\n\t"
    "global_load_dwordx4 %6,  %32, off offset:384 sc1\n\t"
    "global_load_dwordx4 %7,  %32, off offset:448 sc1\n\t"
    "global_load_dwordx4 %8,  %32, off offset:512 sc1\n\t"
    "global_load_dwordx4 %9,  %32, off offset:576 sc1\n\t"
    "global_load_dwordx4 %10, %32, off offset:640 sc1\n\t"
    "global_load_dwordx4 %11, %32, off offset:704 sc1\n\t"
    "global_load_dwordx4 %12, %32, off offset:768 sc1\n\t"
    "global_load_dwordx4 %13, %32, off offset:832 sc1\n\t"
    "global_load_dwordx4 %14, %32, off offset:896 sc1\n\t"
    "global_load_dwordx4 %15, %32, off offset:960 sc1\n\t"
    "global_load_dwordx4 %16, %33, off sc1\n\t"
    "global_load_dwordx4 %17, %33, off offset:64 sc1\n\t"
    "global_load_dwordx4 %18, %33, off offset:128 sc1\n\t"
    "global_load_dwordx4 %19, %33, off offset:192 sc1\n\t"
    "global_load_dwordx4 %20, %33, off offset:256 sc1\n\t"
    "global_load_dwordx4 %21, %33, off offset:320 sc1\n\t"
    "global_load_dwordx4 %22, %33, off offset:384 sc1\n\t"
    "global_load_dwordx4 %23, %33, off offset:448 sc1\n\t"
    "global_load_dwordx4 %24, %33, off offset:512 sc1\n\t"
    "global_load_dwordx4 %25, %33, off offset:576 sc1\n\t"
    "global_load_dwordx4 %26, %33, off offset:640 sc1\n\t"
    "global_load_dwordx4 %27, %33, off offset:704 sc1\n\t"
    "global_load_dwordx4 %28, %33, off offset:768 sc1\n\t"
    "global_load_dwordx4 %29, %33, off offset:832 sc1\n\t"
    "global_load_dwordx4 %30, %33, off offset:896 sc1\n\t"
    "global_load_dwordx4 %31, %33, off offset:960 sc1\n\t"
    "s_waitcnt vmcnt(0)"
    : "=&v"(ha[0]),"=&v"(ha[1]),"=&v"(ha[2]),"=&v"(ha[3]),
      "=&v"(ha[4]),"=&v"(ha[5]),"=&v"(ha[6]),"=&v"(ha[7]),
      "=&v"(ha[8]),"=&v"(ha[9]),"=&v"(ha[10]),"=&v"(ha[11]),
      "=&v"(ha[12]),"=&v"(ha[13]),"=&v"(ha[14]),"=&v"(ha[15]),
      "=&v"(hb[0]),"=&v"(hb[1]),"=&v"(hb[2]),"=&v"(hb[3]),
      "=&v"(hb[4]),"=&v"(hb[5]),"=&v"(hb[6]),"=&v"(hb[7]),
      "=&v"(hb[8]),"=&v"(hb[9]),"=&v"(hb[10]),"=&v"(hb[11]),
      "=&v"(hb[12]),"=&v"(hb[13]),"=&v"(hb[14]),"=&v"(hb[15])
    : "v"(a), "v"(b) : "memory");
}

// ---------------- prep ------------------------------------------------------
__global__ void k_prep(const int* __restrict__ cl, const int* __restrict__ caps,
                       float* __restrict__ out_caps, float* __restrict__ out_capr,
                       float* __restrict__ out_lm1, float* __restrict__ out_ord,
                       int* __restrict__ order_i, int* __restrict__ lensm1_i,
                       int* __restrict__ nvtab, int* __restrict__ capsS,
                       int* __restrict__ capsRev, int* __restrict__ cumtab,
                       int* __restrict__ rowmap)
{
  __shared__ int L[64], O[64], Ls_s[64], Cum[65];
  __shared__ int C_s[64][T52];
  int i = threadIdx.x;
  L[i] = cl[i];
  __syncthreads();
  if (i == 0) {
    for (int a = 0; a < 64; ++a) O[a] = a;
    for (int a = 1; a < 64; ++a) {
      int key = O[a], kl = L[key], b = a - 1;
      while (b >= 0 && L[O[b]] < kl) { O[b + 1] = O[b]; --b; }
      O[b + 1] = key;
    }
  }
  __syncthreads();
  int src = O[i];
  int Ls  = L[src];
  Ls_s[i] = Ls;
  order_i[i]  = src;
  lensm1_i[i] = Ls - 1;
  out_lm1[i]  = (float)(Ls - 1);
  out_ord[i]  = (float)src;
  for (int t = 0; t < T52; ++t) {
    int c = caps[src * T52 + t];
    C_s[i][t] = c;
    capsS[i * T52 + t]    = c;
    out_caps[i * T52 + t] = (float)c;
  }
  __syncthreads();
  for (int j = 0; j < T52; ++j) {
    int rv = (j < Ls) ? C_s[i][Ls - 1 - j] : 0;
    capsRev[i * T52 + j]  = rv;
    out_capr[i * T52 + j] = (float)rv;
  }
  if (i == 0) {
    int s = 0;
    for (int b = 0; b < 64; ++b) { Cum[b] = s; s += Ls_s[b] - 1; }
    Cum[64] = s;
  }
  __syncthreads();
  cumtab[i] = Cum[i];
  if (i == 0) cumtab[64] = Cum[64];
  // full permutation rowmap: [0,Mc) = valid rows, [Mc,MR) = invalid rows
  for (int t = 0; t < Ls - 1; ++t) rowmap[Cum[i] + t] = i * TD + t;
  {
    int Mc = Cum[64];
    int invBase = Mc + i * TD - Cum[i];
    for (int t = Ls - 1; t < TD; ++t)
      rowmap[invBase + (t - (Ls - 1))] = i * TD + t;
  }
  if (i < TD) {
    int nv = 0;
    for (int r = 0; r < 64; ++r) nv += (Ls_s[r] - 1 > i) ? 1 : 0;
    nvtab[i] = nv;
  }
}

// ------- convert weights to bf16 + bias sums + img operands + emb gather ----
__global__ void k_convert(const float* __restrict__ w_ih1, const float* __restrict__ w_ihr1,
                          const float* __restrict__ fc_w, const float* __restrict__ fcr_w,
                          const float* __restrict__ b_ih1, const float* __restrict__ b_hh1,
                          const float* __restrict__ b_ihr1, const float* __restrict__ b_hhr1,
                          const float* __restrict__ w_hh1, const float* __restrict__ w_hhr1,
                          const float* __restrict__ w_ih2, const float* __restrict__ w_ihr2,
                          const float* __restrict__ w_hh2, const float* __restrict__ w_hhr2,
                          const float* __restrict__ img_f_w, const float* __restrict__ img_b_w,
                          const float* __restrict__ b_ih2, const float* __restrict__ b_hh2,
                          const float* __restrict__ b_ihr2, const float* __restrict__ b_hhr2,
                          const float* __restrict__ enc, const int* __restrict__ order_i,
                          const float* __restrict__ emb_w, const float* __restrict__ emb_r_w,
                          const int* __restrict__ capsS, const int* __restrict__ capsRev,
                          const int* __restrict__ rowmap, const int* __restrict__ cumtab,
                          ushort_t* __restrict__ wih1bf, ushort_t* __restrict__ fcwbf,
                          ushort_t* __restrict__ whh1bf, ushort_t* __restrict__ wih2Lbf,
                          ushort_t* __restrict__ whh2bf, ushort_t* __restrict__ wih2Ibf,
                          ushort_t* __restrict__ imgwbf, ushort_t* __restrict__ encbf,
                          ushort_t* __restrict__ embA,
                          float* __restrict__ biasg1, float* __restrict__ biasg2)
{
  long long gid = (long long)blockIdx.x * blockDim.x + threadIdx.x;
  const long long C1 = 2048LL * 512 / 8;          // 131072
  const long long CF = (long long)NPFC * 512 / 8; // 647168
  const long long CPD = (long long)MP * 512 / 8;  // 212992
  const long long bs  = 2 * C1 + 2 * CF;
  const long long bs2 = bs + 6 * C1;
  const long long bs3 = bs2 + 2 * C1;   // wih2Ibf
  const long long bs4 = bs3 + 2 * C1;   // imgwbf
  const long long bs5 = bs4 + 32768;    // encbf
  const long long bs6 = bs5 + 2 * CPD;  // embA
  if (gid < 2 * C1) {
    int dir = gid >= C1; long long cid = gid - (long long)dir * C1;
    const float* s = (dir ? w_ihr1 : w_ih1) + cid * 8;
    ushort_t* d = wih1bf + (long long)dir * 2048 * 512 + cid * 8;
    uint4 v;
    v.x = pack2(s[0], s[1]); v.y = pack2(s[2], s[3]);
    v.z = pack2(s[4], s[5]); v.w = pack2(s[6], s[7]);
    *(uint4*)d = v;
  } else if (gid < bs) {
    long long g2 = gid - 2 * C1; int dir = g2 >= CF;
    long long cid = g2 - (long long)dir * CF;
    long long row = cid >> 6; int k8 = (int)(cid & 63) * 8;
    ushort_t* d = fcwbf + (long long)dir * NPFC * 512 + row * 512 + k8;
    uint4 v;
    if (row < V10K) {
      const float* s = (dir ? fcr_w : fc_w) + row * 512 + k8;
      v.x = pack2(s[0], s[1]); v.y = pack2(s[2], s[3]);
      v.z = pack2(s[4], s[5]); v.w = pack2(s[6], s[7]);
    } else { v.x = v.y = v.z = v.w = 0u; }
    *(uint4*)d = v;
  } else if (gid < bs2) {
    long long e = gid - bs;
    int arr = (int)(e / (2 * C1));
    long long d2 = e - (long long)arr * 2 * C1;
    int dir = d2 >= C1;
    long long cid = d2 - (long long)dir * C1;
    long long row = cid >> 6; int k8 = (int)(cid & 63) * 8;
    const float* s;
    ushort_t* d;
    if (arr == 0)      { s = (dir ? w_hhr1 : w_hh1) + row * 512  + k8; d = whh1bf; }
    else if (arr == 1) { s = (dir ? w_ihr2 : w_ih2) + row * 1024 + k8; d = wih2Lbf; }
    else               { s = (dir ? w_hhr2 : w_hh2) + row * 512  + k8; d = whh2bf; }
    d += (long long)dir * 2048 * 512 + cid * 8;
    uint4 v;
    v.x = pack2(s[0], s[1]); v.y = pack2(s[2], s[3]);
    v.z = pack2(s[4], s[5]); v.w = pack2(s[6], s[7]);
    *(uint4*)d = v;
  } else if (gid < bs3) {
    long long e = gid - bs2; int dir = e >= C1;
    long long cid = e - (long long)dir * C1;
    long long row = cid >> 6; int k8 = (int)(cid & 63) * 8;
    const float* s = (dir ? w_ihr2 : w_ih2) + row * 1024 + 512 + k8;
    ushort_t* d = wih2Ibf + (long long)dir * 2048 * 512 + cid * 8;
    uint4 v;
    v.x = pack2(s[0], s[1]); v.y = pack2(s[2], s[3]);
    v.z = pack2(s[4], s[5]); v.w = pack2(s[6], s[7]);
    *(uint4*)d = v;
  } else if (gid < bs4) {
    long long e = gid - bs3; int dir = e >= C1;
    long long cid = e - (long long)dir * C1;
    long long row = cid >> 8; int c8 = (int)(cid & 255) * 8;
    const float* s = (dir ? img_b_w : img_f_w) + row * 2048 + c8;
    ushort_t* d = imgwbf + (long long)dir * 512 * 2048 + cid * 8;
    uint4 v;
    v.x = pack2(s[0], s[1]); v.y = pack2(s[2], s[3]);
    v.z = pack2(s[4], s[5]); v.w = pack2(s[6], s[7]);
    *(uint4*)d = v;
  } else if (gid < bs5) {
    long long cid = gid - bs4;
    int m = (int)(cid >> 8); int c8 = (int)(cid & 255) * 8;
    const float* s = enc + (long long)order_i[m & 63] * 2048 + c8;
    ushort_t* d = encbf + cid * 8;
    uint4 v;
    v.x = pack2(s[0], s[1]); v.y = pack2(s[2], s[3]);
    v.z = pack2(s[4], s[5]); v.w = pack2(s[6], s[7]);
    *(uint4*)d = v;
  } else if (gid < bs6) {
    long long e = gid - bs5;
    int dir = e >= CPD; long long cid = e - (long long)dir * CPD;
    int c = (int)(cid >> 6); int k8 = (int)(cid & 63) * 8;
    ushort_t* d = embA + (long long)dir * MP * 512 + (long long)c * 512 + k8;
    uint4 v;
    if (c < cumtab[64]) {
      int m = rowmap[c];
      int b = m / TD, t = m - b * TD;
      int row = dir ? capsRev[b * T52 + t] : capsS[b * T52 + t];
      const float* s = (dir ? emb_r_w : emb_w) + (long long)row * 512 + k8;
      v.x = pack2(s[0], s[1]); v.y = pack2(s[2], s[3]);
      v.z = pack2(s[4], s[5]); v.w = pack2(s[6], s[7]);
    } else { v.x = v.y = v.z = v.w = 0u; }
    *(uint4*)d = v;
  } else {
    long long g3 = gid - bs6;
    if (g3 < 4096) {
      int dir = g3 >= 2048; int j = (int)(g3 & 2047);
      biasg1[dir * 2048 + j] = dir ? (b_ihr1[j] + b_hhr1[j]) : (b_ih1[j] + b_hh1[j]);
    } else if (g3 < 8192) {
      long long g4 = g3 - 4096;
      int dir = g4 >= 2048; int j = (int)(g4 & 2047);
      biasg2[dir * 2048 + j] = dir ? (b_ihr2[j] + b_hhr2[j]) : (b_ih2[j] + b_hh2[j]);
    }
  }
}

// ---------------- bf16 MFMA GEMM (r10 BK=32): C[m][n] = sum_k A[m][k]*B[n][k]
// MODE 0: fp32 out, no guards, +bias[n]  (mlim: early-exit on tm >= mlim[64])
// MODE 2: fp32 out, n<Nreal guard, +bias[m]
// MODE 3: bf16 out, no guards, +bias[n]
template<int MODE>
__global__ __launch_bounds__(256)
void k_gemm(const ushort_t* __restrict__ A0, long long As,
            const ushort_t* __restrict__ B0, long long Bs,
            const float* __restrict__ bias0, const float* __restrict__ bias1,
            void* __restrict__ out0, long long Os,
            int Nreal, int K, const int* __restrict__ mlim)
{
  long long tm = (long long)blockIdx.x * 128;
  if (mlim && tm >= mlim[64]) return;
  __shared__ ushort_t Ab[128 * 32];
  __shared__ ushort_t Bb[128 * 32];
  int dirz = blockIdx.z;
  const ushort_t* A = A0 + dirz * As;
  const ushort_t* Bm = B0 + dirz * Bs;
  const float* bias = dirz ? bias1 : bias0;
  int tid = threadIdx.x;
  int lane = tid & 63, wid = tid >> 6;
  int wr = wid >> 1, wc = wid & 1;
  long long tn = (long long)blockIdx.y * 128;
  f32x4 acc[4][4] = {};
  int c0 = tid, c1 = tid + 256;
  const ushort_t* Ag0 = A + (tm + (c0 >> 2)) * K + (c0 & 3) * 8;
  const ushort_t* Ag1 = A + (tm + (c1 >> 2)) * K + (c1 & 3) * 8;
  const ushort_t* Bg0 = Bm + (tn + (c0 >> 2)) * K + (c0 & 3) * 8;
  const ushort_t* Bg1 = Bm + (tn + (c1 >> 2)) * K + (c1 & 3) * 8;
  int KK = K >> 5;
  for (int kk = 0; kk < KK; ++kk) {
    uint4 va0 = *(const uint4*)(Ag0 + kk * 32);
    uint4 va1 = *(const uint4*)(Ag1 + kk * 32);
    uint4 vb0 = *(const uint4*)(Bg0 + kk * 32);
    uint4 vb1 = *(const uint4*)(Bg1 + kk * 32);
    __syncthreads();
    *(uint4*)&Ab[c0 * 8] = va0;
    *(uint4*)&Ab[c1 * 8] = va1;
    *(uint4*)&Bb[c0 * 8] = vb0;
    *(uint4*)&Bb[c1 * 8] = vb1;
    __syncthreads();
    int koff = (lane >> 4) * 8;
    bf16x8 av[4], bv[4];
    #pragma unroll
    for (int mi = 0; mi < 4; ++mi)
      av[mi] = *(const bf16x8*)&Ab[(wr * 64 + mi * 16 + (lane & 15)) * 32 + koff];
    #pragma unroll
    for (int ni = 0; ni < 4; ++ni)
      bv[ni] = *(const bf16x8*)&Bb[(wc * 64 + ni * 16 + (lane & 15)) * 32 + koff];
    #pragma unroll
    for (int mi = 0; mi < 4; ++mi)
      #pragma unroll
      for (int ni = 0; ni < 4; ++ni)
        acc[mi][ni] = __builtin_amdgcn_mfma_f32_16x16x32_bf16(av[mi], bv[ni], acc[mi][ni], 0, 0, 0);
  }
  #pragma unroll
  for (int mi = 0; mi < 4; ++mi) {
    #pragma unroll
    for (int rr = 0; rr < 4; ++rr) {
      long long m = tm + wr * 64 + mi * 16 + ((lane >> 4) * 4) + rr;
      if (MODE == 0) {
        float* orow = (float*)out0 + dirz * Os + m * (long long)Nreal;
        #pragma unroll
        for (int ni = 0; ni < 4; ++ni) {
          int n = (int)tn + wc * 64 + ni * 16 + (lane & 15);
          orow[n] = acc[mi][ni][rr] + bias[n];
        }
      } else if (MODE == 2) {
        float bm = bias[m];
        float* orow = (float*)out0 + dirz * Os + m * (long long)Nreal;
        #pragma unroll
        for (int ni = 0; ni < 4; ++ni) {
          int n = (int)tn + wc * 64 + ni * 16 + (lane & 15);
          if (n < Nreal) orow[n] = acc[mi][ni][rr] + bm;
        }
      } else {
        ushort_t* orow = (ushort_t*)out0 + dirz * Os + m * (long long)Nreal;
        #pragma unroll
        for (int ni = 0; ni < 4; ++ni) {
          int n = (int)tn + wc * 64 + ni * 16 + (lane & 15);
          orow[n] = f2bf(acc[mi][ni][rr] + bias[n]);
        }
      }
    }
  }
}

// ------- FC on compacted rows (BK=32, XCD-grouped grid) + fused zero-fill ---
// rowmap is a FULL permutation: [0,Mc) valid rows, [Mc,MR) invalid rows.
// 1-D grid of 8*20*26 = 4160 blocks. Remap so all m-tiles of a (tn,dir)
// group share bid%8 (=> same XCD under round-robin dispatch): fcw tile is
// fetched once per XCD-group instead of ~8x. Pure index permutation.
__global__ __launch_bounds__(256)
void k_fc(const ushort_t* __restrict__ A0, const ushort_t* __restrict__ B0,
          const float* __restrict__ bias0, const float* __restrict__ bias1,
          float* __restrict__ out0, const int* __restrict__ rowmap,
          const int* __restrict__ cumtab)
{
  const long long PRED = (long long)MR * V10K;
  int Mc = cumtab[64];
  int bid = blockIdx.x;
  int xcd = bid & 7, slot = bid >> 3;      // slot 0..519
  int q = slot / 26, mi = slot % 26;       // q 0..19
  int G = xcd + 8 * q;                     // group id 0..159
  if (G >= 158) return;                    // 158 = 79 tn * 2 dir
  int dirz = G & 1, ni = G >> 1;           // ni 0..78
  long long tm = (long long)mi * 128;
  long long tn = (long long)ni * 128;
  float* out = out0 + (long long)dirz * PRED;
  int tid = threadIdx.x;
  if (tm >= Mc) {
    // pure zero tile: 2 threads/row, float4 stores (V10K % 4 == 0)
    int row = tid >> 1, hf = tid & 1;
    long long c = tm + row;
    if (c < MR) {
      int m = rowmap[c];
      float* orow = out + (long long)m * V10K;
      float4 z = {0.f, 0.f, 0.f, 0.f};
      int col0 = (int)tn + hf * 64;
      #pragma unroll
      for (int qq = 0; qq < 16; ++qq) {
        int col = col0 + qq * 4;
        if (col < V10K) *(float4*)(orow + col) = z;
      }
    }
    return;
  }
  __shared__ ushort_t Ab[128 * 32];
  __shared__ ushort_t Bb[128 * 32];
  const ushort_t* A = A0 + (long long)dirz * MP * 512;
  const ushort_t* Bm = B0 + (long long)dirz * NPFC * 512;
  const float* bias = dirz ? bias1 : bias0;
  int lane = tid & 63, wid = tid >> 6;
  int wr = wid >> 1, wc = wid & 1;
  f32x4 acc[4][4] = {};
  int c0 = tid, c1 = tid + 256;
  const ushort_t* Ag0 = A + (tm + (c0 >> 2)) * 512 + (c0 & 3) * 8;
  const ushort_t* Ag1 = A + (tm + (c1 >> 2)) * 512 + (c1 & 3) * 8;
  const ushort_t* Bg0 = Bm + (tn + (c0 >> 2)) * 512 + (c0 & 3) * 8;
  const ushort_t* Bg1 = Bm + (tn + (c1 >> 2)) * 512 + (c1 & 3) * 8;
  for (int kk = 0; kk < 16; ++kk) {
    uint4 va0 = *(const uint4*)(Ag0 + kk * 32);
    uint4 va1 = *(const uint4*)(Ag1 + kk * 32);
    uint4 vb0 = *(const uint4*)(Bg0 + kk * 32);
    uint4 vb1 = *(const uint4*)(Bg1 + kk * 32);
    __syncthreads();
    *(uint4*)&Ab[c0 * 8] = va0;
    *(uint4*)&Ab[c1 * 8] = va1;
    *(uint4*)&Bb[c0 * 8] = vb0;
    *(uint4*)&Bb[c1 * 8] = vb1;
    __syncthreads();
    int koff = (lane >> 4) * 8;
    bf16x8 av[4], bv[4];
    #pragma unroll
    for (int mi2 = 0; mi2 < 4; ++mi2)
      av[mi2] = *(const bf16x8*)&Ab[(wr * 64 + mi2 * 16 + (lane & 15)) * 32 + koff];
    #pragma unroll
    for (int ni2 = 0; ni2 < 4; ++ni2)
      bv[ni2] = *(const bf16x8*)&Bb[(wc * 64 + ni2 * 16 + (lane & 15)) * 32 + koff];
    #pragma unroll
    for (int mi2 = 0; mi2 < 4; ++mi2)
      #pragma unroll
      for (int ni2 = 0; ni2 < 4; ++ni2)
        acc[mi2][ni2] = __builtin_amdgcn_mfma_f32_16x16x32_bf16(av[mi2], bv[ni2], acc[mi2][ni2], 0, 0, 0);
  }
  #pragma unroll
  for (int mi2 = 0; mi2 < 4; ++mi2) {
    #pragma unroll
    for (int rr = 0; rr < 4; ++rr) {
      long long c = tm + wr * 64 + mi2 * 16 + ((lane >> 4) * 4) + rr;
      if (c < MR) {
        int m = rowmap[c];
        bool val = (c < Mc);
        float* orow = out + (long long)m * V10K;
        #pragma unroll
        for (int ni2 = 0; ni2 < 4; ++ni2) {
          int n = (int)tn + wc * 64 + ni2 * 16 + (lane & 15);
          if (n < V10K) orow[n] = val ? (acc[mi2][ni2][rr] + bias[n]) : 0.f;
        }
      }
    }
  }
}

// ---------------- persistent recurrent kernel (r10 structure, verbatim) -----
// bid 0..127:   L1 (idx=bid:     dir=idx>>6, half=(idx&63)>>5, ht=idx&31)
// bid 128..255: L2 (idx=bid-128: same decomposition)
// 128 threads (2 waves), both waves compute 16 rows each.
// Single combined poll per step (proven in r10; split polls regress).
__global__ __launch_bounds__(128, 1)
void k_rec(const ushort_t* __restrict__ whh1bf, const ushort_t* __restrict__ wih2Lbf,
           const ushort_t* __restrict__ whh2bf, const float* __restrict__ xg1,
           const float* __restrict__ xg2imgT,
           ushort_t* __restrict__ h1hist,   // [52][2][64][512] bf16; slot0 = zeros
           ushort_t* __restrict__ h2buf,    // [2][2][64][512]  (ping-pong, zeroed)
           ushort_t* __restrict__ h2allbf,  // [dir][compact c][512]
           const int* __restrict__ nvtab, const int* __restrict__ cumtab,
           int* __restrict__ slots)         // [0..127]=aS (4 grp x32), [128..255]=bS
{
  const int bid = blockIdx.x;
  const bool isL2 = bid >= 128;
  const int idx = isL2 ? bid - 128 : bid;
  const int dir = idx >> 6, sub = idx & 63, half = sub >> 5, ht = sub & 31;
  const int tid = threadIdx.x;          // 0..127
  const int lane = tid & 63, mt = tid >> 6;
  const int l15 = lane & 15, l4 = lane >> 4;
  const int jl = ht * 16 + l15;
  const int rbase = half * 32 + mt * 16;
  const int r0 = rbase + l4 * 4;

  __shared__ ushort_t Wl[32768];  // 64KB [4 gates][16 cols][512 k] XOR-swizzled
  __shared__ ushort_t Wi[32768];  // 64KB wih2 h1-part (L2 only)
  __shared__ int nv_s[64];
  __shared__ int cum_s[64];

  {
    const ushort_t* src = (isL2 ? whh2bf : whh1bf) + (long long)dir * 2048 * 512;
    #pragma unroll
    for (int i = 0; i < 32; ++i) {
      int c = tid + i * 128;
      int nl = c >> 6;
      int kb = (c & 63) * 16;
      int row = (nl >> 4) * 512 + ht * 16 + (nl & 15);
      u32x4 v = *(const u32x4*)(src + (long long)row * 512 + (long long)(c & 63) * 8);
      *(u32x4*)((char*)Wl + nl * 1024 + (kb ^ ((nl & 7) << 4))) = v;
    }
    if (isL2) {
      const ushort_t* src2 = wih2Lbf + (long long)dir * 2048 * 512;
      #pragma unroll
      for (int i = 0; i < 32; ++i) {
        int c = tid + i * 128;
        int nl = c >> 6;
        int kb = (c & 63) * 16;
        int row = (nl >> 4) * 512 + ht * 16 + (nl & 15);
        u32x4 v = *(const u32x4*)(src2 + (long long)row * 512 + (long long)(c & 63) * 8);
        *(u32x4*)((char*)Wi + nl * 1024 + (kb ^ ((nl & 7) << 4))) = v;
      }
    }
    if (tid < TD) nv_s[tid] = nvtab[tid];
    if (tid < 64) cum_s[tid] = cumtab[tid];
  }
  __syncthreads();

  int* aS = slots + (dir * 2 + half) * 32;
  int* bS = slots + 128 + (dir * 2 + half) * 32;

  if (!isL2) {
    // ---------------- L1 pipeline (2 waves x 16 rows) ----------------
    f32x4 creg = {0.f, 0.f, 0.f, 0.f};
    for (int t = 0; t < TD; ++t) {
      bool act = (rbase < nv_s[t]);
      // x-gate loads (h-independent, compacted xg1): issue before the poll
      float xs[4][4];
      if (act) {
        const float* xb = xg1 + (long long)dir * MP * 2048;
        #pragma unroll
        for (int rr = 0; rr < 4; ++rr) {
          const float* xr = xb + (long long)(cum_s[r0 + rr] + t) * 2048;
          #pragma unroll
          for (int g = 0; g < 4; ++g)
            xs[g][rr] = xr[g * 512 + jl];
        }
      }
      if (t > 0) {
        if (mt == 0) {
          for (;;) {
            int v = __hip_atomic_load(&aS[lane & 31], __ATOMIC_RELAXED, __HIP_MEMORY_SCOPE_AGENT);
            if (__all(v >= t)) break;
          }
        }
        __syncthreads();
      }
      if (act) {
        const ushort_t* hsrc = h1hist + ((long long)t * 2 + dir) * (64 * 512);
        u32x4 hv[16];
        loadA16(hsrc + (long long)(rbase + l15) * 512 + l4 * 8, hv);
        f32x4 acc[4] = {};
        #pragma unroll
        for (int kk = 0; kk < 16; ++kk) {
          bf16x8 av = __builtin_bit_cast(bf16x8, hv[kk]);
          int kb = kk * 64 + l4 * 16;
          #pragma unroll
          for (int g = 0; g < 4; ++g) {
            bf16x8 bv = *(const bf16x8*)((const char*)Wl + (g * 16 + l15) * 1024 + (kb ^ ((l15 & 7) << 4)));
            acc[g] = __builtin_amdgcn_mfma_f32_16x16x32_bf16(av, bv, acc[g], 0, 0, 0);
          }
        }
        ushort_t* hdst = h1hist + ((long long)(t + 1) * 2 + dir) * (64 * 512);
        f32x4 cn;
        #pragma unroll
        for (int rr = 0; rr < 4; ++rr) {
          float gi = acc[0][rr] + xs[0][rr];
          float gf = acc[1][rr] + xs[1][rr];
          float gg = acc[2][rr] + xs[2][rr];
          float go = acc[3][rr] + xs[3][rr];
          float c = sigm(gf) * creg[rr] + sigm(gi) * tanhf(gg);
          float h = sigm(go) * tanhf(c);
          cn[rr] = c;
          store2_sc(hdst + (long long)(r0 + rr) * 512 + jl, (unsigned)f2bf(h));
        }
        creg = cn;
      }
      __syncthreads();   // drains each wave's vmcnt before the slot store
      if (tid == 0)
        __hip_atomic_store(&aS[ht], t + 1, __ATOMIC_RELAXED, __HIP_MEMORY_SCOPE_AGENT);
    }
  } else {
    // ---------------- L2 pipeline (2 waves x 16 rows) ----------------
    f32x4 xv2[4];
    {
      const float* xg = xg2imgT + (long long)dir * (2048 * 64);
      #pragma unroll
      for (int g = 0; g < 4; ++g)
        xv2[g] = *(const f32x4*)(xg + (long long)(g * 512 + jl) * 64 + r0);
    }
    f32x4 creg = {0.f, 0.f, 0.f, 0.f};
    for (int t = 0; t < TD; ++t) {
      // single combined poll: h1(t) ready (aS >= t+1) AND h2(t-1) ready (bS >= t)
      if (mt == 0) {
        for (;;) {
          int va = __hip_atomic_load(&aS[lane & 31], __ATOMIC_RELAXED, __HIP_MEMORY_SCOPE_AGENT);
          int vb = __hip_atomic_load(&bS[lane & 31], __ATOMIC_RELAXED, __HIP_MEMORY_SCOPE_AGENT);
          if (__all((va >= t + 1) & (vb >= t))) break;
        }
      }
      __syncthreads();
      int nv = nv_s[t];
      if (rbase < nv) {
        const ushort_t* h1s = h1hist + ((long long)(t + 1) * 2 + dir) * (64 * 512);
        const ushort_t* h2s = h2buf + ((long long)((t + 1) & 1) * 2 + dir) * (64 * 512);
        u32x4 ha[16], hb[16];
        loadA32(h1s + (long long)(rbase + l15) * 512 + l4 * 8,
                h2s + (long long)(rbase + l15) * 512 + l4 * 8, ha, hb);
        f32x4 acc[4] = {};
        #pragma unroll
        for (int kk = 0; kk < 16; ++kk) {
          bf16x8 av = __builtin_bit_cast(bf16x8, ha[kk]);
          int kb = kk * 64 + l4 * 16;
          #pragma unroll
          for (int g = 0; g < 4; ++g) {
            bf16x8 bv = *(const bf16x8*)((const char*)Wi + (g * 16 + l15) * 1024 + (kb ^ ((l15 & 7) << 4)));
            acc[g] = __builtin_amdgcn_mfma_f32_16x16x32_bf16(av, bv, acc[g], 0, 0, 0);
          }
        }
        #pragma unroll
        for (int kk = 0; kk < 16; ++kk) {
          bf16x8 av = __builtin_bit_cast(bf16x8, hb[kk]);
          int kb = kk * 64 + l4 * 16;
          #pragma unroll
          for (int g = 0; g < 4; ++g) {
            bf16x8 bv = *(const bf16x8*)((const char*)Wl + (g * 16 + l15) * 1024 + (kb ^ ((l15 & 7) << 4)));
            acc[g] = __builtin_amdgcn_mfma_f32_16x16x32_bf16(av, bv, acc[g], 0, 0, 0);
          }
        }
        ushort_t* h2n = h2buf + ((long long)(t & 1) * 2 + dir) * (64 * 512);
        ushort_t* h2a = h2allbf + (long long)dir * MP * 512;
        f32x4 cn;
        #pragma unroll
        for (int rr = 0; rr < 4; ++rr) {
          float gi = acc[0][rr] + xv2[0][rr];
          float gf = acc[1][rr] + xv2[1][rr];
          float gg = acc[2][rr] + xv2[2][rr];
          float go = acc[3][rr] + xv2[3][rr];
          float c = sigm(gf) * creg[rr] + sigm(gi) * tanhf(gg);
          float h = sigm(go) * tanhf(c);
          cn[rr] = c;
          ushort_t hbb = f2bf(h);
          store2_sc(h2n + (long long)(r0 + rr) * 512 + jl, (unsigned)hbb);
          if (r0 + rr < nv)
            h2a[((long long)(cum_s[r0 + rr] + t)) * 512 + jl] = hbb;
        }
        creg = cn;
      }
      __syncthreads();   // drains each wave's vmcnt before the slot store
      if (tid == 0)
        __hip_atomic_store(&bS[ht], t + 1, __ATOMIC_RELAXED, __HIP_MEMORY_SCOPE_AGENT);
    }
  }
}

// ---------------------------------------------------------------------------
extern "C" void kernel_launch(void* const* d_in, const int* in_sizes, int n_in,
                              void* d_out, int out_size, void* d_ws, size_t ws_size,
                              hipStream_t stream)
{
  const float* enc     = (const float*)d_in[0];
  const int*   caps    = (const int*)d_in[1];
  const int*   cl      = (const int*)d_in[2];
  const float* emb_w   = (const float*)d_in[3];
  const float* emb_r_w = (const float*)d_in[4];
  const float* w_ih1   = (const float*)d_in[5];
  const float* w_hh1   = (const float*)d_in[6];
  const float* b_ih1   = (const float*)d_in[7];
  const float* b_hh1   = (const float*)d_in[8];
  const float* w_ih2   = (const float*)d_in[9];
  const float* w_hh2   = (const float*)d_in[10];
  const float* b_ih2   = (const float*)d_in[11];
  const float* b_hh2   = (const float*)d_in[12];
  const float* w_ihr1  = (const float*)d_in[13];
  const float* w_hhr1  = (const float*)d_in[14];
  const float* b_ihr1  = (const float*)d_in[15];
  const float* b_hhr1  = (const float*)d_in[16];
  const float* w_ihr2  = (const float*)d_in[17];
  const float* w_hhr2  = (const float*)d_in[18];
  const float* b_ihr2  = (const float*)d_in[19];
  const float* b_hhr2  = (const float*)d_in[20];
  const float* img_f_w = (const float*)d_in[21];
  const float* img_f_b = (const float*)d_in[22];
  const float* img_b_w = (const float*)d_in[23];
  const float* img_b_b = (const float*)d_in[24];
  const float* fc_w    = (const float*)d_in[25];
  const float* fc_b    = (const float*)d_in[26];
  const float* fcr_w   = (const float*)d_in[27];
  const float* fcr_b   = (const float*)d_in[28];

  float* outF = (float*)d_out;
  const long long PRED = (long long)MR * V10K;          // 32,640,000
  float* o_caps = outF + 2 * PRED;
  float* o_capr = o_caps + B64 * T52;
  float* o_lm1  = o_capr + B64 * T52;
  float* o_ord  = o_lm1 + B64;
  // big scratch parked inside the preds region of d_out (dead before FC):
  float*    xg1       = outF;                           // [2][MP][2048] compact
  ushort_t* whh1bf    = (ushort_t*)(outF + 27500000);   // 2,097,152 us each
  ushort_t* wih2Lbf   = (ushort_t*)(outF + 28600000);
  ushort_t* whh2bf    = (ushort_t*)(outF + 29700000);
  ushort_t* h1hist    = (ushort_t*)(outF + 31000000);   // [52][2][64][512] = 6.8MB
  ushort_t* wih2Ibf   = (ushort_t*)(outF + 34600000);
  ushort_t* imgwbf    = (ushort_t*)(outF + 35700000);   // [2][512][2048] bf16
  ushort_t* encbf     = (ushort_t*)(outF + 36800000);   // [128][2048] bf16
  ushort_t* imgbf     = (ushort_t*)(outF + 37000000);   // [2][128][512] bf16

  char* w = (char*)d_ws;
  auto alloc = [&](size_t bytes) -> char* {
    char* p = w; w += (bytes + 255) & ~(size_t)255; return p;
  };
  int*      order_i  = (int*)alloc(64 * 4);
  int*      lensm1_i = (int*)alloc(64 * 4);
  int*      nvtab    = (int*)alloc(64 * 4);
  int*      cumtab   = (int*)alloc(65 * 4);
  int*      rowmap   = (int*)alloc(MR * 4);
  int*      capsS    = (int*)alloc(B64 * T52 * 4);
  int*      capsRev  = (int*)alloc(B64 * T52 * 4);
  float*    biasg1   = (float*)alloc(2 * 2048 * 4);
  float*    biasg2   = (float*)alloc(2 * 2048 * 4);
  float*    xg2imgT  = (float*)alloc((size_t)2 * 2048 * 64 * 4);
  char*     stateBase = alloc(262144 + 1024);
  ushort_t* h2buf = (ushort_t*)stateBase;               // [2 pp][2 dir][64][512] bf16
  int*      slotp = (int*)(stateBase + 262144);         // 256 flags
  ushort_t* embA    = (ushort_t*)alloc((size_t)2 * MP * 512 * 2);
  ushort_t* wih1bf  = (ushort_t*)alloc((size_t)2 * 2048 * 512 * 2);
  ushort_t* fcwbf   = (ushort_t*)alloc((size_t)2 * NPFC * 512 * 2);
  ushort_t* h2allbf = (ushort_t*)alloc((size_t)2 * MP * 512 * 2);

  hipMemsetAsync(stateBase, 0, 262144 + 1024, stream);
  hipMemsetAsync(h1hist, 0, 131072, stream);   // slot 0 = h1(-1) = zeros

  k_prep<<<1, 64, 0, stream>>>(cl, caps, o_caps, o_capr, o_lm1, o_ord,
                               order_i, lensm1_i, nvtab, capsS, capsRev,
                               cumtab, rowmap);
  k_convert<<<13024, 256, 0, stream>>>(w_ih1, w_ihr1, fc_w, fcr_w,
                                       b_ih1, b_hh1, b_ihr1, b_hhr1,
                                       w_hh1, w_hhr1, w_ih2, w_ihr2, w_hh2, w_hhr2,
                                       img_f_w, img_b_w, b_ih2, b_hh2, b_ihr2, b_hhr2,
                                       enc, order_i, emb_w, emb_r_w,
                                       capsS, capsRev, rowmap, cumtab,
                                       wih1bf, fcwbf, whh1bf, wih2Lbf, whh2bf,
                                       wih2Ibf, imgwbf, encbf, embA, biasg1, biasg2);
  // img = enc @ imgw^T + b  (bf16 out, [2][128][512])
  k_gemm<3><<<dim3(1, 4, 2), 256, 0, stream>>>(encbf, 0LL,
                                               imgwbf, 512LL * 2048,
                                               img_f_b, img_b_b,
                                               imgbf, 128LL * 512,
                                               512, 2048, nullptr);
  // xg2imgT[j][b] = wih2I[j] . img[b] + biasg2[j]   ([2][2048][64] fp32)
  k_gemm<2><<<dim3(16, 1, 2), 256, 0, stream>>>(wih2Ibf, 2048LL * 512,
                                                imgbf, 128LL * 512,
                                                biasg2, biasg2 + 2048,
                                                xg2imgT, 2048LL * 64,
                                                64, 512, nullptr);
  // xg1 [dir][compact c][2048] fp32 (early-exit on tm >= Mc)
  k_gemm<0><<<dim3(26, 16, 2), 256, 0, stream>>>(embA, (long long)MP * 512,
                                                 wih1bf, 2048LL * 512,
                                                 biasg1, biasg1 + 2048,
                                                 xg1, (long long)MP * 2048,
                                                 2048, 512, cumtab);
  k_rec<<<256, 128, 0, stream>>>(whh1bf, wih2Lbf, whh2bf, xg1, xg2imgT,
                                 h1hist, h2buf, h2allbf, nvtab, cumtab, slotp);
  k_fc<<<4160, 256, 0, stream>>>(h2allbf, fcwbf, fc_b, fcr_b,
                                 outF, rowmap, cumtab);
}

// Round 15
// 680.822 us; speedup vs baseline: 1.3647x; 1.0193x over previous
//
#include <hip/hip_runtime.h>
#include <stdint.h>

#define B64   64
#define T52   52
#define TD    51
#define V10K  10000
#define MP    3328   // padded M = 26*128
#define MR    3264   // real M = 64*51
#define NPFC  10112  // padded V = 79*128

typedef float  f32x4  __attribute__((ext_vector_type(4)));
typedef __bf16 bf16x8 __attribute__((ext_vector_type(8)));
typedef unsigned int u32x4 __attribute__((ext_vector_type(4)));
typedef unsigned short ushort_t;

__device__ inline unsigned short f2bf(float f) {
  unsigned u = __builtin_bit_cast(unsigned, f);
  u += 0x7fffu + ((u >> 16) & 1u);
  return (unsigned short)(u >> 16);
}
__device__ inline unsigned pack2(float a, float b) {
  return (unsigned)f2bf(a) | ((unsigned)f2bf(b) << 16);
}
__device__ inline float sigm(float x) { return 1.f / (1.f + expf(-x)); }

// MALL write-through 2B store (agent scope)
__device__ inline void store2_sc(ushort_t* p, unsigned v) {
  asm volatile("global_store_short %0, %1, off sc1" :: "v"(p), "v"(v) : "memory");
}
// 16 x 16B sc1 loads + single wait
__device__ inline void loadA16(const ushort_t* a, u32x4 (&h)[16]) {
  asm volatile(
    "global_load_dwordx4 %0,  %16, off sc1\n\t"
    "global_load_dwordx4 %1,  %16, off offset:64 sc1\n\t"
    "global_load_dwordx4 %2,  %16, off offset:128 sc1\n\t"
    "global_load_dwordx4 %3,  %16, off offset:192 sc1\n\t"
    "global_load_dwordx4 %4,  %16, off offset:256 sc1\n\t"
    "global_load_dwordx4 %5,  %16, off offset:320 sc1\n\t"
    "global_load_dwordx4 %6,  %16, off offset:384 sc1\n\t"
    "global_load_dwordx4 %7,  %16, off offset:448 sc1\n\t"
    "global_load_dwordx4 %8,  %16, off offset:512 sc1\n\t"
    "global_load_dwordx4 %9,  %16, off offset:576 sc1\n\t"
    "global_load_dwordx4 %10, %16, off offset:640 sc1\n\t"
    "global_load_dwordx4 %11, %16, off offset:704 sc1\n\t"
    "global_load_dwordx4 %12, %16, off offset:768 sc1\n\t"
    "global_load_dwordx4 %13, %16, off offset:832 sc1\n\t"
    "global_load_dwordx4 %14, %16, off offset:896 sc1\n\t"
    "global_load_dwordx4 %15, %16, off offset:960 sc1\n\t"
    "s_waitcnt vmcnt(0)"
    : "=&v"(h[0]),"=&v"(h[1]),"=&v"(h[2]),"=&v"(h[3]),
      "=&v"(h[4]),"=&v"(h[5]),"=&v"(h[6]),"=&v"(h[7]),
      "=&v"(h[8]),"=&v"(h[9]),"=&v"(h[10]),"=&v"(h[11]),
      "=&v"(h[12]),"=&v"(h[13]),"=&v"(h[14]),"=&v"(h[15])
    : "v"(a) : "memory");
}
// 32 x 16B sc1 loads from two bases + single wait
__device__ inline void loadA32(const ushort_t* a, const ushort_t* b,
                               u32x4 (&ha)[16], u32x4 (&hb)[16]) {
  asm volatile(
    "global_load_dwordx4 %0,  %32, off sc1\n\t"
    "global_load_dwordx4 %1,  %32, off offset:64 sc1\n\t"
    "global_load_dwordx4 %2,  %32, off offset:128 sc1\n\t"
    "global_load_dwordx4 %3,  %32, off offset:192 sc1\n\t"
    "global_load_dwordx4 %4,  %32, off offset:256 sc1\n\t"
    "global_load_dwordx4 %5,  %32, off offset:320 sc1\n\t"
    "global_load_dwordx4 %6,  %32, off offset:384 sc1\n\t"
    "global_load_dwordx4 %7,  %32, off offset:448 sc1\n\t"
    "global_load_dwordx4 %8,  %32, off offset:512 sc1\n\t"
    "global_load_dwordx4 %9,  %32, off offset:576 sc1\n\t"
    "global_load_dwordx4 %10, %32, off offset:640 sc1\n\t"
    "global_load_dwordx4 %11, %32, off offset:704 sc1\n\t"
    "global_load_dwordx4 %12, %32, off offset:768 sc1\n\t"
    "global_load_dwordx4 %13, %32, off offset:832 sc1\n\t"
    "global_load_dwordx4 %14, %32, off offset:896 sc1\n\t"
    "global_load_dwordx4 %15, %32, off offset:960 sc1\n\t"
    "global_load_dwordx4 %16, %33, off sc1\n\t"
    "global_load_dwordx4 %17, %33, off offset:64 sc1\n\t"
    "global_load_dwordx4 %18, %33, off offset:128 sc1\n\t"
    "global_load_dwordx4 %19, %33, off offset:192 sc1\n\t"
    "global_load_dwordx4 %20, %33, off offset:256 sc1\n\t"
    "global_load_dwordx4 %21, %33, off offset:320 sc1\n\t"
    "global_load_dwordx4 %22, %33, off offset:384 sc1\n\t"
    "global_load_dwordx4 %23, %33, off offset:448 sc1\n\t"
    "global_load_dwordx4 %24, %33, off offset:512 sc1\n\t"
    "global_load_dwordx4 %25, %33, off offset:576 sc1\n\t"
    "global_load_dwordx4 %26, %33, off offset:640 sc1\n\t"
    "global_load_dwordx4 %27, %33, off offset:704 sc1\n\t"
    "global_load_dwordx4 %28, %33, off offset:768 sc1\n\t"
    "global_load_dwordx4 %29, %33, off offset:832 sc1\n\t"
    "global_load_dwordx4 %30, %33, off offset:896 sc1\n\t"
    "global_load_dwordx4 %31, %33, off offset:960 sc1\n\t"
    "s_waitcnt vmcnt(0)"
    : "=&v"(ha[0]),"=&v"(ha[1]),"=&v"(ha[2]),"=&v"(ha[3]),
      "=&v"(ha[4]),"=&v"(ha[5]),"=&v"(ha[6]),"=&v"(ha[7]),
      "=&v"(ha[8]),"=&v"(ha[9]),"=&v"(ha[10]),"=&v"(ha[11]),
      "=&v"(ha[12]),"=&v"(ha[13]),"=&v"(ha[14]),"=&v"(ha[15]),
      "=&v"(hb[0]),"=&v"(hb[1]),"=&v"(hb[2]),"=&v"(hb[3]),
      "=&v"(hb[4]),"=&v"(hb[5]),"=&v"(hb[6]),"=&v"(hb[7]),
      "=&v"(hb[8]),"=&v"(hb[9]),"=&v"(hb[10]),"=&v"(hb[11]),
      "=&v"(hb[12]),"=&v"(hb[13]),"=&v"(hb[14]),"=&v"(hb[15])
    : "v"(a), "v"(b) : "memory");
}

// ---------------- prep ------------------------------------------------------
__global__ void k_prep(const int* __restrict__ cl, const int* __restrict__ caps,
                       float* __restrict__ out_caps, float* __restrict__ out_capr,
                       float* __restrict__ out_lm1, float* __restrict__ out_ord,
                       int* __restrict__ order_i, int* __restrict__ lensm1_i,
                       int* __restrict__ nvtab, int* __restrict__ capsS,
                       int* __restrict__ capsRev, int* __restrict__ cumtab,
                       int* __restrict__ rowmap)
{
  __shared__ int L[64], O[64], Ls_s[64], Cum[65];
  __shared__ int C_s[64][T52];
  int i = threadIdx.x;
  L[i] = cl[i];
  __syncthreads();
  if (i == 0) {
    for (int a = 0; a < 64; ++a) O[a] = a;
    for (int a = 1; a < 64; ++a) {
      int key = O[a], kl = L[key], b = a - 1;
      while (b >= 0 && L[O[b]] < kl) { O[b + 1] = O[b]; --b; }
      O[b + 1] = key;
    }
  }
  __syncthreads();
  int src = O[i];
  int Ls  = L[src];
  Ls_s[i] = Ls;
  order_i[i]  = src;
  lensm1_i[i] = Ls - 1;
  out_lm1[i]  = (float)(Ls - 1);
  out_ord[i]  = (float)src;
  for (int t = 0; t < T52; ++t) {
    int c = caps[src * T52 + t];
    C_s[i][t] = c;
    capsS[i * T52 + t]    = c;
    out_caps[i * T52 + t] = (float)c;
  }
  __syncthreads();
  for (int j = 0; j < T52; ++j) {
    int rv = (j < Ls) ? C_s[i][Ls - 1 - j] : 0;
    capsRev[i * T52 + j]  = rv;
    out_capr[i * T52 + j] = (float)rv;
  }
  if (i == 0) {
    int s = 0;
    for (int b = 0; b < 64; ++b) { Cum[b] = s; s += Ls_s[b] - 1; }
    Cum[64] = s;
  }
  __syncthreads();
  cumtab[i] = Cum[i];
  if (i == 0) cumtab[64] = Cum[64];
  // full permutation rowmap: [0,Mc) = valid rows, [Mc,MR) = invalid rows
  for (int t = 0; t < Ls - 1; ++t) rowmap[Cum[i] + t] = i * TD + t;
  {
    int Mc = Cum[64];
    int invBase = Mc + i * TD - Cum[i];
    for (int t = Ls - 1; t < TD; ++t)
      rowmap[invBase + (t - (Ls - 1))] = i * TD + t;
  }
  if (i < TD) {
    int nv = 0;
    for (int r = 0; r < 64; ++r) nv += (Ls_s[r] - 1 > i) ? 1 : 0;
    nvtab[i] = nv;
  }
}

// ------- convert weights + bias sums + img operands + emb gather + zero-init
__global__ void k_convert(const float* __restrict__ w_ih1, const float* __restrict__ w_ihr1,
                          const float* __restrict__ fc_w, const float* __restrict__ fcr_w,
                          const float* __restrict__ b_ih1, const float* __restrict__ b_hh1,
                          const float* __restrict__ b_ihr1, const float* __restrict__ b_hhr1,
                          const float* __restrict__ w_hh1, const float* __restrict__ w_hhr1,
                          const float* __restrict__ w_ih2, const float* __restrict__ w_ihr2,
                          const float* __restrict__ w_hh2, const float* __restrict__ w_hhr2,
                          const float* __restrict__ img_f_w, const float* __restrict__ img_b_w,
                          const float* __restrict__ b_ih2, const float* __restrict__ b_hh2,
                          const float* __restrict__ b_ihr2, const float* __restrict__ b_hhr2,
                          const float* __restrict__ enc, const int* __restrict__ order_i,
                          const float* __restrict__ emb_w, const float* __restrict__ emb_r_w,
                          const int* __restrict__ capsS, const int* __restrict__ capsRev,
                          const int* __restrict__ rowmap, const int* __restrict__ cumtab,
                          ushort_t* __restrict__ wih1bf, ushort_t* __restrict__ fcwbf,
                          ushort_t* __restrict__ whh1bf, ushort_t* __restrict__ wih2Lbf,
                          ushort_t* __restrict__ whh2bf, ushort_t* __restrict__ wih2Ibf,
                          ushort_t* __restrict__ imgwbf, ushort_t* __restrict__ encbf,
                          ushort_t* __restrict__ embA,
                          float* __restrict__ biasg1, float* __restrict__ biasg2,
                          char* __restrict__ stateBase, char* __restrict__ h1hist0)
{
  long long gid = (long long)blockIdx.x * blockDim.x + threadIdx.x;
  const long long C1 = 2048LL * 512 / 8;          // 131072
  const long long CF = (long long)NPFC * 512 / 8; // 647168
  const long long CPD = (long long)MP * 512 / 8;  // 212992
  const long long bs  = 2 * C1 + 2 * CF;
  const long long bs2 = bs + 6 * C1;
  const long long bs3 = bs2 + 2 * C1;   // wih2Ibf
  const long long bs4 = bs3 + 2 * C1;   // imgwbf
  const long long bs5 = bs4 + 32768;    // encbf
  const long long bs6 = bs5 + 2 * CPD;  // embA
  const long long bs7 = bs6 + 8192;     // biases
  if (gid < 2 * C1) {
    int dir = gid >= C1; long long cid = gid - (long long)dir * C1;
    const float* s = (dir ? w_ihr1 : w_ih1) + cid * 8;
    ushort_t* d = wih1bf + (long long)dir * 2048 * 512 + cid * 8;
    uint4 v;
    v.x = pack2(s[0], s[1]); v.y = pack2(s[2], s[3]);
    v.z = pack2(s[4], s[5]); v.w = pack2(s[6], s[7]);
    *(uint4*)d = v;
  } else if (gid < bs) {
    long long g2 = gid - 2 * C1; int dir = g2 >= CF;
    long long cid = g2 - (long long)dir * CF;
    long long row = cid >> 6; int k8 = (int)(cid & 63) * 8;
    ushort_t* d = fcwbf + (long long)dir * NPFC * 512 + row * 512 + k8;
    uint4 v;
    if (row < V10K) {
      const float* s = (dir ? fcr_w : fc_w) + row * 512 + k8;
      v.x = pack2(s[0], s[1]); v.y = pack2(s[2], s[3]);
      v.z = pack2(s[4], s[5]); v.w = pack2(s[6], s[7]);
    } else { v.x = v.y = v.z = v.w = 0u; }
    *(uint4*)d = v;
  } else if (gid < bs2) {
    long long e = gid - bs;
    int arr = (int)(e / (2 * C1));
    long long d2 = e - (long long)arr * 2 * C1;
    int dir = d2 >= C1;
    long long cid = d2 - (long long)dir * C1;
    long long row = cid >> 6; int k8 = (int)(cid & 63) * 8;
    const float* s;
    ushort_t* d;
    if (arr == 0)      { s = (dir ? w_hhr1 : w_hh1) + row * 512  + k8; d = whh1bf; }
    else if (arr == 1) { s = (dir ? w_ihr2 : w_ih2) + row * 1024 + k8; d = wih2Lbf; }
    else               { s = (dir ? w_hhr2 : w_hh2) + row * 512  + k8; d = whh2bf; }
    d += (long long)dir * 2048 * 512 + cid * 8;
    uint4 v;
    v.x = pack2(s[0], s[1]); v.y = pack2(s[2], s[3]);
    v.z = pack2(s[4], s[5]); v.w = pack2(s[6], s[7]);
    *(uint4*)d = v;
  } else if (gid < bs3) {
    long long e = gid - bs2; int dir = e >= C1;
    long long cid = e - (long long)dir * C1;
    long long row = cid >> 6; int k8 = (int)(cid & 63) * 8;
    const float* s = (dir ? w_ihr2 : w_ih2) + row * 1024 + 512 + k8;
    ushort_t* d = wih2Ibf + (long long)dir * 2048 * 512 + cid * 8;
    uint4 v;
    v.x = pack2(s[0], s[1]); v.y = pack2(s[2], s[3]);
    v.z = pack2(s[4], s[5]); v.w = pack2(s[6], s[7]);
    *(uint4*)d = v;
  } else if (gid < bs4) {
    long long e = gid - bs3; int dir = e >= C1;
    long long cid = e - (long long)dir * C1;
    long long row = cid >> 8; int c8 = (int)(cid & 255) * 8;
    const float* s = (dir ? img_b_w : img_f_w) + row * 2048 + c8;
    ushort_t* d = imgwbf + (long long)dir * 512 * 2048 + cid * 8;
    uint4 v;
    v.x = pack2(s[0], s[1]); v.y = pack2(s[2], s[3]);
    v.z = pack2(s[4], s[5]); v.w = pack2(s[6], s[7]);
    *(uint4*)d = v;
  } else if (gid < bs5) {
    long long cid = gid - bs4;
    int m = (int)(cid >> 8); int c8 = (int)(cid & 255) * 8;
    const float* s = enc + (long long)order_i[m & 63] * 2048 + c8;
    ushort_t* d = encbf + cid * 8;
    uint4 v;
    v.x = pack2(s[0], s[1]); v.y = pack2(s[2], s[3]);
    v.z = pack2(s[4], s[5]); v.w = pack2(s[6], s[7]);
    *(uint4*)d = v;
  } else if (gid < bs6) {
    long long e = gid - bs5;
    int dir = e >= CPD; long long cid = e - (long long)dir * CPD;
    int c = (int)(cid >> 6); int k8 = (int)(cid & 63) * 8;
    ushort_t* d = embA + (long long)dir * MP * 512 + (long long)c * 512 + k8;
    uint4 v;
    if (c < cumtab[64]) {
      int m = rowmap[c];
      int b = m / TD, t = m - b * TD;
      int row = dir ? capsRev[b * T52 + t] : capsS[b * T52 + t];
      const float* s = (dir ? emb_r_w : emb_w) + (long long)row * 512 + k8;
      v.x = pack2(s[0], s[1]); v.y = pack2(s[2], s[3]);
      v.z = pack2(s[4], s[5]); v.w = pack2(s[6], s[7]);
    } else { v.x = v.y = v.z = v.w = 0u; }
    *(uint4*)d = v;
  } else if (gid < bs7) {
    long long g3 = gid - bs6;
    if (g3 < 4096) {
      int dir = g3 >= 2048; int j = (int)(g3 & 2047);
      biasg1[dir * 2048 + j] = dir ? (b_ihr1[j] + b_hhr1[j]) : (b_ih1[j] + b_hh1[j]);
    } else {
      long long g4 = g3 - 4096;
      int dir = g4 >= 2048; int j = (int)(g4 & 2047);
      biasg2[dir * 2048 + j] = dir ? (b_ihr2[j] + b_hhr2[j]) : (b_ih2[j] + b_hh2[j]);
    }
  } else {
    // zero-init: stateBase (h2buf 262144B + slots 1024B = 16448 uint4)
    //            h1hist slot0 (131072B = 8192 uint4)
    long long z = gid - bs7;
    uint4 zero = {0u, 0u, 0u, 0u};
    if (z < 16448) {
      ((uint4*)stateBase)[z] = zero;
    } else if (z < 16448 + 8192) {
      ((uint4*)h1hist0)[z - 16448] = zero;
    }
  }
}

// ---------------- bf16 MFMA GEMM (r10 BK=32): C[m][n] = sum_k A[m][k]*B[n][k]
// MODE 0: fp32 out, no guards, +bias[n]  (mlim: early-exit on tm >= mlim[64])
// MODE 2: fp32 out, n<Nreal guard, +bias[m]
// MODE 3: bf16 out, no guards, +bias[n]
template<int MODE>
__global__ __launch_bounds__(256)
void k_gemm(const ushort_t* __restrict__ A0, long long As,
            const ushort_t* __restrict__ B0, long long Bs,
            const float* __restrict__ bias0, const float* __restrict__ bias1,
            void* __restrict__ out0, long long Os,
            int Nreal, int K, const int* __restrict__ mlim)
{
  long long tm = (long long)blockIdx.x * 128;
  if (mlim && tm >= mlim[64]) return;
  __shared__ ushort_t Ab[128 * 32];
  __shared__ ushort_t Bb[128 * 32];
  int dirz = blockIdx.z;
  const ushort_t* A = A0 + dirz * As;
  const ushort_t* Bm = B0 + dirz * Bs;
  const float* bias = dirz ? bias1 : bias0;
  int tid = threadIdx.x;
  int lane = tid & 63, wid = tid >> 6;
  int wr = wid >> 1, wc = wid & 1;
  long long tn = (long long)blockIdx.y * 128;
  f32x4 acc[4][4] = {};
  int c0 = tid, c1 = tid + 256;
  const ushort_t* Ag0 = A + (tm + (c0 >> 2)) * K + (c0 & 3) * 8;
  const ushort_t* Ag1 = A + (tm + (c1 >> 2)) * K + (c1 & 3) * 8;
  const ushort_t* Bg0 = Bm + (tn + (c0 >> 2)) * K + (c0 & 3) * 8;
  const ushort_t* Bg1 = Bm + (tn + (c1 >> 2)) * K + (c1 & 3) * 8;
  int KK = K >> 5;
  for (int kk = 0; kk < KK; ++kk) {
    uint4 va0 = *(const uint4*)(Ag0 + kk * 32);
    uint4 va1 = *(const uint4*)(Ag1 + kk * 32);
    uint4 vb0 = *(const uint4*)(Bg0 + kk * 32);
    uint4 vb1 = *(const uint4*)(Bg1 + kk * 32);
    __syncthreads();
    *(uint4*)&Ab[c0 * 8] = va0;
    *(uint4*)&Ab[c1 * 8] = va1;
    *(uint4*)&Bb[c0 * 8] = vb0;
    *(uint4*)&Bb[c1 * 8] = vb1;
    __syncthreads();
    int koff = (lane >> 4) * 8;
    bf16x8 av[4], bv[4];
    #pragma unroll
    for (int mi = 0; mi < 4; ++mi)
      av[mi] = *(const bf16x8*)&Ab[(wr * 64 + mi * 16 + (lane & 15)) * 32 + koff];
    #pragma unroll
    for (int ni = 0; ni < 4; ++ni)
      bv[ni] = *(const bf16x8*)&Bb[(wc * 64 + ni * 16 + (lane & 15)) * 32 + koff];
    #pragma unroll
    for (int mi = 0; mi < 4; ++mi)
      #pragma unroll
      for (int ni = 0; ni < 4; ++ni)
        acc[mi][ni] = __builtin_amdgcn_mfma_f32_16x16x32_bf16(av[mi], bv[ni], acc[mi][ni], 0, 0, 0);
  }
  #pragma unroll
  for (int mi = 0; mi < 4; ++mi) {
    #pragma unroll
    for (int rr = 0; rr < 4; ++rr) {
      long long m = tm + wr * 64 + mi * 16 + ((lane >> 4) * 4) + rr;
      if (MODE == 0) {
        float* orow = (float*)out0 + dirz * Os + m * (long long)Nreal;
        #pragma unroll
        for (int ni = 0; ni < 4; ++ni) {
          int n = (int)tn + wc * 64 + ni * 16 + (lane & 15);
          orow[n] = acc[mi][ni][rr] + bias[n];
        }
      } else if (MODE == 2) {
        float bm = bias[m];
        float* orow = (float*)out0 + dirz * Os + m * (long long)Nreal;
        #pragma unroll
        for (int ni = 0; ni < 4; ++ni) {
          int n = (int)tn + wc * 64 + ni * 16 + (lane & 15);
          if (n < Nreal) orow[n] = acc[mi][ni][rr] + bm;
        }
      } else {
        ushort_t* orow = (ushort_t*)out0 + dirz * Os + m * (long long)Nreal;
        #pragma unroll
        for (int ni = 0; ni < 4; ++ni) {
          int n = (int)tn + wc * 64 + ni * 16 + (lane & 15);
          orow[n] = f2bf(acc[mi][ni][rr] + bias[n]);
        }
      }
    }
  }
}

// ------- FC on compacted rows (BK=32) + fused zero-fill of invalid rows -----
// rowmap is a FULL permutation: [0,Mc) valid rows, [Mc,MR) invalid rows.
__global__ __launch_bounds__(256)
void k_fc(const ushort_t* __restrict__ A0, const ushort_t* __restrict__ B0,
          const float* __restrict__ bias0, const float* __restrict__ bias1,
          float* __restrict__ out0, const int* __restrict__ rowmap,
          const int* __restrict__ cumtab)
{
  const long long PRED = (long long)MR * V10K;
  int Mc = cumtab[64];
  long long tm = (long long)blockIdx.x * 128;
  int dirz = blockIdx.z;
  long long tn = (long long)blockIdx.y * 128;
  float* out = out0 + (long long)dirz * PRED;
  int tid = threadIdx.x;
  if (tm >= Mc) {
    // pure zero tile: 2 threads/row, float4 stores (V10K % 4 == 0)
    int row = tid >> 1, hf = tid & 1;
    long long c = tm + row;
    if (c < MR) {
      int m = rowmap[c];
      float* orow = out + (long long)m * V10K;
      float4 z = {0.f, 0.f, 0.f, 0.f};
      int col0 = (int)tn + hf * 64;
      #pragma unroll
      for (int qq = 0; qq < 16; ++qq) {
        int col = col0 + qq * 4;
        if (col < V10K) *(float4*)(orow + col) = z;
      }
    }
    return;
  }
  __shared__ ushort_t Ab[128 * 32];
  __shared__ ushort_t Bb[128 * 32];
  const ushort_t* A = A0 + (long long)dirz * MP * 512;
  const ushort_t* Bm = B0 + (long long)dirz * NPFC * 512;
  const float* bias = dirz ? bias1 : bias0;
  int lane = tid & 63, wid = tid >> 6;
  int wr = wid >> 1, wc = wid & 1;
  f32x4 acc[4][4] = {};
  int c0 = tid, c1 = tid + 256;
  const ushort_t* Ag0 = A + (tm + (c0 >> 2)) * 512 + (c0 & 3) * 8;
  const ushort_t* Ag1 = A + (tm + (c1 >> 2)) * 512 + (c1 & 3) * 8;
  const ushort_t* Bg0 = Bm + (tn + (c0 >> 2)) * 512 + (c0 & 3) * 8;
  const ushort_t* Bg1 = Bm + (tn + (c1 >> 2)) * 512 + (c1 & 3) * 8;
  for (int kk = 0; kk < 16; ++kk) {
    uint4 va0 = *(const uint4*)(Ag0 + kk * 32);
    uint4 va1 = *(const uint4*)(Ag1 + kk * 32);
    uint4 vb0 = *(const uint4*)(Bg0 + kk * 32);
    uint4 vb1 = *(const uint4*)(Bg1 + kk * 32);
    __syncthreads();
    *(uint4*)&Ab[c0 * 8] = va0;
    *(uint4*)&Ab[c1 * 8] = va1;
    *(uint4*)&Bb[c0 * 8] = vb0;
    *(uint4*)&Bb[c1 * 8] = vb1;
    __syncthreads();
    int koff = (lane >> 4) * 8;
    bf16x8 av[4], bv[4];
    #pragma unroll
    for (int mi2 = 0; mi2 < 4; ++mi2)
      av[mi2] = *(const bf16x8*)&Ab[(wr * 64 + mi2 * 16 + (lane & 15)) * 32 + koff];
    #pragma unroll
    for (int ni2 = 0; ni2 < 4; ++ni2)
      bv[ni2] = *(const bf16x8*)&Bb[(wc * 64 + ni2 * 16 + (lane & 15)) * 32 + koff];
    #pragma unroll
    for (int mi2 = 0; mi2 < 4; ++mi2)
      #pragma unroll
      for (int ni2 = 0; ni2 < 4; ++ni2)
        acc[mi2][ni2] = __builtin_amdgcn_mfma_f32_16x16x32_bf16(av[mi2], bv[ni2], acc[mi2][ni2], 0, 0, 0);
  }
  #pragma unroll
  for (int mi2 = 0; mi2 < 4; ++mi2) {
    #pragma unroll
    for (int rr = 0; rr < 4; ++rr) {
      long long c = tm + wr * 64 + mi2 * 16 + ((lane >> 4) * 4) + rr;
      if (c < MR) {
        int m = rowmap[c];
        bool val = (c < Mc);
        float* orow = out + (long long)m * V10K;
        #pragma unroll
        for (int ni2 = 0; ni2 < 4; ++ni2) {
          int n = (int)tn + wc * 64 + ni2 * 16 + (lane & 15);
          if (n < V10K) orow[n] = val ? (acc[mi2][ni2][rr] + bias[n]) : 0.f;
        }
      }
    }
  }
}

// ---------------- persistent recurrent kernel (r10 structure) ---------------
// bid 0..127:   L1 (idx=bid:     dir=idx>>6, half=(idx&63)>>5, ht=idx&31)
// bid 128..255: L2 (idx=bid-128: same decomposition)
// 128 threads (2 waves), both waves compute 16 rows each.
// Single combined poll per step (proven in r10; split polls regress).
// h2all stores deferred until AFTER the flag (read only by k_fc post-kernel).
__global__ __launch_bounds__(128, 1)
void k_rec(const ushort_t* __restrict__ whh1bf, const ushort_t* __restrict__ wih2Lbf,
           const ushort_t* __restrict__ whh2bf, const float* __restrict__ xg1,
           const float* __restrict__ xg2imgT,
           ushort_t* __restrict__ h1hist,   // [52][2][64][512] bf16; slot0 = zeros
           ushort_t* __restrict__ h2buf,    // [2][2][64][512]  (ping-pong, zeroed)
           ushort_t* __restrict__ h2allbf,  // [dir][compact c][512]
           const int* __restrict__ nvtab, const int* __restrict__ cumtab,
           int* __restrict__ slots)         // [0..127]=aS (4 grp x32), [128..255]=bS
{
  const int bid = blockIdx.x;
  const bool isL2 = bid >= 128;
  const int idx = isL2 ? bid - 128 : bid;
  const int dir = idx >> 6, sub = idx & 63, half = sub >> 5, ht = sub & 31;
  const int tid = threadIdx.x;          // 0..127
  const int lane = tid & 63, mt = tid >> 6;
  const int l15 = lane & 15, l4 = lane >> 4;
  const int jl = ht * 16 + l15;
  const int rbase = half * 32 + mt * 16;
  const int r0 = rbase + l4 * 4;

  __shared__ ushort_t Wl[32768];  // 64KB [4 gates][16 cols][512 k] XOR-swizzled
  __shared__ ushort_t Wi[32768];  // 64KB wih2 h1-part (L2 only)
  __shared__ int nv_s[64];
  __shared__ int cum_s[64];

  {
    const ushort_t* src = (isL2 ? whh2bf : whh1bf) + (long long)dir * 2048 * 512;
    #pragma unroll
    for (int i = 0; i < 32; ++i) {
      int c = tid + i * 128;
      int nl = c >> 6;
      int kb = (c & 63) * 16;
      int row = (nl >> 4) * 512 + ht * 16 + (nl & 15);
      u32x4 v = *(const u32x4*)(src + (long long)row * 512 + (long long)(c & 63) * 8);
      *(u32x4*)((char*)Wl + nl * 1024 + (kb ^ ((nl & 7) << 4))) = v;
    }
    if (isL2) {
      const ushort_t* src2 = wih2Lbf + (long long)dir * 2048 * 512;
      #pragma unroll
      for (int i = 0; i < 32; ++i) {
        int c = tid + i * 128;
        int nl = c >> 6;
        int kb = (c & 63) * 16;
        int row = (nl >> 4) * 512 + ht * 16 + (nl & 15);
        u32x4 v = *(const u32x4*)(src2 + (long long)row * 512 + (long long)(c & 63) * 8);
        *(u32x4*)((char*)Wi + nl * 1024 + (kb ^ ((nl & 7) << 4))) = v;
      }
    }
    if (tid < TD) nv_s[tid] = nvtab[tid];
    if (tid < 64) cum_s[tid] = cumtab[tid];
  }
  __syncthreads();

  int* aS = slots + (dir * 2 + half) * 32;
  int* bS = slots + 128 + (dir * 2 + half) * 32;

  if (!isL2) {
    // ---------------- L1 pipeline (2 waves x 16 rows) ----------------
    f32x4 creg = {0.f, 0.f, 0.f, 0.f};
    for (int t = 0; t < TD; ++t) {
      bool act = (rbase < nv_s[t]);
      // x-gate loads (h-independent, compacted xg1): issue before the poll
      float xs[4][4];
      if (act) {
        const float* xb = xg1 + (long long)dir * MP * 2048;
        #pragma unroll
        for (int rr = 0; rr < 4; ++rr) {
          const float* xr = xb + (long long)(cum_s[r0 + rr] + t) * 2048;
          #pragma unroll
          for (int g = 0; g < 4; ++g)
            xs[g][rr] = xr[g * 512 + jl];
        }
      }
      if (t > 0) {
        if (mt == 0) {
          for (;;) {
            int v = __hip_atomic_load(&aS[lane & 31], __ATOMIC_RELAXED, __HIP_MEMORY_SCOPE_AGENT);
            if (__all(v >= t)) break;
          }
        }
        __syncthreads();
      }
      if (act) {
        const ushort_t* hsrc = h1hist + ((long long)t * 2 + dir) * (64 * 512);
        u32x4 hv[16];
        loadA16(hsrc + (long long)(rbase + l15) * 512 + l4 * 8, hv);
        f32x4 acc[4] = {};
        #pragma unroll
        for (int kk = 0; kk < 16; ++kk) {
          bf16x8 av = __builtin_bit_cast(bf16x8, hv[kk]);
          int kb = kk * 64 + l4 * 16;
          #pragma unroll
          for (int g = 0; g < 4; ++g) {
            bf16x8 bv = *(const bf16x8*)((const char*)Wl + (g * 16 + l15) * 1024 + (kb ^ ((l15 & 7) << 4)));
            acc[g] = __builtin_amdgcn_mfma_f32_16x16x32_bf16(av, bv, acc[g], 0, 0, 0);
          }
        }
        ushort_t* hdst = h1hist + ((long long)(t + 1) * 2 + dir) * (64 * 512);
        f32x4 cn;
        #pragma unroll
        for (int rr = 0; rr < 4; ++rr) {
          float gi = acc[0][rr] + xs[0][rr];
          float gf = acc[1][rr] + xs[1][rr];
          float gg = acc[2][rr] + xs[2][rr];
          float go = acc[3][rr] + xs[3][rr];
          float c = sigm(gf) * creg[rr] + sigm(gi) * tanhf(gg);
          float h = sigm(go) * tanhf(c);
          cn[rr] = c;
          store2_sc(hdst + (long long)(r0 + rr) * 512 + jl, (unsigned)f2bf(h));
        }
        creg = cn;
      }
      __syncthreads();   // drains each wave's vmcnt before the slot store
      if (tid == 0)
        __hip_atomic_store(&aS[ht], t + 1, __ATOMIC_RELAXED, __HIP_MEMORY_SCOPE_AGENT);
    }
  } else {
    // ---------------- L2 pipeline (2 waves x 16 rows) ----------------
    f32x4 xv2[4];
    {
      const float* xg = xg2imgT + (long long)dir * (2048 * 64);
      #pragma unroll
      for (int g = 0; g < 4; ++g)
        xv2[g] = *(const f32x4*)(xg + (long long)(g * 512 + jl) * 64 + r0);
    }
    f32x4 creg = {0.f, 0.f, 0.f, 0.f};
    for (int t = 0; t < TD; ++t) {
      // single combined poll: h1(t) ready (aS >= t+1) AND h2(t-1) ready (bS >= t)
      if (mt == 0) {
        for (;;) {
          int va = __hip_atomic_load(&aS[lane & 31], __ATOMIC_RELAXED, __HIP_MEMORY_SCOPE_AGENT);
          int vb = __hip_atomic_load(&bS[lane & 31], __ATOMIC_RELAXED, __HIP_MEMORY_SCOPE_AGENT);
          if (__all((va >= t + 1) & (vb >= t))) break;
        }
      }
      __syncthreads();
      int nv = nv_s[t];
      bool act = (rbase < nv);
      ushort_t hb4[4];
      if (act) {
        const ushort_t* h1s = h1hist + ((long long)(t + 1) * 2 + dir) * (64 * 512);
        const ushort_t* h2s = h2buf + ((long long)((t + 1) & 1) * 2 + dir) * (64 * 512);
        u32x4 ha[16], hb[16];
        loadA32(h1s + (long long)(rbase + l15) * 512 + l4 * 8,
                h2s + (long long)(rbase + l15) * 512 + l4 * 8, ha, hb);
        f32x4 acc[4] = {};
        #pragma unroll
        for (int kk = 0; kk < 16; ++kk) {
          bf16x8 av = __builtin_bit_cast(bf16x8, ha[kk]);
          int kb = kk * 64 + l4 * 16;
          #pragma unroll
          for (int g = 0; g < 4; ++g) {
            bf16x8 bv = *(const bf16x8*)((const char*)Wi + (g * 16 + l15) * 1024 + (kb ^ ((l15 & 7) << 4)));
            acc[g] = __builtin_amdgcn_mfma_f32_16x16x32_bf16(av, bv, acc[g], 0, 0, 0);
          }
        }
        #pragma unroll
        for (int kk = 0; kk < 16; ++kk) {
          bf16x8 av = __builtin_bit_cast(bf16x8, hb[kk]);
          int kb = kk * 64 + l4 * 16;
          #pragma unroll
          for (int g = 0; g < 4; ++g) {
            bf16x8 bv = *(const bf16x8*)((const char*)Wl + (g * 16 + l15) * 1024 + (kb ^ ((l15 & 7) << 4)));
            acc[g] = __builtin_amdgcn_mfma_f32_16x16x32_bf16(av, bv, acc[g], 0, 0, 0);
          }
        }
        ushort_t* h2n = h2buf + ((long long)(t & 1) * 2 + dir) * (64 * 512);
        f32x4 cn;
        #pragma unroll
        for (int rr = 0; rr < 4; ++rr) {
          float gi = acc[0][rr] + xv2[0][rr];
          float gf = acc[1][rr] + xv2[1][rr];
          float gg = acc[2][rr] + xv2[2][rr];
          float go = acc[3][rr] + xv2[3][rr];
          float c = sigm(gf) * creg[rr] + sigm(gi) * tanhf(gg);
          float h = sigm(go) * tanhf(c);
          cn[rr] = c;
          ushort_t hbb = f2bf(h);
          hb4[rr] = hbb;
          store2_sc(h2n + (long long)(r0 + rr) * 512 + jl, (unsigned)hbb);
        }
        creg = cn;
      }
      __syncthreads();   // drains each wave's vmcnt (h2n sc1) before the slot store
      if (tid == 0)
        __hip_atomic_store(&bS[ht], t + 1, __ATOMIC_RELAXED, __HIP_MEMORY_SCOPE_AGENT);
      // deferred h2all stores: consumed only by k_fc after kernel end
      if (act) {
        ushort_t* h2a = h2allbf + (long long)dir * MP * 512;
        #pragma unroll
        for (int rr = 0; rr < 4; ++rr)
          if (r0 + rr < nv)
            h2a[((long long)(cum_s[r0 + rr] + t)) * 512 + jl] = hb4[rr];
      }
    }
  }
}

// ---------------------------------------------------------------------------
extern "C" void kernel_launch(void* const* d_in, const int* in_sizes, int n_in,
                              void* d_out, int out_size, void* d_ws, size_t ws_size,
                              hipStream_t stream)
{
  const float* enc     = (const float*)d_in[0];
  const int*   caps    = (const int*)d_in[1];
  const int*   cl      = (const int*)d_in[2];
  const float* emb_w   = (const float*)d_in[3];
  const float* emb_r_w = (const float*)d_in[4];
  const float* w_ih1   = (const float*)d_in[5];
  const float* w_hh1   = (const float*)d_in[6];
  const float* b_ih1   = (const float*)d_in[7];
  const float* b_hh1   = (const float*)d_in[8];
  const float* w_ih2   = (const float*)d_in[9];
  const float* w_hh2   = (const float*)d_in[10];
  const float* b_ih2   = (const float*)d_in[11];
  const float* b_hh2   = (const float*)d_in[12];
  const float* w_ihr1  = (const float*)d_in[13];
  const float* w_hhr1  = (const float*)d_in[14];
  const float* b_ihr1  = (const float*)d_in[15];
  const float* b_hhr1  = (const float*)d_in[16];
  const float* w_ihr2  = (const float*)d_in[17];
  const float* w_hhr2  = (const float*)d_in[18];
  const float* b_ihr2  = (const float*)d_in[19];
  const float* b_hhr2  = (const float*)d_in[20];
  const float* img_f_w = (const float*)d_in[21];
  const float* img_f_b = (const float*)d_in[22];
  const float* img_b_w = (const float*)d_in[23];
  const float* img_b_b = (const float*)d_in[24];
  const float* fc_w    = (const float*)d_in[25];
  const float* fc_b    = (const float*)d_in[26];
  const float* fcr_w   = (const float*)d_in[27];
  const float* fcr_b   = (const float*)d_in[28];

  float* outF = (float*)d_out;
  const long long PRED = (long long)MR * V10K;          // 32,640,000
  float* o_caps = outF + 2 * PRED;
  float* o_capr = o_caps + B64 * T52;
  float* o_lm1  = o_capr + B64 * T52;
  float* o_ord  = o_lm1 + B64;
  // big scratch parked inside the preds region of d_out (dead before FC):
  float*    xg1       = outF;                           // [2][MP][2048] compact
  ushort_t* whh1bf    = (ushort_t*)(outF + 27500000);   // 2,097,152 us each
  ushort_t* wih2Lbf   = (ushort_t*)(outF + 28600000);
  ushort_t* whh2bf    = (ushort_t*)(outF + 29700000);
  ushort_t* h1hist    = (ushort_t*)(outF + 31000000);   // [52][2][64][512] = 6.8MB
  ushort_t* wih2Ibf   = (ushort_t*)(outF + 34600000);
  ushort_t* imgwbf    = (ushort_t*)(outF + 35700000);   // [2][512][2048] bf16
  ushort_t* encbf     = (ushort_t*)(outF + 36800000);   // [128][2048] bf16
  ushort_t* imgbf     = (ushort_t*)(outF + 37000000);   // [2][128][512] bf16

  char* w = (char*)d_ws;
  auto alloc = [&](size_t bytes) -> char* {
    char* p = w; w += (bytes + 255) & ~(size_t)255; return p;
  };
  int*      order_i  = (int*)alloc(64 * 4);
  int*      lensm1_i = (int*)alloc(64 * 4);
  int*      nvtab    = (int*)alloc(64 * 4);
  int*      cumtab   = (int*)alloc(65 * 4);
  int*      rowmap   = (int*)alloc(MR * 4);
  int*      capsS    = (int*)alloc(B64 * T52 * 4);
  int*      capsRev  = (int*)alloc(B64 * T52 * 4);
  float*    biasg1   = (float*)alloc(2 * 2048 * 4);
  float*    biasg2   = (float*)alloc(2 * 2048 * 4);
  float*    xg2imgT  = (float*)alloc((size_t)2 * 2048 * 64 * 4);
  char*     stateBase = alloc(262144 + 1024);
  ushort_t* h2buf = (ushort_t*)stateBase;               // [2 pp][2 dir][64][512] bf16
  int*      slotp = (int*)(stateBase + 262144);         // 256 flags
  ushort_t* embA    = (ushort_t*)alloc((size_t)2 * MP * 512 * 2);
  ushort_t* wih1bf  = (ushort_t*)alloc((size_t)2 * 2048 * 512 * 2);
  ushort_t* fcwbf   = (ushort_t*)alloc((size_t)2 * NPFC * 512 * 2);
  ushort_t* h2allbf = (ushort_t*)alloc((size_t)2 * MP * 512 * 2);

  k_prep<<<1, 64, 0, stream>>>(cl, caps, o_caps, o_capr, o_lm1, o_ord,
                               order_i, lensm1_i, nvtab, capsS, capsRev,
                               cumtab, rowmap);
  // k_convert also zero-inits h2buf/slots (16448 uint4) + h1hist slot0 (8192)
  k_convert<<<13121, 256, 0, stream>>>(w_ih1, w_ihr1, fc_w, fcr_w,
                                       b_ih1, b_hh1, b_ihr1, b_hhr1,
                                       w_hh1, w_hhr1, w_ih2, w_ihr2, w_hh2, w_hhr2,
                                       img_f_w, img_b_w, b_ih2, b_hh2, b_ihr2, b_hhr2,
                                       enc, order_i, emb_w, emb_r_w,
                                       capsS, capsRev, rowmap, cumtab,
                                       wih1bf, fcwbf, whh1bf, wih2Lbf, whh2bf,
                                       wih2Ibf, imgwbf, encbf, embA, biasg1, biasg2,
                                       stateBase, (char*)h1hist);
  // img = enc @ imgw^T + b  (bf16 out, [2][128][512])
  k_gemm<3><<<dim3(1, 4, 2), 256, 0, stream>>>(encbf, 0LL,
                                               imgwbf, 512LL * 2048,
                                               img_f_b, img_b_b,
                                               imgbf, 128LL * 512,
                                               512, 2048, nullptr);
  // xg2imgT[j][b] = wih2I[j] . img[b] + biasg2[j]   ([2][2048][64] fp32)
  k_gemm<2><<<dim3(16, 1, 2), 256, 0, stream>>>(wih2Ibf, 2048LL * 512,
                                                imgbf, 128LL * 512,
                                                biasg2, biasg2 + 2048,
                                                xg2imgT, 2048LL * 64,
                                                64, 512, nullptr);
  // xg1 [dir][compact c][2048] fp32 (early-exit on tm >= Mc)
  k_gemm<0><<<dim3(26, 16, 2), 256, 0, stream>>>(embA, (long long)MP * 512,
                                                 wih1bf, 2048LL * 512,
                                                 biasg1, biasg1 + 2048,
                                                 xg1, (long long)MP * 2048,
                                                 2048, 512, cumtab);
  k_rec<<<256, 128, 0, stream>>>(whh1bf, wih2Lbf, whh2bf, xg1, xg2imgT,
                                 h1hist, h2buf, h2allbf, nvtab, cumtab, slotp);
  k_fc<<<dim3(26, 79, 2), 256, 0, stream>>>(h2allbf, fcwbf, fc_b, fcr_b,
                                            outF, rowmap, cumtab);
}

// Round 16
// 680.380 us; speedup vs baseline: 1.3656x; 1.0006x over previous
//
#include <hip/hip_runtime.h>
#include <stdint.h>

#define B64   64
#define T52   52
#define TD    51
#define V10K  10000
#define MP    3328   // padded M = 26*128
#define MR    3264   // real M = 64*51
#define NPFC  10112  // padded V = 79*128

typedef float  f32x4  __attribute__((ext_vector_type(4)));
typedef __bf16 bf16x8 __attribute__((ext_vector_type(8)));
typedef unsigned int u32x4 __attribute__((ext_vector_type(4)));
typedef unsigned short ushort_t;

__device__ inline unsigned short f2bf(float f) {
  unsigned u = __builtin_bit_cast(unsigned, f);
  u += 0x7fffu + ((u >> 16) & 1u);
  return (unsigned short)(u >> 16);
}
__device__ inline unsigned pack2(float a, float b) {
  return (unsigned)f2bf(a) | ((unsigned)f2bf(b) << 16);
}
__device__ inline float sigm(float x) { return 1.f / (1.f + expf(-x)); }

// MALL write-through 2B store (agent scope)
__device__ inline void store2_sc(ushort_t* p, unsigned v) {
  asm volatile("global_store_short %0, %1, off sc1" :: "v"(p), "v"(v) : "memory");
}
// 16 x 16B sc1 loads + single wait
__device__ inline void loadA16(const ushort_t* a, u32x4 (&h)[16]) {
  asm volatile(
    "global_load_dwordx4 %0,  %16, off sc1\n\t"
    "global_load_dwordx4 %1,  %16, off offset:64 sc1\n\t"
    "global_load_dwordx4 %2,  %16, off offset:128 sc1\n\t"
    "global_load_dwordx4 %3,  %16, off offset:192 sc1\n\t"
    "global_load_dwordx4 %4,  %16, off offset:256 sc1\n\t"
    "global_load_dwordx4 %5,  %16, off offset:320 sc1\n\t"
    "global_load_dwordx4 %6,  %16, off offset:384 sc1\n\t"
    "global_load_dwordx4 %7,  %16, off offset:448 sc1\n\t"
    "global_load_dwordx4 %8,  %16, off offset:512 sc1\n\t"
    "global_load_dwordx4 %9,  %16, off offset:576 sc1\n\t"
    "global_load_dwordx4 %10, %16, off offset:640 sc1\n\t"
    "global_load_dwordx4 %11, %16, off offset:704 sc1\n\t"
    "global_load_dwordx4 %12, %16, off offset:768 sc1\n\t"
    "global_load_dwordx4 %13, %16, off offset:832 sc1\n\t"
    "global_load_dwordx4 %14, %16, off offset:896 sc1\n\t"
    "global_load_dwordx4 %15, %16, off offset:960 sc1\n\t"
    "s_waitcnt vmcnt(0)"
    : "=&v"(h[0]),"=&v"(h[1]),"=&v"(h[2]),"=&v"(h[3]),
      "=&v"(h[4]),"=&v"(h[5]),"=&v"(h[6]),"=&v"(h[7]),
      "=&v"(h[8]),"=&v"(h[9]),"=&v"(h[10]),"=&v"(h[11]),
      "=&v"(h[12]),"=&v"(h[13]),"=&v"(h[14]),"=&v"(h[15])
    : "v"(a) : "memory");
}
// 32 x 16B sc1 loads from two bases + single wait
__device__ inline void loadA32(const ushort_t* a, const ushort_t* b,
                               u32x4 (&ha)[16], u32x4 (&hb)[16]) {
  asm volatile(
    "global_load_dwordx4 %0,  %32, off sc1\n\t"
    "global_load_dwordx4 %1,  %32, off offset:64 sc1\n\t"
    "global_load_dwordx4 %2,  %32, off offset:128 sc1\n\t"
    "global_load_dwordx4 %3,  %32, off offset:192 sc1\n\t"
    "global_load_dwordx4 %4,  %32, off offset:256 sc1\n\t"
    "global_load_dwordx4 %5,  %32, off offset:320 sc1\n\t"
    "global_load_dwordx4 %6,  %32, off offset:384 sc1\n\t"
    "global_load_dwordx4 %7,  %32, off offset:448 sc1\n\t"
    "global_load_dwordx4 %8,  %32, off offset:512 sc1\n\t"
    "global_load_dwordx4 %9,  %32, off offset:576 sc1\n\t"
    "global_load_dwordx4 %10, %32, off offset:640 sc1\n\t"
    "global_load_dwordx4 %11, %32, off offset:704 sc1\n\t"
    "global_load_dwordx4 %12, %32, off offset:768 sc1\n\t"
    "global_load_dwordx4 %13, %32, off offset:832 sc1\n\t"
    "global_load_dwordx4 %14, %32, off offset:896 sc1\n\t"
    "global_load_dwordx4 %15, %32, off offset:960 sc1\n\t"
    "global_load_dwordx4 %16, %33, off sc1\n\t"
    "global_load_dwordx4 %17, %33, off offset:64 sc1\n\t"
    "global_load_dwordx4 %18, %33, off offset:128 sc1\n\t"
    "global_load_dwordx4 %19, %33, off offset:192 sc1\n\t"
    "global_load_dwordx4 %20, %33, off offset:256 sc1\n\t"
    "global_load_dwordx4 %21, %33, off offset:320 sc1\n\t"
    "global_load_dwordx4 %22, %33, off offset:384 sc1\n\t"
    "global_load_dwordx4 %23, %33, off offset:448 sc1\n\t"
    "global_load_dwordx4 %24, %33, off offset:512 sc1\n\t"
    "global_load_dwordx4 %25, %33, off offset:576 sc1\n\t"
    "global_load_dwordx4 %26, %33, off offset:640 sc1\n\t"
    "global_load_dwordx4 %27, %33, off offset:704 sc1\n\t"
    "global_load_dwordx4 %28, %33, off offset:768 sc1\n\t"
    "global_load_dwordx4 %29, %33, off offset:832 sc1\n\t"
    "global_load_dwordx4 %30, %33, off offset:896 sc1\n\t"
    "global_load_dwordx4 %31, %33, off offset:960 sc1\n\t"
    "s_waitcnt vmcnt(0)"
    : "=&v"(ha[0]),"=&v"(ha[1]),"=&v"(ha[2]),"=&v"(ha[3]),
      "=&v"(ha[4]),"=&v"(ha[5]),"=&v"(ha[6]),"=&v"(ha[7]),
      "=&v"(ha[8]),"=&v"(ha[9]),"=&v"(ha[10]),"=&v"(ha[11]),
      "=&v"(ha[12]),"=&v"(ha[13]),"=&v"(ha[14]),"=&v"(ha[15]),
      "=&v"(hb[0]),"=&v"(hb[1]),"=&v"(hb[2]),"=&v"(hb[3]),
      "=&v"(hb[4]),"=&v"(hb[5]),"=&v"(hb[6]),"=&v"(hb[7]),
      "=&v"(hb[8]),"=&v"(hb[9]),"=&v"(hb[10]),"=&v"(hb[11]),
      "=&v"(hb[12]),"=&v"(hb[13]),"=&v"(hb[14]),"=&v"(hb[15])
    : "v"(a), "v"(b) : "memory");
}

// ---------------- prep ------------------------------------------------------
__global__ void k_prep(const int* __restrict__ cl, const int* __restrict__ caps,
                       float* __restrict__ out_caps, float* __restrict__ out_capr,
                       float* __restrict__ out_lm1, float* __restrict__ out_ord,
                       int* __restrict__ order_i, int* __restrict__ lensm1_i,
                       int* __restrict__ nvtab, int* __restrict__ capsS,
                       int* __restrict__ capsRev, int* __restrict__ cumtab,
                       int* __restrict__ rowmap)
{
  __shared__ int L[64], O[64], Ls_s[64], Cum[65];
  __shared__ int C_s[64][T52];
  int i = threadIdx.x;
  L[i] = cl[i];
  __syncthreads();
  if (i == 0) {
    for (int a = 0; a < 64; ++a) O[a] = a;
    for (int a = 1; a < 64; ++a) {
      int key = O[a], kl = L[key], b = a - 1;
      while (b >= 0 && L[O[b]] < kl) { O[b + 1] = O[b]; --b; }
      O[b + 1] = key;
    }
  }
  __syncthreads();
  int src = O[i];
  int Ls  = L[src];
  Ls_s[i] = Ls;
  order_i[i]  = src;
  lensm1_i[i] = Ls - 1;
  out_lm1[i]  = (float)(Ls - 1);
  out_ord[i]  = (float)src;
  for (int t = 0; t < T52; ++t) {
    int c = caps[src * T52 + t];
    C_s[i][t] = c;
    capsS[i * T52 + t]    = c;
    out_caps[i * T52 + t] = (float)c;
  }
  __syncthreads();
  for (int j = 0; j < T52; ++j) {
    int rv = (j < Ls) ? C_s[i][Ls - 1 - j] : 0;
    capsRev[i * T52 + j]  = rv;
    out_capr[i * T52 + j] = (float)rv;
  }
  if (i == 0) {
    int s = 0;
    for (int b = 0; b < 64; ++b) { Cum[b] = s; s += Ls_s[b] - 1; }
    Cum[64] = s;
  }
  __syncthreads();
  cumtab[i] = Cum[i];
  if (i == 0) cumtab[64] = Cum[64];
  // full permutation rowmap: [0,Mc) = valid rows, [Mc,MR) = invalid rows
  for (int t = 0; t < Ls - 1; ++t) rowmap[Cum[i] + t] = i * TD + t;
  {
    int Mc = Cum[64];
    int invBase = Mc + i * TD - Cum[i];
    for (int t = Ls - 1; t < TD; ++t)
      rowmap[invBase + (t - (Ls - 1))] = i * TD + t;
  }
  if (i < TD) {
    int nv = 0;
    for (int r = 0; r < 64; ++r) nv += (Ls_s[r] - 1 > i) ? 1 : 0;
    nvtab[i] = nv;
  }
}

// ------- convert weights + bias sums + img operands + emb gather + zero-init
__global__ void k_convert(const float* __restrict__ w_ih1, const float* __restrict__ w_ihr1,
                          const float* __restrict__ fc_w, const float* __restrict__ fcr_w,
                          const float* __restrict__ b_ih1, const float* __restrict__ b_hh1,
                          const float* __restrict__ b_ihr1, const float* __restrict__ b_hhr1,
                          const float* __restrict__ w_hh1, const float* __restrict__ w_hhr1,
                          const float* __restrict__ w_ih2, const float* __restrict__ w_ihr2,
                          const float* __restrict__ w_hh2, const float* __restrict__ w_hhr2,
                          const float* __restrict__ img_f_w, const float* __restrict__ img_b_w,
                          const float* __restrict__ b_ih2, const float* __restrict__ b_hh2,
                          const float* __restrict__ b_ihr2, const float* __restrict__ b_hhr2,
                          const float* __restrict__ enc, const int* __restrict__ order_i,
                          const float* __restrict__ emb_w, const float* __restrict__ emb_r_w,
                          const int* __restrict__ capsS, const int* __restrict__ capsRev,
                          const int* __restrict__ rowmap, const int* __restrict__ cumtab,
                          ushort_t* __restrict__ wih1bf, ushort_t* __restrict__ fcwbf,
                          ushort_t* __restrict__ whh1bf, ushort_t* __restrict__ wih2Lbf,
                          ushort_t* __restrict__ whh2bf, ushort_t* __restrict__ wih2Ibf,
                          ushort_t* __restrict__ imgwbf, ushort_t* __restrict__ encbf,
                          ushort_t* __restrict__ embA,
                          float* __restrict__ biasg1, float* __restrict__ biasg2,
                          char* __restrict__ stateBase, char* __restrict__ h1hist0)
{
  long long gid = (long long)blockIdx.x * blockDim.x + threadIdx.x;
  const long long C1 = 2048LL * 512 / 8;          // 131072
  const long long CF = (long long)NPFC * 512 / 8; // 647168
  const long long CPD = (long long)MP * 512 / 8;  // 212992
  const long long bs  = 2 * C1 + 2 * CF;
  const long long bs2 = bs + 6 * C1;
  const long long bs3 = bs2 + 2 * C1;   // wih2Ibf
  const long long bs4 = bs3 + 2 * C1;   // imgwbf
  const long long bs5 = bs4 + 32768;    // encbf
  const long long bs6 = bs5 + 2 * CPD;  // embA
  const long long bs7 = bs6 + 8192;     // biases
  if (gid < 2 * C1) {
    int dir = gid >= C1; long long cid = gid - (long long)dir * C1;
    const float* s = (dir ? w_ihr1 : w_ih1) + cid * 8;
    ushort_t* d = wih1bf + (long long)dir * 2048 * 512 + cid * 8;
    uint4 v;
    v.x = pack2(s[0], s[1]); v.y = pack2(s[2], s[3]);
    v.z = pack2(s[4], s[5]); v.w = pack2(s[6], s[7]);
    *(uint4*)d = v;
  } else if (gid < bs) {
    long long g2 = gid - 2 * C1; int dir = g2 >= CF;
    long long cid = g2 - (long long)dir * CF;
    long long row = cid >> 6; int k8 = (int)(cid & 63) * 8;
    ushort_t* d = fcwbf + (long long)dir * NPFC * 512 + row * 512 + k8;
    uint4 v;
    if (row < V10K) {
      const float* s = (dir ? fcr_w : fc_w) + row * 512 + k8;
      v.x = pack2(s[0], s[1]); v.y = pack2(s[2], s[3]);
      v.z = pack2(s[4], s[5]); v.w = pack2(s[6], s[7]);
    } else { v.x = v.y = v.z = v.w = 0u; }
    *(uint4*)d = v;
  } else if (gid < bs2) {
    long long e = gid - bs;
    int arr = (int)(e / (2 * C1));
    long long d2 = e - (long long)arr * 2 * C1;
    int dir = d2 >= C1;
    long long cid = d2 - (long long)dir * C1;
    long long row = cid >> 6; int k8 = (int)(cid & 63) * 8;
    const float* s;
    ushort_t* d;
    if (arr == 0)      { s = (dir ? w_hhr1 : w_hh1) + row * 512  + k8; d = whh1bf; }
    else if (arr == 1) { s = (dir ? w_ihr2 : w_ih2) + row * 1024 + k8; d = wih2Lbf; }
    else               { s = (dir ? w_hhr2 : w_hh2) + row * 512  + k8; d = whh2bf; }
    d += (long long)dir * 2048 * 512 + cid * 8;
    uint4 v;
    v.x = pack2(s[0], s[1]); v.y = pack2(s[2], s[3]);
    v.z = pack2(s[4], s[5]); v.w = pack2(s[6], s[7]);
    *(uint4*)d = v;
  } else if (gid < bs3) {
    long long e = gid - bs2; int dir = e >= C1;
    long long cid = e - (long long)dir * C1;
    long long row = cid >> 6; int k8 = (int)(cid & 63) * 8;
    const float* s = (dir ? w_ihr2 : w_ih2) + row * 1024 + 512 + k8;
    ushort_t* d = wih2Ibf + (long long)dir * 2048 * 512 + cid * 8;
    uint4 v;
    v.x = pack2(s[0], s[1]); v.y = pack2(s[2], s[3]);
    v.z = pack2(s[4], s[5]); v.w = pack2(s[6], s[7]);
    *(uint4*)d = v;
  } else if (gid < bs4) {
    long long e = gid - bs3; int dir = e >= C1;
    long long cid = e - (long long)dir * C1;
    long long row = cid >> 8; int c8 = (int)(cid & 255) * 8;
    const float* s = (dir ? img_b_w : img_f_w) + row * 2048 + c8;
    ushort_t* d = imgwbf + (long long)dir * 512 * 2048 + cid * 8;
    uint4 v;
    v.x = pack2(s[0], s[1]); v.y = pack2(s[2], s[3]);
    v.z = pack2(s[4], s[5]); v.w = pack2(s[6], s[7]);
    *(uint4*)d = v;
  } else if (gid < bs5) {
    long long cid = gid - bs4;
    int m = (int)(cid >> 8); int c8 = (int)(cid & 255) * 8;
    const float* s = enc + (long long)order_i[m & 63] * 2048 + c8;
    ushort_t* d = encbf + cid * 8;
    uint4 v;
    v.x = pack2(s[0], s[1]); v.y = pack2(s[2], s[3]);
    v.z = pack2(s[4], s[5]); v.w = pack2(s[6], s[7]);
    *(uint4*)d = v;
  } else if (gid < bs6) {
    long long e = gid - bs5;
    int dir = e >= CPD; long long cid = e - (long long)dir * CPD;
    int c = (int)(cid >> 6); int k8 = (int)(cid & 63) * 8;
    ushort_t* d = embA + (long long)dir * MP * 512 + (long long)c * 512 + k8;
    uint4 v;
    if (c < cumtab[64]) {
      int m = rowmap[c];
      int b = m / TD, t = m - b * TD;
      int row = dir ? capsRev[b * T52 + t] : capsS[b * T52 + t];
      const float* s = (dir ? emb_r_w : emb_w) + (long long)row * 512 + k8;
      v.x = pack2(s[0], s[1]); v.y = pack2(s[2], s[3]);
      v.z = pack2(s[4], s[5]); v.w = pack2(s[6], s[7]);
    } else { v.x = v.y = v.z = v.w = 0u; }
    *(uint4*)d = v;
  } else if (gid < bs7) {
    long long g3 = gid - bs6;
    if (g3 < 4096) {
      int dir = g3 >= 2048; int j = (int)(g3 & 2047);
      biasg1[dir * 2048 + j] = dir ? (b_ihr1[j] + b_hhr1[j]) : (b_ih1[j] + b_hh1[j]);
    } else {
      long long g4 = g3 - 4096;
      int dir = g4 >= 2048; int j = (int)(g4 & 2047);
      biasg2[dir * 2048 + j] = dir ? (b_ihr2[j] + b_hhr2[j]) : (b_ih2[j] + b_hh2[j]);
    }
  } else {
    // zero-init: stateBase (h2buf 262144B + slots 1024B = 16448 uint4)
    //            h1hist slot0 (131072B = 8192 uint4)
    long long z = gid - bs7;
    uint4 zero = {0u, 0u, 0u, 0u};
    if (z < 16448) {
      ((uint4*)stateBase)[z] = zero;
    } else if (z < 16448 + 8192) {
      ((uint4*)h1hist0)[z - 16448] = zero;
    }
  }
}

// ---------------- bf16 MFMA GEMM (r10 BK=32): C[m][n] = sum_k A[m][k]*B[n][k]
// MODE 0: fp32 out, no guards, +bias[n]  (mlim: early-exit on tm >= mlim[64])
// MODE 2: fp32 out, n<Nreal guard, +bias[m]
// MODE 3: bf16 out, no guards, +bias[n]
template<int MODE>
__global__ __launch_bounds__(256)
void k_gemm(const ushort_t* __restrict__ A0, long long As,
            const ushort_t* __restrict__ B0, long long Bs,
            const float* __restrict__ bias0, const float* __restrict__ bias1,
            void* __restrict__ out0, long long Os,
            int Nreal, int K, const int* __restrict__ mlim)
{
  long long tm = (long long)blockIdx.x * 128;
  if (mlim && tm >= mlim[64]) return;
  __shared__ ushort_t Ab[128 * 32];
  __shared__ ushort_t Bb[128 * 32];
  int dirz = blockIdx.z;
  const ushort_t* A = A0 + dirz * As;
  const ushort_t* Bm = B0 + dirz * Bs;
  const float* bias = dirz ? bias1 : bias0;
  int tid = threadIdx.x;
  int lane = tid & 63, wid = tid >> 6;
  int wr = wid >> 1, wc = wid & 1;
  long long tn = (long long)blockIdx.y * 128;
  f32x4 acc[4][4] = {};
  int c0 = tid, c1 = tid + 256;
  const ushort_t* Ag0 = A + (tm + (c0 >> 2)) * K + (c0 & 3) * 8;
  const ushort_t* Ag1 = A + (tm + (c1 >> 2)) * K + (c1 & 3) * 8;
  const ushort_t* Bg0 = Bm + (tn + (c0 >> 2)) * K + (c0 & 3) * 8;
  const ushort_t* Bg1 = Bm + (tn + (c1 >> 2)) * K + (c1 & 3) * 8;
  int KK = K >> 5;
  for (int kk = 0; kk < KK; ++kk) {
    uint4 va0 = *(const uint4*)(Ag0 + kk * 32);
    uint4 va1 = *(const uint4*)(Ag1 + kk * 32);
    uint4 vb0 = *(const uint4*)(Bg0 + kk * 32);
    uint4 vb1 = *(const uint4*)(Bg1 + kk * 32);
    __syncthreads();
    *(uint4*)&Ab[c0 * 8] = va0;
    *(uint4*)&Ab[c1 * 8] = va1;
    *(uint4*)&Bb[c0 * 8] = vb0;
    *(uint4*)&Bb[c1 * 8] = vb1;
    __syncthreads();
    int koff = (lane >> 4) * 8;
    bf16x8 av[4], bv[4];
    #pragma unroll
    for (int mi = 0; mi < 4; ++mi)
      av[mi] = *(const bf16x8*)&Ab[(wr * 64 + mi * 16 + (lane & 15)) * 32 + koff];
    #pragma unroll
    for (int ni = 0; ni < 4; ++ni)
      bv[ni] = *(const bf16x8*)&Bb[(wc * 64 + ni * 16 + (lane & 15)) * 32 + koff];
    #pragma unroll
    for (int mi = 0; mi < 4; ++mi)
      #pragma unroll
      for (int ni = 0; ni < 4; ++ni)
        acc[mi][ni] = __builtin_amdgcn_mfma_f32_16x16x32_bf16(av[mi], bv[ni], acc[mi][ni], 0, 0, 0);
  }
  #pragma unroll
  for (int mi = 0; mi < 4; ++mi) {
    #pragma unroll
    for (int rr = 0; rr < 4; ++rr) {
      long long m = tm + wr * 64 + mi * 16 + ((lane >> 4) * 4) + rr;
      if (MODE == 0) {
        float* orow = (float*)out0 + dirz * Os + m * (long long)Nreal;
        #pragma unroll
        for (int ni = 0; ni < 4; ++ni) {
          int n = (int)tn + wc * 64 + ni * 16 + (lane & 15);
          orow[n] = acc[mi][ni][rr] + bias[n];
        }
      } else if (MODE == 2) {
        float bm = bias[m];
        float* orow = (float*)out0 + dirz * Os + m * (long long)Nreal;
        #pragma unroll
        for (int ni = 0; ni < 4; ++ni) {
          int n = (int)tn + wc * 64 + ni * 16 + (lane & 15);
          if (n < Nreal) orow[n] = acc[mi][ni][rr] + bm;
        }
      } else {
        ushort_t* orow = (ushort_t*)out0 + dirz * Os + m * (long long)Nreal;
        #pragma unroll
        for (int ni = 0; ni < 4; ++ni) {
          int n = (int)tn + wc * 64 + ni * 16 + (lane & 15);
          orow[n] = f2bf(acc[mi][ni][rr] + bias[n]);
        }
      }
    }
  }
}

// ------- FC on compacted rows (BK=32) + fused zero-fill of invalid rows -----
// rowmap is a FULL permutation: [0,Mc) valid rows, [Mc,MR) invalid rows.
__global__ __launch_bounds__(256)
void k_fc(const ushort_t* __restrict__ A0, const ushort_t* __restrict__ B0,
          const float* __restrict__ bias0, const float* __restrict__ bias1,
          float* __restrict__ out0, const int* __restrict__ rowmap,
          const int* __restrict__ cumtab)
{
  const long long PRED = (long long)MR * V10K;
  int Mc = cumtab[64];
  long long tm = (long long)blockIdx.x * 128;
  int dirz = blockIdx.z;
  long long tn = (long long)blockIdx.y * 128;
  float* out = out0 + (long long)dirz * PRED;
  int tid = threadIdx.x;
  if (tm >= Mc) {
    // pure zero tile: 2 threads/row, float4 stores (V10K % 4 == 0)
    int row = tid >> 1, hf = tid & 1;
    long long c = tm + row;
    if (c < MR) {
      int m = rowmap[c];
      float* orow = out + (long long)m * V10K;
      float4 z = {0.f, 0.f, 0.f, 0.f};
      int col0 = (int)tn + hf * 64;
      #pragma unroll
      for (int qq = 0; qq < 16; ++qq) {
        int col = col0 + qq * 4;
        if (col < V10K) *(float4*)(orow + col) = z;
      }
    }
    return;
  }
  __shared__ ushort_t Ab[128 * 32];
  __shared__ ushort_t Bb[128 * 32];
  const ushort_t* A = A0 + (long long)dirz * MP * 512;
  const ushort_t* Bm = B0 + (long long)dirz * NPFC * 512;
  const float* bias = dirz ? bias1 : bias0;
  int lane = tid & 63, wid = tid >> 6;
  int wr = wid >> 1, wc = wid & 1;
  f32x4 acc[4][4] = {};
  int c0 = tid, c1 = tid + 256;
  const ushort_t* Ag0 = A + (tm + (c0 >> 2)) * 512 + (c0 & 3) * 8;
  const ushort_t* Ag1 = A + (tm + (c1 >> 2)) * 512 + (c1 & 3) * 8;
  const ushort_t* Bg0 = Bm + (tn + (c0 >> 2)) * 512 + (c0 & 3) * 8;
  const ushort_t* Bg1 = Bm + (tn + (c1 >> 2)) * 512 + (c1 & 3) * 8;
  for (int kk = 0; kk < 16; ++kk) {
    uint4 va0 = *(const uint4*)(Ag0 + kk * 32);
    uint4 va1 = *(const uint4*)(Ag1 + kk * 32);
    uint4 vb0 = *(const uint4*)(Bg0 + kk * 32);
    uint4 vb1 = *(const uint4*)(Bg1 + kk * 32);
    __syncthreads();
    *(uint4*)&Ab[c0 * 8] = va0;
    *(uint4*)&Ab[c1 * 8] = va1;
    *(uint4*)&Bb[c0 * 8] = vb0;
    *(uint4*)&Bb[c1 * 8] = vb1;
    __syncthreads();
    int koff = (lane >> 4) * 8;
    bf16x8 av[4], bv[4];
    #pragma unroll
    for (int mi2 = 0; mi2 < 4; ++mi2)
      av[mi2] = *(const bf16x8*)&Ab[(wr * 64 + mi2 * 16 + (lane & 15)) * 32 + koff];
    #pragma unroll
    for (int ni2 = 0; ni2 < 4; ++ni2)
      bv[ni2] = *(const bf16x8*)&Bb[(wc * 64 + ni2 * 16 + (lane & 15)) * 32 + koff];
    #pragma unroll
    for (int mi2 = 0; mi2 < 4; ++mi2)
      #pragma unroll
      for (int ni2 = 0; ni2 < 4; ++ni2)
        acc[mi2][ni2] = __builtin_amdgcn_mfma_f32_16x16x32_bf16(av[mi2], bv[ni2], acc[mi2][ni2], 0, 0, 0);
  }
  #pragma unroll
  for (int mi2 = 0; mi2 < 4; ++mi2) {
    #pragma unroll
    for (int rr = 0; rr < 4; ++rr) {
      long long c = tm + wr * 64 + mi2 * 16 + ((lane >> 4) * 4) + rr;
      if (c < MR) {
        int m = rowmap[c];
        bool val = (c < Mc);
        float* orow = out + (long long)m * V10K;
        #pragma unroll
        for (int ni2 = 0; ni2 < 4; ++ni2) {
          int n = (int)tn + wc * 64 + ni2 * 16 + (lane & 15);
          if (n < V10K) orow[n] = val ? (acc[mi2][ni2][rr] + bias[n]) : 0.f;
        }
      }
    }
  }
}

// ---------------- persistent recurrent kernel (r10 structure) ---------------
// bid 0..127:   L1 (idx=bid:     dir=idx>>6, half=(idx&63)>>5, ht=idx&31)
// bid 128..255: L2 (idx=bid-128: same decomposition)
// 128 threads (2 waves), both waves compute 16 rows each.
// Single combined poll per step; L2 poll folded to ONE load/iter via
// lane-split (lanes 0-31 check aS>=t+1, lanes 32-63 check bS>=t).
// h2all stores deferred until AFTER the flag (read only by k_fc post-kernel).
__global__ __launch_bounds__(128, 1)
void k_rec(const ushort_t* __restrict__ whh1bf, const ushort_t* __restrict__ wih2Lbf,
           const ushort_t* __restrict__ whh2bf, const float* __restrict__ xg1,
           const float* __restrict__ xg2imgT,
           ushort_t* __restrict__ h1hist,   // [52][2][64][512] bf16; slot0 = zeros
           ushort_t* __restrict__ h2buf,    // [2][2][64][512]  (ping-pong, zeroed)
           ushort_t* __restrict__ h2allbf,  // [dir][compact c][512]
           const int* __restrict__ nvtab, const int* __restrict__ cumtab,
           int* __restrict__ slots)         // [0..127]=aS (4 grp x32), [128..255]=bS
{
  const int bid = blockIdx.x;
  const bool isL2 = bid >= 128;
  const int idx = isL2 ? bid - 128 : bid;
  const int dir = idx >> 6, sub = idx & 63, half = sub >> 5, ht = sub & 31;
  const int tid = threadIdx.x;          // 0..127
  const int lane = tid & 63, mt = tid >> 6;
  const int l15 = lane & 15, l4 = lane >> 4;
  const int jl = ht * 16 + l15;
  const int rbase = half * 32 + mt * 16;
  const int r0 = rbase + l4 * 4;

  __shared__ ushort_t Wl[32768];  // 64KB [4 gates][16 cols][512 k] XOR-swizzled
  __shared__ ushort_t Wi[32768];  // 64KB wih2 h1-part (L2 only)
  __shared__ int nv_s[64];
  __shared__ int cum_s[64];

  {
    const ushort_t* src = (isL2 ? whh2bf : whh1bf) + (long long)dir * 2048 * 512;
    #pragma unroll
    for (int i = 0; i < 32; ++i) {
      int c = tid + i * 128;
      int nl = c >> 6;
      int kb = (c & 63) * 16;
      int row = (nl >> 4) * 512 + ht * 16 + (nl & 15);
      u32x4 v = *(const u32x4*)(src + (long long)row * 512 + (long long)(c & 63) * 8);
      *(u32x4*)((char*)Wl + nl * 1024 + (kb ^ ((nl & 7) << 4))) = v;
    }
    if (isL2) {
      const ushort_t* src2 = wih2Lbf + (long long)dir * 2048 * 512;
      #pragma unroll
      for (int i = 0; i < 32; ++i) {
        int c = tid + i * 128;
        int nl = c >> 6;
        int kb = (c & 63) * 16;
        int row = (nl >> 4) * 512 + ht * 16 + (nl & 15);
        u32x4 v = *(const u32x4*)(src2 + (long long)row * 512 + (long long)(c & 63) * 8);
        *(u32x4*)((char*)Wi + nl * 1024 + (kb ^ ((nl & 7) << 4))) = v;
      }
    }
    if (tid < TD) nv_s[tid] = nvtab[tid];
    if (tid < 64) cum_s[tid] = cumtab[tid];
  }
  __syncthreads();

  int* aS = slots + (dir * 2 + half) * 32;
  int* bS = slots + 128 + (dir * 2 + half) * 32;

  if (!isL2) {
    // ---------------- L1 pipeline (2 waves x 16 rows) ----------------
    f32x4 creg = {0.f, 0.f, 0.f, 0.f};
    for (int t = 0; t < TD; ++t) {
      bool act = (rbase < nv_s[t]);
      // x-gate loads (h-independent, compacted xg1): issue before the poll
      float xs[4][4];
      if (act) {
        const float* xb = xg1 + (long long)dir * MP * 2048;
        #pragma unroll
        for (int rr = 0; rr < 4; ++rr) {
          const float* xr = xb + (long long)(cum_s[r0 + rr] + t) * 2048;
          #pragma unroll
          for (int g = 0; g < 4; ++g)
            xs[g][rr] = xr[g * 512 + jl];
        }
      }
      if (t > 0) {
        if (mt == 0) {
          for (;;) {
            int v = __hip_atomic_load(&aS[lane & 31], __ATOMIC_RELAXED, __HIP_MEMORY_SCOPE_AGENT);
            if (__all(v >= t)) break;
          }
        }
        __syncthreads();
      }
      if (act) {
        const ushort_t* hsrc = h1hist + ((long long)t * 2 + dir) * (64 * 512);
        u32x4 hv[16];
        loadA16(hsrc + (long long)(rbase + l15) * 512 + l4 * 8, hv);
        f32x4 acc[4] = {};
        #pragma unroll
        for (int kk = 0; kk < 16; ++kk) {
          bf16x8 av = __builtin_bit_cast(bf16x8, hv[kk]);
          int kb = kk * 64 + l4 * 16;
          #pragma unroll
          for (int g = 0; g < 4; ++g) {
            bf16x8 bv = *(const bf16x8*)((const char*)Wl + (g * 16 + l15) * 1024 + (kb ^ ((l15 & 7) << 4)));
            acc[g] = __builtin_amdgcn_mfma_f32_16x16x32_bf16(av, bv, acc[g], 0, 0, 0);
          }
        }
        ushort_t* hdst = h1hist + ((long long)(t + 1) * 2 + dir) * (64 * 512);
        f32x4 cn;
        #pragma unroll
        for (int rr = 0; rr < 4; ++rr) {
          float gi = acc[0][rr] + xs[0][rr];
          float gf = acc[1][rr] + xs[1][rr];
          float gg = acc[2][rr] + xs[2][rr];
          float go = acc[3][rr] + xs[3][rr];
          float c = sigm(gf) * creg[rr] + sigm(gi) * tanhf(gg);
          float h = sigm(go) * tanhf(c);
          cn[rr] = c;
          store2_sc(hdst + (long long)(r0 + rr) * 512 + jl, (unsigned)f2bf(h));
        }
        creg = cn;
      }
      __syncthreads();   // drains each wave's vmcnt before the slot store
      if (tid == 0)
        __hip_atomic_store(&aS[ht], t + 1, __ATOMIC_RELAXED, __HIP_MEMORY_SCOPE_AGENT);
    }
  } else {
    // ---------------- L2 pipeline (2 waves x 16 rows) ----------------
    f32x4 xv2[4];
    {
      const float* xg = xg2imgT + (long long)dir * (2048 * 64);
      #pragma unroll
      for (int g = 0; g < 4; ++g)
        xv2[g] = *(const f32x4*)(xg + (long long)(g * 512 + jl) * 64 + r0);
    }
    // lane-split poll source: lanes 0-31 watch aS, lanes 32-63 watch bS
    int* pollPtr = (lane < 32) ? &aS[lane & 31] : &bS[lane & 31];
    const int thrOff = (lane < 32) ? 1 : 0;   // aS needs >= t+1, bS needs >= t
    f32x4 creg = {0.f, 0.f, 0.f, 0.f};
    for (int t = 0; t < TD; ++t) {
      // single combined poll, ONE load per iteration
      if (mt == 0) {
        int thr = t + thrOff;
        for (;;) {
          int v = __hip_atomic_load(pollPtr, __ATOMIC_RELAXED, __HIP_MEMORY_SCOPE_AGENT);
          if (__all(v >= thr)) break;
        }
      }
      __syncthreads();
      int nv = nv_s[t];
      bool act = (rbase < nv);
      ushort_t hb4[4];
      if (act) {
        const ushort_t* h1s = h1hist + ((long long)(t + 1) * 2 + dir) * (64 * 512);
        const ushort_t* h2s = h2buf + ((long long)((t + 1) & 1) * 2 + dir) * (64 * 512);
        u32x4 ha[16], hb[16];
        loadA32(h1s + (long long)(rbase + l15) * 512 + l4 * 8,
                h2s + (long long)(rbase + l15) * 512 + l4 * 8, ha, hb);
        f32x4 acc[4] = {};
        #pragma unroll
        for (int kk = 0; kk < 16; ++kk) {
          bf16x8 av = __builtin_bit_cast(bf16x8, ha[kk]);
          int kb = kk * 64 + l4 * 16;
          #pragma unroll
          for (int g = 0; g < 4; ++g) {
            bf16x8 bv = *(const bf16x8*)((const char*)Wi + (g * 16 + l15) * 1024 + (kb ^ ((l15 & 7) << 4)));
            acc[g] = __builtin_amdgcn_mfma_f32_16x16x32_bf16(av, bv, acc[g], 0, 0, 0);
          }
        }
        #pragma unroll
        for (int kk = 0; kk < 16; ++kk) {
          bf16x8 av = __builtin_bit_cast(bf16x8, hb[kk]);
          int kb = kk * 64 + l4 * 16;
          #pragma unroll
          for (int g = 0; g < 4; ++g) {
            bf16x8 bv = *(const bf16x8*)((const char*)Wl + (g * 16 + l15) * 1024 + (kb ^ ((l15 & 7) << 4)));
            acc[g] = __builtin_amdgcn_mfma_f32_16x16x32_bf16(av, bv, acc[g], 0, 0, 0);
          }
        }
        ushort_t* h2n = h2buf + ((long long)(t & 1) * 2 + dir) * (64 * 512);
        f32x4 cn;
        #pragma unroll
        for (int rr = 0; rr < 4; ++rr) {
          float gi = acc[0][rr] + xv2[0][rr];
          float gf = acc[1][rr] + xv2[1][rr];
          float gg = acc[2][rr] + xv2[2][rr];
          float go = acc[3][rr] + xv2[3][rr];
          float c = sigm(gf) * creg[rr] + sigm(gi) * tanhf(gg);
          float h = sigm(go) * tanhf(c);
          cn[rr] = c;
          ushort_t hbb = f2bf(h);
          hb4[rr] = hbb;
          store2_sc(h2n + (long long)(r0 + rr) * 512 + jl, (unsigned)hbb);
        }
        creg = cn;
      }
      __syncthreads();   // drains each wave's vmcnt (h2n sc1) before the slot store
      if (tid == 0)
        __hip_atomic_store(&bS[ht], t + 1, __ATOMIC_RELAXED, __HIP_MEMORY_SCOPE_AGENT);
      // deferred h2all stores: consumed only by k_fc after kernel end
      if (act) {
        ushort_t* h2a = h2allbf + (long long)dir * MP * 512;
        #pragma unroll
        for (int rr = 0; rr < 4; ++rr)
          if (r0 + rr < nv)
            h2a[((long long)(cum_s[r0 + rr] + t)) * 512 + jl] = hb4[rr];
      }
    }
  }
}

// ---------------------------------------------------------------------------
extern "C" void kernel_launch(void* const* d_in, const int* in_sizes, int n_in,
                              void* d_out, int out_size, void* d_ws, size_t ws_size,
                              hipStream_t stream)
{
  const float* enc     = (const float*)d_in[0];
  const int*   caps    = (const int*)d_in[1];
  const int*   cl      = (const int*)d_in[2];
  const float* emb_w   = (const float*)d_in[3];
  const float* emb_r_w = (const float*)d_in[4];
  const float* w_ih1   = (const float*)d_in[5];
  const float* w_hh1   = (const float*)d_in[6];
  const float* b_ih1   = (const float*)d_in[7];
  const float* b_hh1   = (const float*)d_in[8];
  const float* w_ih2   = (const float*)d_in[9];
  const float* w_hh2   = (const float*)d_in[10];
  const float* b_ih2   = (const float*)d_in[11];
  const float* b_hh2   = (const float*)d_in[12];
  const float* w_ihr1  = (const float*)d_in[13];
  const float* w_hhr1  = (const float*)d_in[14];
  const float* b_ihr1  = (const float*)d_in[15];
  const float* b_hhr1  = (const float*)d_in[16];
  const float* w_ihr2  = (const float*)d_in[17];
  const float* w_hhr2  = (const float*)d_in[18];
  const float* b_ihr2  = (const float*)d_in[19];
  const float* b_hhr2  = (const float*)d_in[20];
  const float* img_f_w = (const float*)d_in[21];
  const float* img_f_b = (const float*)d_in[22];
  const float* img_b_w = (const float*)d_in[23];
  const float* img_b_b = (const float*)d_in[24];
  const float* fc_w    = (const float*)d_in[25];
  const float* fc_b    = (const float*)d_in[26];
  const float* fcr_w   = (const float*)d_in[27];
  const float* fcr_b   = (const float*)d_in[28];

  float* outF = (float*)d_out;
  const long long PRED = (long long)MR * V10K;          // 32,640,000
  float* o_caps = outF + 2 * PRED;
  float* o_capr = o_caps + B64 * T52;
  float* o_lm1  = o_capr + B64 * T52;
  float* o_ord  = o_lm1 + B64;
  // big scratch parked inside the preds region of d_out (dead before FC):
  float*    xg1       = outF;                           // [2][MP][2048] compact
  ushort_t* whh1bf    = (ushort_t*)(outF + 27500000);   // 2,097,152 us each
  ushort_t* wih2Lbf   = (ushort_t*)(outF + 28600000);
  ushort_t* whh2bf    = (ushort_t*)(outF + 29700000);
  ushort_t* h1hist    = (ushort_t*)(outF + 31000000);   // [52][2][64][512] = 6.8MB
  ushort_t* wih2Ibf   = (ushort_t*)(outF + 34600000);
  ushort_t* imgwbf    = (ushort_t*)(outF + 35700000);   // [2][512][2048] bf16
  ushort_t* encbf     = (ushort_t*)(outF + 36800000);   // [128][2048] bf16
  ushort_t* imgbf     = (ushort_t*)(outF + 37000000);   // [2][128][512] bf16

  char* w = (char*)d_ws;
  auto alloc = [&](size_t bytes) -> char* {
    char* p = w; w += (bytes + 255) & ~(size_t)255; return p;
  };
  int*      order_i  = (int*)alloc(64 * 4);
  int*      lensm1_i = (int*)alloc(64 * 4);
  int*      nvtab    = (int*)alloc(64 * 4);
  int*      cumtab   = (int*)alloc(65 * 4);
  int*      rowmap   = (int*)alloc(MR * 4);
  int*      capsS    = (int*)alloc(B64 * T52 * 4);
  int*      capsRev  = (int*)alloc(B64 * T52 * 4);
  float*    biasg1   = (float*)alloc(2 * 2048 * 4);
  float*    biasg2   = (float*)alloc(2 * 2048 * 4);
  float*    xg2imgT  = (float*)alloc((size_t)2 * 2048 * 64 * 4);
  char*     stateBase = alloc(262144 + 1024);
  ushort_t* h2buf = (ushort_t*)stateBase;               // [2 pp][2 dir][64][512] bf16
  int*      slotp = (int*)(stateBase + 262144);         // 256 flags
  ushort_t* embA    = (ushort_t*)alloc((size_t)2 * MP * 512 * 2);
  ushort_t* wih1bf  = (ushort_t*)alloc((size_t)2 * 2048 * 512 * 2);
  ushort_t* fcwbf   = (ushort_t*)alloc((size_t)2 * NPFC * 512 * 2);
  ushort_t* h2allbf = (ushort_t*)alloc((size_t)2 * MP * 512 * 2);

  k_prep<<<1, 64, 0, stream>>>(cl, caps, o_caps, o_capr, o_lm1, o_ord,
                               order_i, lensm1_i, nvtab, capsS, capsRev,
                               cumtab, rowmap);
  // k_convert also zero-inits h2buf/slots (16448 uint4) + h1hist slot0 (8192)
  k_convert<<<13121, 256, 0, stream>>>(w_ih1, w_ihr1, fc_w, fcr_w,
                                       b_ih1, b_hh1, b_ihr1, b_hhr1,
                                       w_hh1, w_hhr1, w_ih2, w_ihr2, w_hh2, w_hhr2,
                                       img_f_w, img_b_w, b_ih2, b_hh2, b_ihr2, b_hhr2,
                                       enc, order_i, emb_w, emb_r_w,
                                       capsS, capsRev, rowmap, cumtab,
                                       wih1bf, fcwbf, whh1bf, wih2Lbf, whh2bf,
                                       wih2Ibf, imgwbf, encbf, embA, biasg1, biasg2,
                                       stateBase, (char*)h1hist);
  // img = enc @ imgw^T + b  (bf16 out, [2][128][512])
  k_gemm<3><<<dim3(1, 4, 2), 256, 0, stream>>>(encbf, 0LL,
                                               imgwbf, 512LL * 2048,
                                               img_f_b, img_b_b,
                                               imgbf, 128LL * 512,
                                               512, 2048, nullptr);
  // xg2imgT[j][b] = wih2I[j] . img[b] + biasg2[j]   ([2][2048][64] fp32)
  k_gemm<2><<<dim3(16, 1, 2), 256, 0, stream>>>(wih2Ibf, 2048LL * 512,
                                                imgbf, 128LL * 512,
                                                biasg2, biasg2 + 2048,
                                                xg2imgT, 2048LL * 64,
                                                64, 512, nullptr);
  // xg1 [dir][compact c][2048] fp32 (early-exit on tm >= Mc)
  k_gemm<0><<<dim3(26, 16, 2), 256, 0, stream>>>(embA, (long long)MP * 512,
                                                 wih1bf, 2048LL * 512,
                                                 biasg1, biasg1 + 2048,
                                                 xg1, (long long)MP * 2048,
                                                 2048, 512, cumtab);
  k_rec<<<256, 128, 0, stream>>>(whh1bf, wih2Lbf, whh2bf, xg1, xg2imgT,
                                 h1hist, h2buf, h2allbf, nvtab, cumtab, slotp);
  k_fc<<<dim3(26, 79, 2), 256, 0, stream>>>(h2allbf, fcwbf, fc_b, fcr_b,
                                            outF, rowmap, cumtab);
}